// Round 6
// baseline (489.311 us; speedup 1.0000x reference)
//
#include <hip/hip_runtime.h>
#include <math.h>

#define BB 4
#define SS 2048
#define DD 1024
#define HHD 16      // heads
#define HD 64       // head dim
#define DH 512      // indexer hidden
#define KSEL 614    // top-k count
#define KPAD 640    // padded to multiple of 64
#define MTOT (BB*SS)
#define QKVS 3072   // fused QKV row stride
#define NCH (KPAD/64)

typedef __attribute__((ext_vector_type(8))) short bf16x8;
typedef __attribute__((ext_vector_type(4))) float f32x4;

#define LDS_CAST(p) ((__attribute__((address_space(3))) void*)(p))
#define GLB_CAST(p) ((const __attribute__((address_space(1))) void*)(p))

// ---------------- fp32 -> bf16 helpers (RNE)
__device__ inline short bf16rne(float v)
{
    unsigned u = __builtin_bit_cast(unsigned, v);
    return (short)((u + 0x7FFFu + ((u >> 16) & 1u)) >> 16);
}

__device__ inline void split1(float v, short& h, short& l)
{
    unsigned u = __builtin_bit_cast(unsigned, v);
    unsigned hr = (u + 0x7FFFu + ((u >> 16) & 1u)) >> 16;
    h = (short)hr;
    float hf = __builtin_bit_cast(float, hr << 16);
    float res = v - hf;
    unsigned u2 = __builtin_bit_cast(unsigned, res);
    unsigned lr = (u2 + 0x7FFFu + ((u2 >> 16) & 1u)) >> 16;
    l = (short)lr;
}

__device__ inline bf16x8 pack8(float4 a, float4 b)
{
    bf16x8 o;
    o[0]=bf16rne(a.x); o[1]=bf16rne(a.y); o[2]=bf16rne(a.z); o[3]=bf16rne(a.w);
    o[4]=bf16rne(b.x); o[5]=bf16rne(b.y); o[6]=bf16rne(b.z); o[7]=bf16rne(b.w);
    return o;
}

__global__ __launch_bounds__(256)
void split_convert(const float* __restrict__ in, short* __restrict__ hi,
                   short* __restrict__ lo, int n4)
{
    const int i = blockIdx.x * 256 + threadIdx.x;
    if (i >= n4) return;
    float4 v = reinterpret_cast<const float4*>(in)[i];
    short4 h, l;
    split1(v.x, h.x, l.x);
    split1(v.y, h.y, l.y);
    split1(v.z, h.z, l.z);
    split1(v.w, h.w, l.w);
    reinterpret_cast<short4*>(hi)[i] = h;
    reinterpret_cast<short4*>(lo)[i] = l;
}

__global__ __launch_bounds__(256)
void concat_bias(const float* __restrict__ a, const float* __restrict__ b,
                 float* __restrict__ o)
{
    const int i = blockIdx.x * 256 + threadIdx.x;   // 2048
    o[i] = (i < 1024) ? a[i] : b[i - 1024];
}

// ---------------- plain bf16 MFMA GEMM: C[M,N] = Ahi @ Bhi^T + bias  (m97 structure)
__global__ __launch_bounds__(256)
void gemm_bf16(const short* __restrict__ Ahi, const short* __restrict__ Bhi,
               const float* __restrict__ bias, float* __restrict__ C,
               int M, int N, int K, int ldc)
{
    __shared__ short sAh[128*32];
    __shared__ short sBh[128*32];

    const int t = threadIdx.x;
    const int lane = t & 63, wid = t >> 6;
    const int wm = wid >> 1, wn = wid & 1;
    const int row0 = blockIdx.y * 128, col0 = blockIdx.x * 128;
    const int g = lane >> 4, r = lane & 15;
    const int sw = g ^ ((lane >> 2) & 3);
    const int srow = lane >> 2;
    const int sslot = lane & 3;

    f32x4 acc[4][4];
    #pragma unroll
    for (int mt = 0; mt < 4; ++mt)
        #pragma unroll
        for (int nt = 0; nt < 4; ++nt) acc[mt][nt] = (f32x4){0.f, 0.f, 0.f, 0.f};

    for (int k0 = 0; k0 < K; k0 += 32) {
        #pragma unroll
        for (int i = 0; i < 2; ++i) {
            const int rl = wid * 32 + i * 16 + srow;
            const int scol = k0 + ((sslot ^ ((rl >> 2) & 3)) << 3);
            const size_t ga = (size_t)(row0 + rl) * K + scol;
            const size_t gb = (size_t)(col0 + rl) * K + scol;
            const int ldso = (wid * 32 + i * 16) * 32;
            __builtin_amdgcn_global_load_lds(GLB_CAST(Ahi + ga), LDS_CAST(sAh + ldso), 16, 0, 0);
            __builtin_amdgcn_global_load_lds(GLB_CAST(Bhi + gb), LDS_CAST(sBh + ldso), 16, 0, 0);
        }
        __syncthreads();

        bf16x8 ah[4], bh[4];
        #pragma unroll
        for (int mt = 0; mt < 4; ++mt)
            ah[mt] = *reinterpret_cast<const bf16x8*>(sAh + (wm * 64 + mt * 16 + r) * 32 + sw * 8);
        #pragma unroll
        for (int nt = 0; nt < 4; ++nt)
            bh[nt] = *reinterpret_cast<const bf16x8*>(sBh + (wn * 64 + nt * 16 + r) * 32 + sw * 8);
        #pragma unroll
        for (int mt = 0; mt < 4; ++mt)
            #pragma unroll
            for (int nt = 0; nt < 4; ++nt)
                acc[mt][nt] = __builtin_amdgcn_mfma_f32_16x16x32_bf16(ah[mt], bh[nt], acc[mt][nt], 0, 0, 0);
        __syncthreads();
    }

    #pragma unroll
    for (int nt = 0; nt < 4; ++nt) {
        const int col = wn * 64 + nt * 16 + r;
        const float bv = bias[col0 + col];
        #pragma unroll
        for (int mt = 0; mt < 4; ++mt) {
            #pragma unroll
            for (int e = 0; e < 4; ++e) {
                const int row = row0 + wm * 64 + mt * 16 + 4 * g + e;
                C[(size_t)row * ldc + col0 + col] = acc[mt][nt][e] + bv;
            }
        }
    }
}

// ---------------- split-bf16 MFMA GEMM (3-term): C = (Ahi+Alo)@(Bhi+Blo)^T + bias
template<bool RELU>
__global__ __launch_bounds__(256)
void gemm_split(const short* __restrict__ Ahi, const short* __restrict__ Alo,
                const short* __restrict__ Bhi, const short* __restrict__ Blo,
                const float* __restrict__ bias, float* __restrict__ C,
                int M, int N, int K, int ldc)
{
    __shared__ short sAh[128*32];
    __shared__ short sAl[128*32];
    __shared__ short sBh[128*32];
    __shared__ short sBl[128*32];

    const int t = threadIdx.x;
    const int lane = t & 63, wid = t >> 6;
    const int wm = wid >> 1, wn = wid & 1;
    const int row0 = blockIdx.y * 128, col0 = blockIdx.x * 128;
    const int g = lane >> 4, r = lane & 15;
    const int sw = g ^ ((lane >> 2) & 3);
    const int srow = lane >> 2;
    const int sslot = lane & 3;

    f32x4 acc[4][4];
    #pragma unroll
    for (int mt = 0; mt < 4; ++mt)
        #pragma unroll
        for (int nt = 0; nt < 4; ++nt) acc[mt][nt] = (f32x4){0.f, 0.f, 0.f, 0.f};

    for (int k0 = 0; k0 < K; k0 += 32) {
        #pragma unroll
        for (int i = 0; i < 2; ++i) {
            const int rl = wid * 32 + i * 16 + srow;
            const int scol = k0 + ((sslot ^ ((rl >> 2) & 3)) << 3);
            const size_t ga = (size_t)(row0 + rl) * K + scol;
            const size_t gb = (size_t)(col0 + rl) * K + scol;
            const int ldso = (wid * 32 + i * 16) * 32;
            __builtin_amdgcn_global_load_lds(GLB_CAST(Ahi + ga), LDS_CAST(sAh + ldso), 16, 0, 0);
            __builtin_amdgcn_global_load_lds(GLB_CAST(Alo + ga), LDS_CAST(sAl + ldso), 16, 0, 0);
            __builtin_amdgcn_global_load_lds(GLB_CAST(Bhi + gb), LDS_CAST(sBh + ldso), 16, 0, 0);
            __builtin_amdgcn_global_load_lds(GLB_CAST(Blo + gb), LDS_CAST(sBl + ldso), 16, 0, 0);
        }
        __syncthreads();

        bf16x8 ah[4], al[4], bh[4], bl[4];
        #pragma unroll
        for (int mt = 0; mt < 4; ++mt) {
            const int row = wm * 64 + mt * 16 + r;
            ah[mt] = *reinterpret_cast<const bf16x8*>(sAh + row * 32 + sw * 8);
            al[mt] = *reinterpret_cast<const bf16x8*>(sAl + row * 32 + sw * 8);
        }
        #pragma unroll
        for (int nt = 0; nt < 4; ++nt) {
            const int row = wn * 64 + nt * 16 + r;
            bh[nt] = *reinterpret_cast<const bf16x8*>(sBh + row * 32 + sw * 8);
            bl[nt] = *reinterpret_cast<const bf16x8*>(sBl + row * 32 + sw * 8);
        }
        #pragma unroll
        for (int mt = 0; mt < 4; ++mt)
            #pragma unroll
            for (int nt = 0; nt < 4; ++nt) {
                acc[mt][nt] = __builtin_amdgcn_mfma_f32_16x16x32_bf16(ah[mt], bh[nt], acc[mt][nt], 0, 0, 0);
                acc[mt][nt] = __builtin_amdgcn_mfma_f32_16x16x32_bf16(ah[mt], bl[nt], acc[mt][nt], 0, 0, 0);
                acc[mt][nt] = __builtin_amdgcn_mfma_f32_16x16x32_bf16(al[mt], bh[nt], acc[mt][nt], 0, 0, 0);
            }
        __syncthreads();
    }

    #pragma unroll
    for (int nt = 0; nt < 4; ++nt) {
        const int col = wn * 64 + nt * 16 + r;
        const float bv = bias[col0 + col];
        #pragma unroll
        for (int mt = 0; mt < 4; ++mt) {
            #pragma unroll
            for (int e = 0; e < 4; ++e) {
                const int row = row0 + wm * 64 + mt * 16 + 4 * g + e;
                float v = acc[mt][nt][e] + bv;
                if (RELU) v = fmaxf(v, 0.f);
                C[(size_t)row * ldc + col0 + col] = v;
            }
        }
    }
}

// ---------------- importance / top-k
__global__ __launch_bounds__(256)
void importance_kernel(const float* __restrict__ h, const float* __restrict__ wi2,
                       const float* __restrict__ bi2, float* __restrict__ imp)
{
    const int wid = threadIdx.x >> 6, lane = threadIdx.x & 63;
    const int row = blockIdx.x * 4 + wid;
    const float* hr = h + (size_t)row * DH;
    float s = 0.f;
    #pragma unroll
    for (int i = 0; i < DH/64; ++i)
        s = fmaf(hr[lane + i*64], wi2[lane + i*64], s);
    #pragma unroll
    for (int off = 32; off; off >>= 1) s += __shfl_down(s, off);
    if (lane == 0) imp[row] = s + bi2[0];
}

__global__ __launch_bounds__(256)
void rank_kernel(const float* __restrict__ imp, int* __restrict__ flags)
{
    const int b = blockIdx.y;
    const int i = blockIdx.x * 256 + threadIdx.x;
    const float* bimp = imp + b * SS;
    const float v = bimp[i];
    int rank = 0;
    for (int j = 0; j < SS; ++j) {
        const float u = bimp[j];
        rank += (u > v) || ((u == v) && (j < i));
    }
    flags[b * SS + i] = (rank < KSEL) ? 1 : 0;
}

__global__ __launch_bounds__(256)
void compact_kernel(const int* __restrict__ flags, int* __restrict__ idxg)
{
    __shared__ int sscan[SS];
    __shared__ int sidx[KSEL];
    const int b = blockIdx.x, t = threadIdx.x;
    for (int i = t; i < SS; i += 256) sscan[i] = flags[b * SS + i];
    __syncthreads();
    for (int off = 1; off < SS; off <<= 1) {
        int vals[SS/256];
        #pragma unroll
        for (int c = 0; c < SS/256; ++c) {
            const int i = t + c * 256;
            int v = sscan[i];
            if (i >= off) v += sscan[i - off];
            vals[c] = v;
        }
        __syncthreads();
        #pragma unroll
        for (int c = 0; c < SS/256; ++c) sscan[t + c * 256] = vals[c];
        __syncthreads();
    }
    for (int i = t; i < SS; i += 256) {
        const int f = flags[b * SS + i];
        if (f) sidx[sscan[i] - 1] = i;
    }
    __syncthreads();
    for (int p = t; p < KPAD; p += 256)
        idxg[b * KPAD + p] = sidx[min(p, KSEL - 1)];
}

// ---------------- one-shot K/V gather + fp32->bf16 + V transpose
// Kg[b][h][KPAD][64] bf16 ; Vg[b][h][64(d)][KPAD] bf16
__global__ __launch_bounds__(256)
void gather_kv(const float* __restrict__ QKV, const int* __restrict__ idxg,
               short* __restrict__ Kg, short* __restrict__ Vg)
{
    __shared__ short Vs[64][72];   // [d][key]
    const int t = threadIdx.x;
    const int c = blockIdx.x, h = blockIdx.y, b = blockIdx.z;
    const int srow = t >> 2;   // key in chunk 0..63
    const int sq4  = t & 3;    // 16-elem quarter

    const int krow = idxg[b * KPAD + c * 64 + srow];
    const float* kb = QKV + (size_t)(b * SS + krow) * QKVS + 1024 + h * HD + sq4 * 16;
    float4 k0 = *reinterpret_cast<const float4*>(kb);
    float4 k1 = *reinterpret_cast<const float4*>(kb + 4);
    float4 k2 = *reinterpret_cast<const float4*>(kb + 8);
    float4 k3 = *reinterpret_cast<const float4*>(kb + 12);
    short* kout = Kg + ((size_t)(b * HHD + h) * KPAD + c * 64 + srow) * HD + sq4 * 16;
    *reinterpret_cast<bf16x8*>(kout)     = pack8(k0, k1);
    *reinterpret_cast<bf16x8*>(kout + 8) = pack8(k2, k3);

    const float* vbp = kb + 1024;
    float4 v0 = *reinterpret_cast<const float4*>(vbp);
    float4 v1 = *reinterpret_cast<const float4*>(vbp + 4);
    float4 v2 = *reinterpret_cast<const float4*>(vbp + 8);
    float4 v3 = *reinterpret_cast<const float4*>(vbp + 12);
    float vv[16] = {v0.x,v0.y,v0.z,v0.w, v1.x,v1.y,v1.z,v1.w,
                    v2.x,v2.y,v2.z,v2.w, v3.x,v3.y,v3.z,v3.w};
    #pragma unroll
    for (int j = 0; j < 16; ++j)
        Vs[sq4 * 16 + j][srow] = bf16rne(vv[j]);
    __syncthreads();

    short* vout = Vg + ((size_t)(b * HHD + h) * HD + srow) * KPAD + c * 64 + sq4 * 16;
    *reinterpret_cast<bf16x8*>(vout)     = *reinterpret_cast<const bf16x8*>(&Vs[srow][sq4 * 16]);
    *reinterpret_cast<bf16x8*>(vout + 8) = *reinterpret_cast<const bf16x8*>(&Vs[srow][sq4 * 16 + 8]);
}

// ---------------- MFMA sparse flash attention: barrier-free, K/V fragments from global bf16
__global__ __launch_bounds__(256)
void attn_mfma(const float* __restrict__ QKV, const short* __restrict__ Kg,
               const short* __restrict__ Vg,
               short* __restrict__ AOhi, short* __restrict__ AOlo)
{
    __shared__ short Ps[4][16*72];

    const int t = threadIdx.x;
    const int lane = t & 63, w = t >> 6;
    const int g = lane >> 4, r = lane & 15;
    const int qt = blockIdx.x, h = blockIdx.y, b = blockIdx.z;
    const int q0 = qt * 64;
    short* Psw = &Ps[w][0];

    // Q fragments, pre-scaled by 1/8, plain bf16
    bf16x8 qh[2];
    {
        const float* qrow = QKV + (size_t)(b * SS + q0 + w * 16 + r) * QKVS + h * HD;
        #pragma unroll
        for (int ch = 0; ch < 2; ++ch) {
            float4 f0 = *reinterpret_cast<const float4*>(&qrow[ch*32 + 8*g]);
            float4 f1 = *reinterpret_cast<const float4*>(&qrow[ch*32 + 8*g + 4]);
            float v[8] = {f0.x, f0.y, f0.z, f0.w, f1.x, f1.y, f1.z, f1.w};
            #pragma unroll
            for (int e = 0; e < 8; ++e) qh[ch][e] = bf16rne(v[e] * 0.125f);
        }
    }

    const short* kbase = Kg + (size_t)(b * HHD + h) * KPAD * HD;
    const short* vbase = Vg + (size_t)(b * HHD + h) * HD * KPAD;

    f32x4 oacc[4];
    #pragma unroll
    for (int dt = 0; dt < 4; ++dt) oacc[dt] = (f32x4){0.f, 0.f, 0.f, 0.f};
    float mrun[4] = {-INFINITY, -INFINITY, -INFINITY, -INFINITY};
    float lrun[4] = {0.f, 0.f, 0.f, 0.f};

    for (int c = 0; c < NCH; ++c) {
        // ---- QK^T: fragments straight from global (L1/L2-resident)
        f32x4 sa[4];
        #pragma unroll
        for (int kt = 0; kt < 4; ++kt) {
            const short* kr = kbase + (size_t)(c*64 + kt*16 + r) * HD + 8*g;
            bf16x8 kf0 = *reinterpret_cast<const bf16x8*>(kr);
            bf16x8 kf1 = *reinterpret_cast<const bf16x8*>(kr + 32);
            f32x4 s = (f32x4){0.f, 0.f, 0.f, 0.f};
            s = __builtin_amdgcn_mfma_f32_16x16x32_bf16(qh[0], kf0, s, 0, 0, 0);
            s = __builtin_amdgcn_mfma_f32_16x16x32_bf16(qh[1], kf1, s, 0, 0, 0);
            sa[kt] = s;
        }
        if (c == NCH - 1) {
            #pragma unroll
            for (int kt = 0; kt < 4; ++kt)
                if (c*64 + kt*16 + r >= KSEL)
                    sa[kt] = (f32x4){-INFINITY, -INFINITY, -INFINITY, -INFINITY};
        }

        // ---- online softmax (rows q = 4g+e; reduce over 16-lane key groups)
        float p[4][4], scl[4];
        #pragma unroll
        for (int e = 0; e < 4; ++e) {
            float mx = fmaxf(fmaxf(sa[0][e], sa[1][e]), fmaxf(sa[2][e], sa[3][e]));
            #pragma unroll
            for (int off = 1; off < 16; off <<= 1) mx = fmaxf(mx, __shfl_xor(mx, off));
            const float mnew = fmaxf(mrun[e], mx);
            scl[e] = __expf(mrun[e] - mnew);
            float s0 = 0.f;
            #pragma unroll
            for (int kt = 0; kt < 4; ++kt) { p[kt][e] = __expf(sa[kt][e] - mnew); s0 += p[kt][e]; }
            #pragma unroll
            for (int off = 1; off < 16; off <<= 1) s0 += __shfl_xor(s0, off);
            lrun[e] = lrun[e] * scl[e] + s0;
            mrun[e] = mnew;
        }
        #pragma unroll
        for (int dt = 0; dt < 4; ++dt)
            #pragma unroll
            for (int e = 0; e < 4; ++e) oacc[dt][e] *= scl[e];

        // ---- P -> bf16 per-wave LDS transpose (in-order DS pipe, no barrier needed)
        #pragma unroll
        for (int kt = 0; kt < 4; ++kt)
            #pragma unroll
            for (int e = 0; e < 4; ++e)
                Psw[(4*g + e)*72 + ((kt*16 + r) ^ (8*g))] = bf16rne(p[kt][e]);

        // ---- PV: V fragments straight from global
        #pragma unroll
        for (int kc = 0; kc < 2; ++kc) {
            bf16x8 pf = *reinterpret_cast<const bf16x8*>(&Psw[r*72 + kc*32 + 8*(g ^ (r >> 2))]);
            #pragma unroll
            for (int dt = 0; dt < 4; ++dt) {
                bf16x8 vf = *reinterpret_cast<const bf16x8*>(
                    vbase + (size_t)(dt*16 + r) * KPAD + c*64 + kc*32 + 8*g);
                oacc[dt] = __builtin_amdgcn_mfma_f32_16x16x32_bf16(pf, vf, oacc[dt], 0, 0, 0);
            }
        }
    }

    // ---- epilogue: normalize, split hi/lo, store
    #pragma unroll
    for (int dt = 0; dt < 4; ++dt)
        #pragma unroll
        for (int e = 0; e < 4; ++e) {
            const float o = oacc[dt][e] / lrun[e];
            short hh, ll;
            split1(o, hh, ll);
            const size_t a = (size_t)(b * SS + q0 + w*16 + 4*g + e) * DD + h * HD + dt*16 + r;
            AOhi[a] = hh; AOlo[a] = ll;
        }
}

extern "C" void kernel_launch(void* const* d_in, const int* in_sizes, int n_in,
                              void* d_out, int out_size, void* d_ws, size_t ws_size,
                              hipStream_t stream)
{
    const float* x   = (const float*)d_in[0];
    const float* wq  = (const float*)d_in[1];
    const float* bq  = (const float*)d_in[2];
    const float* wk  = (const float*)d_in[3];
    const float* bk  = (const float*)d_in[4];
    const float* wv  = (const float*)d_in[5];
    const float* bv  = (const float*)d_in[6];
    const float* wo  = (const float*)d_in[7];
    const float* bo  = (const float*)d_in[8];
    const float* wi1 = (const float*)d_in[9];
    const float* bi1 = (const float*)d_in[10];
    const float* wi2 = (const float*)d_in[11];
    const float* bi2 = (const float*)d_in[12];
    float* out = (float*)d_out;

    const size_t MB = 1ull << 20;
    char* W = (char*)d_ws;
    short* x_hi  = (short*)(W + 0);          // 16 MB
    short* x_lo  = (short*)(W + 16*MB);      // 16 MB
    float* QKV   = (float*)(W + 32*MB);      // 96 MB
    short* Bqk_hi= (short*)(W + 128*MB);     // 4 MB (2048 x 1024 bf16: wq,wk)
    short* Bv_hi = (short*)(W + 132*MB);     // 2 MB
    short* Bv_lo = (short*)(W + 134*MB);     // 2 MB
    short* wo_hi = (short*)(W + 136*MB);     // 2 MB
    short* wo_lo = (short*)(W + 138*MB);     // 2 MB
    short* dead_lo = (short*)(W + 140*MB);   // 4 MB scratch for unneeded lo of wq/wk
    float* Hw    = (float*)(W + 144*MB);     // 16 MB (dead after importance_kernel)
    float* bqk   = (float*)(W + 160*MB);
    float* imp   = (float*)(W + 160*MB + 64*1024);
    int*   flags = (int*)(W + 160*MB + 128*1024);
    int*   idxg  = (int*)(W + 160*MB + 192*1024);
    // wi1 hi/lo live inside the (not yet written) QKV region
    short* Wi_hi = (short*)(W + 32*MB);      // 1 MB
    short* Wi_lo = (short*)(W + 33*MB);      // 1 MB
    // Kg/Vg overwrite Hw (dead after importance); 5.25 MB each
    short* Kg = (short*)(W + 144*MB);
    short* Vg = (short*)(W + 150*MB);
    // attn output hi/lo overwrite x_hi/x_lo (dead after projections)
    short* AO_hi = x_hi;
    short* AO_lo = x_lo;

    const size_t NM = (size_t)MTOT * DD;

    // 0. splits + fused bias
    split_convert<<<(NM/4 + 255)/256, 256, 0, stream>>>(x, x_hi, x_lo, NM/4);
    split_convert<<<(DD*DD/4 + 255)/256, 256, 0, stream>>>(wq, Bqk_hi,         dead_lo,          DD*DD/4);
    split_convert<<<(DD*DD/4 + 255)/256, 256, 0, stream>>>(wk, Bqk_hi + DD*DD, dead_lo + DD*DD,  DD*DD/4);
    split_convert<<<(DD*DD/4 + 255)/256, 256, 0, stream>>>(wv, Bv_hi, Bv_lo, DD*DD/4);
    split_convert<<<(DD*DD/4 + 255)/256, 256, 0, stream>>>(wo, wo_hi, wo_lo, DD*DD/4);
    split_convert<<<(DH*DD/4 + 255)/256, 256, 0, stream>>>(wi1, Wi_hi, Wi_lo, DH*DD/4);
    concat_bias<<<2048/256, 256, 0, stream>>>(bq, bk, bqk);

    // 1. indexer h = relu(x @ wi1^T + bi1)  -- 3-term split
    gemm_split<true><<<dim3(DH/128, MTOT/128), 256, 0, stream>>>(
        x_hi, x_lo, Wi_hi, Wi_lo, bi1, Hw, MTOT, DH, DD, DH);
    // 2-3. importance + top-k
    importance_kernel<<<MTOT/4, 256, 0, stream>>>(Hw, wi2, bi2, imp);
    rank_kernel<<<dim3(SS/256, BB), 256, 0, stream>>>(imp, flags);
    compact_kernel<<<BB, 256, 0, stream>>>(flags, idxg);

    // 4a. Q,K projection: pure bf16 (softmax-damped) -> QKV cols 0..2047
    gemm_bf16<<<dim3(2048/128, MTOT/128), 256, 0, stream>>>(
        x_hi, Bqk_hi, bqk, QKV, MTOT, 2048, DD, QKVS);
    // 4b. V projection: 3-term split (linear path) -> QKV cols 2048..3071
    gemm_split<false><<<dim3(DD/128, MTOT/128), 256, 0, stream>>>(
        x_hi, x_lo, Bv_hi, Bv_lo, bv, QKV + 2048, MTOT, DD, DD, QKVS);

    // 4c. one-shot gather K/V -> bf16 (Hw region now dead)
    gather_kv<<<dim3(NCH, HHD, BB), 256, 0, stream>>>(QKV, idxg, Kg, Vg);

    // 5. barrier-free MFMA sparse flash attention -> bf16 hi/lo directly
    attn_mfma<<<dim3(SS/64, HHD, BB), 256, 0, stream>>>(QKV, Kg, Vg, AO_hi, AO_lo);

    // 6. output projection (3-term split: linear path)
    gemm_split<false><<<dim3(DD/128, MTOT/128), 256, 0, stream>>>(
        AO_hi, AO_lo, wo_hi, wo_lo, bo, out, MTOT, DD, DD, DD);
}

// Round 7
// 419.626 us; speedup vs baseline: 1.1661x; 1.1661x over previous
//
#include <hip/hip_runtime.h>
#include <math.h>

#define BB 4
#define SS 2048
#define DD 1024
#define HHD 16      // heads
#define HD 64       // head dim
#define DH 512      // indexer hidden
#define KSEL 614    // top-k count
#define KPAD 640    // padded to multiple of 64
#define MTOT (BB*SS)
#define QKVS 3072   // fused QKV row stride
#define NCH (KPAD/64)

typedef __attribute__((ext_vector_type(8))) short bf16x8;
typedef __attribute__((ext_vector_type(4))) float f32x4;

#define LDS_CAST(p) ((__attribute__((address_space(3))) void*)(p))
#define GLB_CAST(p) ((const __attribute__((address_space(1))) void*)(p))

// ---------------- fp32 -> bf16 helpers (RNE)
__device__ inline short bf16rne(float v)
{
    unsigned u = __builtin_bit_cast(unsigned, v);
    return (short)((u + 0x7FFFu + ((u >> 16) & 1u)) >> 16);
}

__device__ inline void split1(float v, short& h, short& l)
{
    unsigned u = __builtin_bit_cast(unsigned, v);
    unsigned hr = (u + 0x7FFFu + ((u >> 16) & 1u)) >> 16;
    h = (short)hr;
    float hf = __builtin_bit_cast(float, hr << 16);
    float res = v - hf;
    unsigned u2 = __builtin_bit_cast(unsigned, res);
    unsigned lr = (u2 + 0x7FFFu + ((u2 >> 16) & 1u)) >> 16;
    l = (short)lr;
}

__device__ inline bf16x8 pack8(float4 a, float4 b)
{
    bf16x8 o;
    o[0]=bf16rne(a.x); o[1]=bf16rne(a.y); o[2]=bf16rne(a.z); o[3]=bf16rne(a.w);
    o[4]=bf16rne(b.x); o[5]=bf16rne(b.y); o[6]=bf16rne(b.z); o[7]=bf16rne(b.w);
    return o;
}

__global__ __launch_bounds__(256)
void split_convert(const float* __restrict__ in, short* __restrict__ hi,
                   short* __restrict__ lo, int n4)
{
    const int i = blockIdx.x * 256 + threadIdx.x;
    if (i >= n4) return;
    float4 v = reinterpret_cast<const float4*>(in)[i];
    short4 h, l;
    split1(v.x, h.x, l.x);
    split1(v.y, h.y, l.y);
    split1(v.z, h.z, l.z);
    split1(v.w, h.w, l.w);
    reinterpret_cast<short4*>(hi)[i] = h;
    reinterpret_cast<short4*>(lo)[i] = l;
}

__global__ __launch_bounds__(256)
void concat_bias(const float* __restrict__ a, const float* __restrict__ b,
                 float* __restrict__ o)
{
    const int i = blockIdx.x * 256 + threadIdx.x;   // 2048
    o[i] = (i < 1024) ? a[i] : b[i - 1024];
}

// ---------------- plain bf16 MFMA GEMM: C[M,N] = Ahi @ Bhi^T + bias  (m97 structure)
__global__ __launch_bounds__(256)
void gemm_bf16(const short* __restrict__ Ahi, const short* __restrict__ Bhi,
               const float* __restrict__ bias, float* __restrict__ C,
               int M, int N, int K, int ldc)
{
    __shared__ short sAh[128*32];
    __shared__ short sBh[128*32];

    const int t = threadIdx.x;
    const int lane = t & 63, wid = t >> 6;
    const int wm = wid >> 1, wn = wid & 1;
    const int row0 = blockIdx.y * 128, col0 = blockIdx.x * 128;
    const int g = lane >> 4, r = lane & 15;
    const int sw = g ^ ((lane >> 2) & 3);
    const int srow = lane >> 2;
    const int sslot = lane & 3;

    f32x4 acc[4][4];
    #pragma unroll
    for (int mt = 0; mt < 4; ++mt)
        #pragma unroll
        for (int nt = 0; nt < 4; ++nt) acc[mt][nt] = (f32x4){0.f, 0.f, 0.f, 0.f};

    for (int k0 = 0; k0 < K; k0 += 32) {
        #pragma unroll
        for (int i = 0; i < 2; ++i) {
            const int rl = wid * 32 + i * 16 + srow;
            const int scol = k0 + ((sslot ^ ((rl >> 2) & 3)) << 3);
            const size_t ga = (size_t)(row0 + rl) * K + scol;
            const size_t gb = (size_t)(col0 + rl) * K + scol;
            const int ldso = (wid * 32 + i * 16) * 32;
            __builtin_amdgcn_global_load_lds(GLB_CAST(Ahi + ga), LDS_CAST(sAh + ldso), 16, 0, 0);
            __builtin_amdgcn_global_load_lds(GLB_CAST(Bhi + gb), LDS_CAST(sBh + ldso), 16, 0, 0);
        }
        __syncthreads();

        bf16x8 ah[4], bh[4];
        #pragma unroll
        for (int mt = 0; mt < 4; ++mt)
            ah[mt] = *reinterpret_cast<const bf16x8*>(sAh + (wm * 64 + mt * 16 + r) * 32 + sw * 8);
        #pragma unroll
        for (int nt = 0; nt < 4; ++nt)
            bh[nt] = *reinterpret_cast<const bf16x8*>(sBh + (wn * 64 + nt * 16 + r) * 32 + sw * 8);
        #pragma unroll
        for (int mt = 0; mt < 4; ++mt)
            #pragma unroll
            for (int nt = 0; nt < 4; ++nt)
                acc[mt][nt] = __builtin_amdgcn_mfma_f32_16x16x32_bf16(ah[mt], bh[nt], acc[mt][nt], 0, 0, 0);
        __syncthreads();
    }

    #pragma unroll
    for (int nt = 0; nt < 4; ++nt) {
        const int col = wn * 64 + nt * 16 + r;
        const float bv = bias[col0 + col];
        #pragma unroll
        for (int mt = 0; mt < 4; ++mt) {
            #pragma unroll
            for (int e = 0; e < 4; ++e) {
                const int row = row0 + wm * 64 + mt * 16 + 4 * g + e;
                C[(size_t)row * ldc + col0 + col] = acc[mt][nt][e] + bv;
            }
        }
    }
}

// ---------------- split-bf16 MFMA GEMM (3-term): C = (Ahi+Alo)@(Bhi+Blo)^T + bias
template<bool RELU>
__global__ __launch_bounds__(256)
void gemm_split(const short* __restrict__ Ahi, const short* __restrict__ Alo,
                const short* __restrict__ Bhi, const short* __restrict__ Blo,
                const float* __restrict__ bias, float* __restrict__ C,
                int M, int N, int K, int ldc)
{
    __shared__ short sAh[128*32];
    __shared__ short sAl[128*32];
    __shared__ short sBh[128*32];
    __shared__ short sBl[128*32];

    const int t = threadIdx.x;
    const int lane = t & 63, wid = t >> 6;
    const int wm = wid >> 1, wn = wid & 1;
    const int row0 = blockIdx.y * 128, col0 = blockIdx.x * 128;
    const int g = lane >> 4, r = lane & 15;
    const int sw = g ^ ((lane >> 2) & 3);
    const int srow = lane >> 2;
    const int sslot = lane & 3;

    f32x4 acc[4][4];
    #pragma unroll
    for (int mt = 0; mt < 4; ++mt)
        #pragma unroll
        for (int nt = 0; nt < 4; ++nt) acc[mt][nt] = (f32x4){0.f, 0.f, 0.f, 0.f};

    for (int k0 = 0; k0 < K; k0 += 32) {
        #pragma unroll
        for (int i = 0; i < 2; ++i) {
            const int rl = wid * 32 + i * 16 + srow;
            const int scol = k0 + ((sslot ^ ((rl >> 2) & 3)) << 3);
            const size_t ga = (size_t)(row0 + rl) * K + scol;
            const size_t gb = (size_t)(col0 + rl) * K + scol;
            const int ldso = (wid * 32 + i * 16) * 32;
            __builtin_amdgcn_global_load_lds(GLB_CAST(Ahi + ga), LDS_CAST(sAh + ldso), 16, 0, 0);
            __builtin_amdgcn_global_load_lds(GLB_CAST(Alo + ga), LDS_CAST(sAl + ldso), 16, 0, 0);
            __builtin_amdgcn_global_load_lds(GLB_CAST(Bhi + gb), LDS_CAST(sBh + ldso), 16, 0, 0);
            __builtin_amdgcn_global_load_lds(GLB_CAST(Blo + gb), LDS_CAST(sBl + ldso), 16, 0, 0);
        }
        __syncthreads();

        bf16x8 ah[4], al[4], bh[4], bl[4];
        #pragma unroll
        for (int mt = 0; mt < 4; ++mt) {
            const int row = wm * 64 + mt * 16 + r;
            ah[mt] = *reinterpret_cast<const bf16x8*>(sAh + row * 32 + sw * 8);
            al[mt] = *reinterpret_cast<const bf16x8*>(sAl + row * 32 + sw * 8);
        }
        #pragma unroll
        for (int nt = 0; nt < 4; ++nt) {
            const int row = wn * 64 + nt * 16 + r;
            bh[nt] = *reinterpret_cast<const bf16x8*>(sBh + row * 32 + sw * 8);
            bl[nt] = *reinterpret_cast<const bf16x8*>(sBl + row * 32 + sw * 8);
        }
        #pragma unroll
        for (int mt = 0; mt < 4; ++mt)
            #pragma unroll
            for (int nt = 0; nt < 4; ++nt) {
                acc[mt][nt] = __builtin_amdgcn_mfma_f32_16x16x32_bf16(ah[mt], bh[nt], acc[mt][nt], 0, 0, 0);
                acc[mt][nt] = __builtin_amdgcn_mfma_f32_16x16x32_bf16(ah[mt], bl[nt], acc[mt][nt], 0, 0, 0);
                acc[mt][nt] = __builtin_amdgcn_mfma_f32_16x16x32_bf16(al[mt], bh[nt], acc[mt][nt], 0, 0, 0);
            }
        __syncthreads();
    }

    #pragma unroll
    for (int nt = 0; nt < 4; ++nt) {
        const int col = wn * 64 + nt * 16 + r;
        const float bv = bias[col0 + col];
        #pragma unroll
        for (int mt = 0; mt < 4; ++mt) {
            #pragma unroll
            for (int e = 0; e < 4; ++e) {
                const int row = row0 + wm * 64 + mt * 16 + 4 * g + e;
                float v = acc[mt][nt][e] + bv;
                if (RELU) v = fmaxf(v, 0.f);
                C[(size_t)row * ldc + col0 + col] = v;
            }
        }
    }
}

// ---------------- importance / top-k
__global__ __launch_bounds__(256)
void importance_kernel(const float* __restrict__ h, const float* __restrict__ wi2,
                       const float* __restrict__ bi2, float* __restrict__ imp)
{
    const int wid = threadIdx.x >> 6, lane = threadIdx.x & 63;
    const int row = blockIdx.x * 4 + wid;
    const float* hr = h + (size_t)row * DH;
    float s = 0.f;
    #pragma unroll
    for (int i = 0; i < DH/64; ++i)
        s = fmaf(hr[lane + i*64], wi2[lane + i*64], s);
    #pragma unroll
    for (int off = 32; off; off >>= 1) s += __shfl_down(s, off);
    if (lane == 0) imp[row] = s + bi2[0];
}

__global__ __launch_bounds__(256)
void rank_kernel(const float* __restrict__ imp, int* __restrict__ flags)
{
    const int b = blockIdx.y;
    const int i = blockIdx.x * 256 + threadIdx.x;
    const float* bimp = imp + b * SS;
    const float v = bimp[i];
    int rank = 0;
    for (int j = 0; j < SS; ++j) {
        const float u = bimp[j];
        rank += (u > v) || ((u == v) && (j < i));
    }
    flags[b * SS + i] = (rank < KSEL) ? 1 : 0;
}

__global__ __launch_bounds__(256)
void compact_kernel(const int* __restrict__ flags, int* __restrict__ idxg)
{
    __shared__ int sscan[SS];
    __shared__ int sidx[KSEL];
    const int b = blockIdx.x, t = threadIdx.x;
    for (int i = t; i < SS; i += 256) sscan[i] = flags[b * SS + i];
    __syncthreads();
    for (int off = 1; off < SS; off <<= 1) {
        int vals[SS/256];
        #pragma unroll
        for (int c = 0; c < SS/256; ++c) {
            const int i = t + c * 256;
            int v = sscan[i];
            if (i >= off) v += sscan[i - off];
            vals[c] = v;
        }
        __syncthreads();
        #pragma unroll
        for (int c = 0; c < SS/256; ++c) sscan[t + c * 256] = vals[c];
        __syncthreads();
    }
    for (int i = t; i < SS; i += 256) {
        const int f = flags[b * SS + i];
        if (f) sidx[sscan[i] - 1] = i;
    }
    __syncthreads();
    for (int p = t; p < KPAD; p += 256)
        idxg[b * KPAD + p] = sidx[min(p, KSEL - 1)];
}

// ---------------- one-shot K/V gather + fp32->bf16 + V transpose, CHUNK-CONTIGUOUS
// Kg[b][h][c][64 keys][64 d] bf16 (plain rows)
// Vg[b][h][c][64 d][64 keys] bf16 with key-col swizzle: key stored at key ^ (8*(d>>4))
__global__ __launch_bounds__(256)
void gather_kv(const float* __restrict__ QKV, const int* __restrict__ idxg,
               short* __restrict__ Kg, short* __restrict__ Vg)
{
    __shared__ short Vs[64*72];   // [d][key] padded
    const int t = threadIdx.x;
    const int c = blockIdx.x, h = blockIdx.y, b = blockIdx.z;
    const int srow = t >> 2;   // key (load phase) / d (store phase)
    const int sq4  = t & 3;    // 16-elem quarter

    const size_t cbase = ((size_t)(b * HHD + h) * NCH + c) * 4096;

    const int krow = idxg[b * KPAD + c * 64 + srow];
    const float* kb = QKV + (size_t)(b * SS + krow) * QKVS + 1024 + h * HD + sq4 * 16;
    float4 k0 = *reinterpret_cast<const float4*>(kb);
    float4 k1 = *reinterpret_cast<const float4*>(kb + 4);
    float4 k2 = *reinterpret_cast<const float4*>(kb + 8);
    float4 k3 = *reinterpret_cast<const float4*>(kb + 12);
    short* kout = Kg + cbase + srow * HD + sq4 * 16;
    *reinterpret_cast<bf16x8*>(kout)     = pack8(k0, k1);
    *reinterpret_cast<bf16x8*>(kout + 8) = pack8(k2, k3);

    const float* vbp = kb + 1024;
    float4 v0 = *reinterpret_cast<const float4*>(vbp);
    float4 v1 = *reinterpret_cast<const float4*>(vbp + 4);
    float4 v2 = *reinterpret_cast<const float4*>(vbp + 8);
    float4 v3 = *reinterpret_cast<const float4*>(vbp + 12);
    float vv[16] = {v0.x,v0.y,v0.z,v0.w, v1.x,v1.y,v1.z,v1.w,
                    v2.x,v2.y,v2.z,v2.w, v3.x,v3.y,v3.z,v3.w};
    #pragma unroll
    for (int j = 0; j < 16; ++j)
        Vs[(sq4 * 16 + j) * 72 + srow] = bf16rne(vv[j]);   // Vs[d][key]
    __syncthreads();

    // store phase: row d = srow, keys sq4*16..+15, swizzled by x = 8*(d>>4)
    const int x = 8 * (srow >> 4);
    short* vout = Vg + cbase + srow * 64;
    *reinterpret_cast<bf16x8*>(vout + ((sq4 * 16)     ^ x)) = *reinterpret_cast<const bf16x8*>(&Vs[srow * 72 + sq4 * 16]);
    *reinterpret_cast<bf16x8*>(vout + ((sq4 * 16 + 8) ^ x)) = *reinterpret_cast<const bf16x8*>(&Vs[srow * 72 + sq4 * 16 + 8]);
}

// ---------------- MFMA sparse flash attention: double-buffered LDS, reg-staged bf16 chunks
__global__ __launch_bounds__(256)
void attn_mfma(const float* __restrict__ QKV, const short* __restrict__ Kg,
               const short* __restrict__ Vg,
               short* __restrict__ AOhi, short* __restrict__ AOlo)
{
    __shared__ short Ks[2][64*72];
    __shared__ short Vs[2][64*72];
    __shared__ short Ps[4][16*72];

    const int t = threadIdx.x;
    const int lane = t & 63, w = t >> 6;
    const int g = lane >> 4, r = lane & 15;
    const int qt = blockIdx.x, h = blockIdx.y, b = blockIdx.z;
    const int q0 = qt * 64;
    short* Psw = &Ps[w][0];

    // staging mapping: thread t copies 32B at tile offset t*16 elems
    const int srow = t >> 2;          // tile row 0..63
    const int scol = (t & 3) * 16;    // elem col 0/16/32/48
    const short* kcbase = Kg + ((size_t)(b * HHD + h) * NCH) * 4096 + srow * 64 + scol;
    const short* vcbase = Vg + ((size_t)(b * HHD + h) * NCH) * 4096 + srow * 64 + scol;

    // Q fragments, pre-scaled by 1/8, plain bf16
    bf16x8 qh[2];
    {
        const float* qrow = QKV + (size_t)(b * SS + q0 + w * 16 + r) * QKVS + h * HD;
        #pragma unroll
        for (int ch = 0; ch < 2; ++ch) {
            float4 f0 = *reinterpret_cast<const float4*>(&qrow[ch*32 + 8*g]);
            float4 f1 = *reinterpret_cast<const float4*>(&qrow[ch*32 + 8*g + 4]);
            float v[8] = {f0.x, f0.y, f0.z, f0.w, f1.x, f1.y, f1.z, f1.w};
            #pragma unroll
            for (int e = 0; e < 8; ++e) qh[ch][e] = bf16rne(v[e] * 0.125f);
        }
    }

    f32x4 oacc[4];
    #pragma unroll
    for (int dt = 0; dt < 4; ++dt) oacc[dt] = (f32x4){0.f, 0.f, 0.f, 0.f};
    float mrun[4] = {-INFINITY, -INFINITY, -INFINITY, -INFINITY};
    float lrun[4] = {0.f, 0.f, 0.f, 0.f};

    // prologue: load chunk 0 into regs
    bf16x8 kreg0 = *reinterpret_cast<const bf16x8*>(kcbase);
    bf16x8 kreg1 = *reinterpret_cast<const bf16x8*>(kcbase + 8);
    bf16x8 vreg0 = *reinterpret_cast<const bf16x8*>(vcbase);
    bf16x8 vreg1 = *reinterpret_cast<const bf16x8*>(vcbase + 8);

    for (int c = 0; c < NCH; ++c) {
        const int cur = c & 1;
        // write staged regs -> LDS buf[cur]
        *reinterpret_cast<bf16x8*>(&Ks[cur][srow*72 + scol])     = kreg0;
        *reinterpret_cast<bf16x8*>(&Ks[cur][srow*72 + scol + 8]) = kreg1;
        *reinterpret_cast<bf16x8*>(&Vs[cur][srow*72 + scol])     = vreg0;
        *reinterpret_cast<bf16x8*>(&Vs[cur][srow*72 + scol + 8]) = vreg1;
        // issue next-chunk loads (latency hides under compute below)
        if (c + 1 < NCH) {
            const short* kn = kcbase + (size_t)(c + 1) * 4096;
            const short* vn = vcbase + (size_t)(c + 1) * 4096;
            kreg0 = *reinterpret_cast<const bf16x8*>(kn);
            kreg1 = *reinterpret_cast<const bf16x8*>(kn + 8);
            vreg0 = *reinterpret_cast<const bf16x8*>(vn);
            vreg1 = *reinterpret_cast<const bf16x8*>(vn + 8);
        }
        __syncthreads();

        // ---- QK^T from LDS
        f32x4 sa[4];
        #pragma unroll
        for (int kt = 0; kt < 4; ++kt) {
            bf16x8 kf0 = *reinterpret_cast<const bf16x8*>(&Ks[cur][(kt*16 + r)*72 + 8*g]);
            bf16x8 kf1 = *reinterpret_cast<const bf16x8*>(&Ks[cur][(kt*16 + r)*72 + 32 + 8*g]);
            f32x4 s = (f32x4){0.f, 0.f, 0.f, 0.f};
            s = __builtin_amdgcn_mfma_f32_16x16x32_bf16(qh[0], kf0, s, 0, 0, 0);
            s = __builtin_amdgcn_mfma_f32_16x16x32_bf16(qh[1], kf1, s, 0, 0, 0);
            sa[kt] = s;
        }
        if (c == NCH - 1) {
            #pragma unroll
            for (int kt = 0; kt < 4; ++kt)
                if (c*64 + kt*16 + r >= KSEL)
                    sa[kt] = (f32x4){-INFINITY, -INFINITY, -INFINITY, -INFINITY};
        }

        // ---- online softmax (rows q = 4g+e; reduce over 16-lane key groups)
        float p[4][4], scl[4];
        #pragma unroll
        for (int e = 0; e < 4; ++e) {
            float mx = fmaxf(fmaxf(sa[0][e], sa[1][e]), fmaxf(sa[2][e], sa[3][e]));
            #pragma unroll
            for (int off = 1; off < 16; off <<= 1) mx = fmaxf(mx, __shfl_xor(mx, off));
            const float mnew = fmaxf(mrun[e], mx);
            scl[e] = __expf(mrun[e] - mnew);
            float s0 = 0.f;
            #pragma unroll
            for (int kt = 0; kt < 4; ++kt) { p[kt][e] = __expf(sa[kt][e] - mnew); s0 += p[kt][e]; }
            #pragma unroll
            for (int off = 1; off < 16; off <<= 1) s0 += __shfl_xor(s0, off);
            lrun[e] = lrun[e] * scl[e] + s0;
            mrun[e] = mnew;
        }
        #pragma unroll
        for (int dt = 0; dt < 4; ++dt)
            #pragma unroll
            for (int e = 0; e < 4; ++e) oacc[dt][e] *= scl[e];

        // ---- P -> bf16 per-wave LDS transpose (in-order DS pipe within wave)
        #pragma unroll
        for (int kt = 0; kt < 4; ++kt)
            #pragma unroll
            for (int e = 0; e < 4; ++e)
                Psw[(4*g + e)*72 + ((kt*16 + r) ^ (8*g))] = bf16rne(p[kt][e]);

        // ---- PV from LDS
        #pragma unroll
        for (int kc = 0; kc < 2; ++kc) {
            bf16x8 pf = *reinterpret_cast<const bf16x8*>(&Psw[r*72 + kc*32 + 8*(g ^ (r >> 2))]);
            #pragma unroll
            for (int dt = 0; dt < 4; ++dt) {
                bf16x8 vf = *reinterpret_cast<const bf16x8*>(&Vs[cur][(dt*16 + r)*72 + kc*32 + 8*(g ^ dt)]);
                oacc[dt] = __builtin_amdgcn_mfma_f32_16x16x32_bf16(pf, vf, oacc[dt], 0, 0, 0);
            }
        }
    }

    // ---- epilogue: normalize, split hi/lo, store
    #pragma unroll
    for (int dt = 0; dt < 4; ++dt)
        #pragma unroll
        for (int e = 0; e < 4; ++e) {
            const float o = oacc[dt][e] / lrun[e];
            short hh, ll;
            split1(o, hh, ll);
            const size_t a = (size_t)(b * SS + q0 + w*16 + 4*g + e) * DD + h * HD + dt*16 + r;
            AOhi[a] = hh; AOlo[a] = ll;
        }
}

extern "C" void kernel_launch(void* const* d_in, const int* in_sizes, int n_in,
                              void* d_out, int out_size, void* d_ws, size_t ws_size,
                              hipStream_t stream)
{
    const float* x   = (const float*)d_in[0];
    const float* wq  = (const float*)d_in[1];
    const float* bq  = (const float*)d_in[2];
    const float* wk  = (const float*)d_in[3];
    const float* bk  = (const float*)d_in[4];
    const float* wv  = (const float*)d_in[5];
    const float* bv  = (const float*)d_in[6];
    const float* wo  = (const float*)d_in[7];
    const float* bo  = (const float*)d_in[8];
    const float* wi1 = (const float*)d_in[9];
    const float* bi1 = (const float*)d_in[10];
    const float* wi2 = (const float*)d_in[11];
    const float* bi2 = (const float*)d_in[12];
    float* out = (float*)d_out;

    const size_t MB = 1ull << 20;
    char* W = (char*)d_ws;
    short* x_hi  = (short*)(W + 0);          // 16 MB
    short* x_lo  = (short*)(W + 16*MB);      // 16 MB
    float* QKV   = (float*)(W + 32*MB);      // 96 MB
    short* Bqk_hi= (short*)(W + 128*MB);     // 4 MB (2048 x 1024 bf16: wq,wk)
    short* Bv_hi = (short*)(W + 132*MB);     // 2 MB
    short* Bv_lo = (short*)(W + 134*MB);     // 2 MB
    short* wo_hi = (short*)(W + 136*MB);     // 2 MB
    short* wo_lo = (short*)(W + 138*MB);     // 2 MB
    short* dead_lo = (short*)(W + 140*MB);   // 4 MB scratch for unneeded lo of wq/wk
    float* Hw    = (float*)(W + 144*MB);     // 16 MB (dead after importance_kernel)
    float* bqk   = (float*)(W + 160*MB);
    float* imp   = (float*)(W + 160*MB + 64*1024);
    int*   flags = (int*)(W + 160*MB + 128*1024);
    int*   idxg  = (int*)(W + 160*MB + 192*1024);
    // wi1 hi/lo live inside the (not yet written) QKV region
    short* Wi_hi = (short*)(W + 32*MB);      // 1 MB
    short* Wi_lo = (short*)(W + 33*MB);      // 1 MB
    // Kg/Vg overwrite Hw (dead after importance); 5.25 MB each
    short* Kg = (short*)(W + 144*MB);
    short* Vg = (short*)(W + 150*MB);
    // attn output hi/lo overwrite x_hi/x_lo (dead after projections)
    short* AO_hi = x_hi;
    short* AO_lo = x_lo;

    const size_t NM = (size_t)MTOT * DD;

    // 0. splits + fused bias
    split_convert<<<(NM/4 + 255)/256, 256, 0, stream>>>(x, x_hi, x_lo, NM/4);
    split_convert<<<(DD*DD/4 + 255)/256, 256, 0, stream>>>(wq, Bqk_hi,         dead_lo,          DD*DD/4);
    split_convert<<<(DD*DD/4 + 255)/256, 256, 0, stream>>>(wk, Bqk_hi + DD*DD, dead_lo + DD*DD,  DD*DD/4);
    split_convert<<<(DD*DD/4 + 255)/256, 256, 0, stream>>>(wv, Bv_hi, Bv_lo, DD*DD/4);
    split_convert<<<(DD*DD/4 + 255)/256, 256, 0, stream>>>(wo, wo_hi, wo_lo, DD*DD/4);
    split_convert<<<(DH*DD/4 + 255)/256, 256, 0, stream>>>(wi1, Wi_hi, Wi_lo, DH*DD/4);
    concat_bias<<<2048/256, 256, 0, stream>>>(bq, bk, bqk);

    // 1. indexer h = relu(x @ wi1^T + bi1)  -- 3-term split
    gemm_split<true><<<dim3(DH/128, MTOT/128), 256, 0, stream>>>(
        x_hi, x_lo, Wi_hi, Wi_lo, bi1, Hw, MTOT, DH, DD, DH);
    // 2-3. importance + top-k
    importance_kernel<<<MTOT/4, 256, 0, stream>>>(Hw, wi2, bi2, imp);
    rank_kernel<<<dim3(SS/256, BB), 256, 0, stream>>>(imp, flags);
    compact_kernel<<<BB, 256, 0, stream>>>(flags, idxg);

    // 4a. Q,K projection: pure bf16 (softmax-damped) -> QKV cols 0..2047
    gemm_bf16<<<dim3(2048/128, MTOT/128), 256, 0, stream>>>(
        x_hi, Bqk_hi, bqk, QKV, MTOT, 2048, DD, QKVS);
    // 4b. V projection: 3-term split (linear path) -> QKV cols 2048..3071
    gemm_split<false><<<dim3(DD/128, MTOT/128), 256, 0, stream>>>(
        x_hi, x_lo, Bv_hi, Bv_lo, bv, QKV + 2048, MTOT, DD, DD, QKVS);

    // 4c. one-shot gather K/V -> bf16 chunk-contiguous (Hw region now dead)
    gather_kv<<<dim3(NCH, HHD, BB), 256, 0, stream>>>(QKV, idxg, Kg, Vg);

    // 5. double-buffered MFMA sparse flash attention -> bf16 hi/lo directly
    attn_mfma<<<dim3(SS/64, HHD, BB), 256, 0, stream>>>(QKV, Kg, Vg, AO_hi, AO_lo);

    // 6. output projection (3-term split: linear path)
    gemm_split<false><<<dim3(DD/128, MTOT/128), 256, 0, stream>>>(
        AO_hi, AO_lo, wo_hi, wo_lo, bo, out, MTOT, DD, DD, DD);
}

// Round 8
// 382.832 us; speedup vs baseline: 1.2781x; 1.0961x over previous
//
#include <hip/hip_runtime.h>
#include <math.h>

#define BB 4
#define SS 2048
#define DD 1024
#define HHD 16      // heads
#define HD 64       // head dim
#define DH 512      // indexer hidden
#define KSEL 614    // top-k count
#define KPAD 640    // padded to multiple of 64
#define MTOT (BB*SS)
#define QKVS 3072   // fused QKV row stride
#define NCH (KPAD/64)

typedef __attribute__((ext_vector_type(8))) short bf16x8;
typedef __attribute__((ext_vector_type(4))) float f32x4;

#define LDS_CAST(p) ((__attribute__((address_space(3))) void*)(p))
#define GLB_CAST(p) ((const __attribute__((address_space(1))) void*)(p))

// ---------------- fp32 -> bf16 helpers (RNE)
__device__ inline short bf16rne(float v)
{
    unsigned u = __builtin_bit_cast(unsigned, v);
    return (short)((u + 0x7FFFu + ((u >> 16) & 1u)) >> 16);
}

__device__ inline void split1(float v, short& h, short& l)
{
    unsigned u = __builtin_bit_cast(unsigned, v);
    unsigned hr = (u + 0x7FFFu + ((u >> 16) & 1u)) >> 16;
    h = (short)hr;
    float hf = __builtin_bit_cast(float, hr << 16);
    float res = v - hf;
    unsigned u2 = __builtin_bit_cast(unsigned, res);
    unsigned lr = (u2 + 0x7FFFu + ((u2 >> 16) & 1u)) >> 16;
    l = (short)lr;
}

__device__ inline bf16x8 pack8(float4 a, float4 b)
{
    bf16x8 o;
    o[0]=bf16rne(a.x); o[1]=bf16rne(a.y); o[2]=bf16rne(a.z); o[3]=bf16rne(a.w);
    o[4]=bf16rne(b.x); o[5]=bf16rne(b.y); o[6]=bf16rne(b.z); o[7]=bf16rne(b.w);
    return o;
}

__global__ __launch_bounds__(256)
void split_convert(const float* __restrict__ in, short* __restrict__ hi,
                   short* __restrict__ lo, int n4)
{
    const int i = blockIdx.x * 256 + threadIdx.x;
    if (i >= n4) return;
    float4 v = reinterpret_cast<const float4*>(in)[i];
    short4 h, l;
    split1(v.x, h.x, l.x);
    split1(v.y, h.y, l.y);
    split1(v.z, h.z, l.z);
    split1(v.w, h.w, l.w);
    reinterpret_cast<short4*>(hi)[i] = h;
    reinterpret_cast<short4*>(lo)[i] = l;
}

// fused weight splits: y=0 wq(hi), 1 wk(hi), 2 wv(hi+lo), 3 wo(hi+lo), 4 wi1(hi+lo)
__global__ __launch_bounds__(256)
void split_weights(const float* __restrict__ wq, const float* __restrict__ wk,
                   const float* __restrict__ wv, const float* __restrict__ wo,
                   const float* __restrict__ wi1,
                   short* __restrict__ Bqk_hi,
                   short* __restrict__ Bv_hi, short* __restrict__ Bv_lo,
                   short* __restrict__ wo_hi, short* __restrict__ wo_lo,
                   short* __restrict__ Wi_hi, short* __restrict__ Wi_lo)
{
    const int i = blockIdx.x * 256 + threadIdx.x;
    const int which = blockIdx.y;
    if (which == 0) {
        float4 v = reinterpret_cast<const float4*>(wq)[i];
        short4 hh;
        hh.x = bf16rne(v.x); hh.y = bf16rne(v.y); hh.z = bf16rne(v.z); hh.w = bf16rne(v.w);
        reinterpret_cast<short4*>(Bqk_hi)[i] = hh;
    } else if (which == 1) {
        float4 v = reinterpret_cast<const float4*>(wk)[i];
        short4 hh;
        hh.x = bf16rne(v.x); hh.y = bf16rne(v.y); hh.z = bf16rne(v.z); hh.w = bf16rne(v.w);
        reinterpret_cast<short4*>(Bqk_hi + DD*DD)[i] = hh;
    } else if (which == 2) {
        float4 v = reinterpret_cast<const float4*>(wv)[i];
        short4 h, l;
        split1(v.x, h.x, l.x); split1(v.y, h.y, l.y);
        split1(v.z, h.z, l.z); split1(v.w, h.w, l.w);
        reinterpret_cast<short4*>(Bv_hi)[i] = h;
        reinterpret_cast<short4*>(Bv_lo)[i] = l;
    } else if (which == 3) {
        float4 v = reinterpret_cast<const float4*>(wo)[i];
        short4 h, l;
        split1(v.x, h.x, l.x); split1(v.y, h.y, l.y);
        split1(v.z, h.z, l.z); split1(v.w, h.w, l.w);
        reinterpret_cast<short4*>(wo_hi)[i] = h;
        reinterpret_cast<short4*>(wo_lo)[i] = l;
    } else {
        if (i >= DH*DD/4) return;
        float4 v = reinterpret_cast<const float4*>(wi1)[i];
        short4 h, l;
        split1(v.x, h.x, l.x); split1(v.y, h.y, l.y);
        split1(v.z, h.z, l.z); split1(v.w, h.w, l.w);
        reinterpret_cast<short4*>(Wi_hi)[i] = h;
        reinterpret_cast<short4*>(Wi_lo)[i] = l;
    }
}

__global__ __launch_bounds__(256)
void concat_bias(const float* __restrict__ a, const float* __restrict__ b,
                 float* __restrict__ o)
{
    const int i = blockIdx.x * 256 + threadIdx.x;   // 2048
    o[i] = (i < 1024) ? a[i] : b[i - 1024];
}

// ---------------- plain bf16 MFMA GEMM: C[M,N] = Ahi @ Bhi^T + bias  (m97 structure)
__global__ __launch_bounds__(256)
void gemm_bf16(const short* __restrict__ Ahi, const short* __restrict__ Bhi,
               const float* __restrict__ bias, float* __restrict__ C,
               int M, int N, int K, int ldc)
{
    __shared__ short sAh[128*32];
    __shared__ short sBh[128*32];

    const int t = threadIdx.x;
    const int lane = t & 63, wid = t >> 6;
    const int wm = wid >> 1, wn = wid & 1;
    const int row0 = blockIdx.y * 128, col0 = blockIdx.x * 128;
    const int g = lane >> 4, r = lane & 15;
    const int sw = g ^ ((lane >> 2) & 3);
    const int srow = lane >> 2;
    const int sslot = lane & 3;

    f32x4 acc[4][4];
    #pragma unroll
    for (int mt = 0; mt < 4; ++mt)
        #pragma unroll
        for (int nt = 0; nt < 4; ++nt) acc[mt][nt] = (f32x4){0.f, 0.f, 0.f, 0.f};

    for (int k0 = 0; k0 < K; k0 += 32) {
        #pragma unroll
        for (int i = 0; i < 2; ++i) {
            const int rl = wid * 32 + i * 16 + srow;
            const int scol = k0 + ((sslot ^ ((rl >> 2) & 3)) << 3);
            const size_t ga = (size_t)(row0 + rl) * K + scol;
            const size_t gb = (size_t)(col0 + rl) * K + scol;
            const int ldso = (wid * 32 + i * 16) * 32;
            __builtin_amdgcn_global_load_lds(GLB_CAST(Ahi + ga), LDS_CAST(sAh + ldso), 16, 0, 0);
            __builtin_amdgcn_global_load_lds(GLB_CAST(Bhi + gb), LDS_CAST(sBh + ldso), 16, 0, 0);
        }
        __syncthreads();

        bf16x8 ah[4], bh[4];
        #pragma unroll
        for (int mt = 0; mt < 4; ++mt)
            ah[mt] = *reinterpret_cast<const bf16x8*>(sAh + (wm * 64 + mt * 16 + r) * 32 + sw * 8);
        #pragma unroll
        for (int nt = 0; nt < 4; ++nt)
            bh[nt] = *reinterpret_cast<const bf16x8*>(sBh + (wn * 64 + nt * 16 + r) * 32 + sw * 8);
        #pragma unroll
        for (int mt = 0; mt < 4; ++mt)
            #pragma unroll
            for (int nt = 0; nt < 4; ++nt)
                acc[mt][nt] = __builtin_amdgcn_mfma_f32_16x16x32_bf16(ah[mt], bh[nt], acc[mt][nt], 0, 0, 0);
        __syncthreads();
    }

    #pragma unroll
    for (int nt = 0; nt < 4; ++nt) {
        const int col = wn * 64 + nt * 16 + r;
        const float bv = bias[col0 + col];
        #pragma unroll
        for (int mt = 0; mt < 4; ++mt) {
            #pragma unroll
            for (int e = 0; e < 4; ++e) {
                const int row = row0 + wm * 64 + mt * 16 + 4 * g + e;
                C[(size_t)row * ldc + col0 + col] = acc[mt][nt][e] + bv;
            }
        }
    }
}

// ---------------- split-bf16 MFMA GEMM (3-term): C = (Ahi+Alo)@(Bhi+Blo)^T + bias
template<bool RELU>
__global__ __launch_bounds__(256)
void gemm_split(const short* __restrict__ Ahi, const short* __restrict__ Alo,
                const short* __restrict__ Bhi, const short* __restrict__ Blo,
                const float* __restrict__ bias, float* __restrict__ C,
                int M, int N, int K, int ldc)
{
    __shared__ short sAh[128*32];
    __shared__ short sAl[128*32];
    __shared__ short sBh[128*32];
    __shared__ short sBl[128*32];

    const int t = threadIdx.x;
    const int lane = t & 63, wid = t >> 6;
    const int wm = wid >> 1, wn = wid & 1;
    const int row0 = blockIdx.y * 128, col0 = blockIdx.x * 128;
    const int g = lane >> 4, r = lane & 15;
    const int sw = g ^ ((lane >> 2) & 3);
    const int srow = lane >> 2;
    const int sslot = lane & 3;

    f32x4 acc[4][4];
    #pragma unroll
    for (int mt = 0; mt < 4; ++mt)
        #pragma unroll
        for (int nt = 0; nt < 4; ++nt) acc[mt][nt] = (f32x4){0.f, 0.f, 0.f, 0.f};

    for (int k0 = 0; k0 < K; k0 += 32) {
        #pragma unroll
        for (int i = 0; i < 2; ++i) {
            const int rl = wid * 32 + i * 16 + srow;
            const int scol = k0 + ((sslot ^ ((rl >> 2) & 3)) << 3);
            const size_t ga = (size_t)(row0 + rl) * K + scol;
            const size_t gb = (size_t)(col0 + rl) * K + scol;
            const int ldso = (wid * 32 + i * 16) * 32;
            __builtin_amdgcn_global_load_lds(GLB_CAST(Ahi + ga), LDS_CAST(sAh + ldso), 16, 0, 0);
            __builtin_amdgcn_global_load_lds(GLB_CAST(Alo + ga), LDS_CAST(sAl + ldso), 16, 0, 0);
            __builtin_amdgcn_global_load_lds(GLB_CAST(Bhi + gb), LDS_CAST(sBh + ldso), 16, 0, 0);
            __builtin_amdgcn_global_load_lds(GLB_CAST(Blo + gb), LDS_CAST(sBl + ldso), 16, 0, 0);
        }
        __syncthreads();

        bf16x8 ah[4], al[4], bh[4], bl[4];
        #pragma unroll
        for (int mt = 0; mt < 4; ++mt) {
            const int row = wm * 64 + mt * 16 + r;
            ah[mt] = *reinterpret_cast<const bf16x8*>(sAh + row * 32 + sw * 8);
            al[mt] = *reinterpret_cast<const bf16x8*>(sAl + row * 32 + sw * 8);
        }
        #pragma unroll
        for (int nt = 0; nt < 4; ++nt) {
            const int row = wn * 64 + nt * 16 + r;
            bh[nt] = *reinterpret_cast<const bf16x8*>(sBh + row * 32 + sw * 8);
            bl[nt] = *reinterpret_cast<const bf16x8*>(sBl + row * 32 + sw * 8);
        }
        #pragma unroll
        for (int mt = 0; mt < 4; ++mt)
            #pragma unroll
            for (int nt = 0; nt < 4; ++nt) {
                acc[mt][nt] = __builtin_amdgcn_mfma_f32_16x16x32_bf16(ah[mt], bh[nt], acc[mt][nt], 0, 0, 0);
                acc[mt][nt] = __builtin_amdgcn_mfma_f32_16x16x32_bf16(ah[mt], bl[nt], acc[mt][nt], 0, 0, 0);
                acc[mt][nt] = __builtin_amdgcn_mfma_f32_16x16x32_bf16(al[mt], bh[nt], acc[mt][nt], 0, 0, 0);
            }
        __syncthreads();
    }

    #pragma unroll
    for (int nt = 0; nt < 4; ++nt) {
        const int col = wn * 64 + nt * 16 + r;
        const float bv = bias[col0 + col];
        #pragma unroll
        for (int mt = 0; mt < 4; ++mt) {
            #pragma unroll
            for (int e = 0; e < 4; ++e) {
                const int row = row0 + wm * 64 + mt * 16 + 4 * g + e;
                float v = acc[mt][nt][e] + bv;
                if (RELU) v = fmaxf(v, 0.f);
                C[(size_t)row * ldc + col0 + col] = v;
            }
        }
    }
}

// ---------------- importance / top-k
__global__ __launch_bounds__(256)
void importance_kernel(const float* __restrict__ h, const float* __restrict__ wi2,
                       const float* __restrict__ bi2, float* __restrict__ imp)
{
    const int wid = threadIdx.x >> 6, lane = threadIdx.x & 63;
    const int row = blockIdx.x * 4 + wid;
    const float* hr = h + (size_t)row * DH;
    float s = 0.f;
    #pragma unroll
    for (int i = 0; i < DH/64; ++i)
        s = fmaf(hr[lane + i*64], wi2[lane + i*64], s);
    #pragma unroll
    for (int off = 32; off; off >>= 1) s += __shfl_down(s, off);
    if (lane == 0) imp[row] = s + bi2[0];
}

__global__ __launch_bounds__(256)
void rank_kernel(const float* __restrict__ imp, int* __restrict__ flags)
{
    const int b = blockIdx.y;
    const int i = blockIdx.x * 256 + threadIdx.x;
    const float* bimp = imp + b * SS;
    const float v = bimp[i];
    int rank = 0;
    for (int j = 0; j < SS; ++j) {
        const float u = bimp[j];
        rank += (u > v) || ((u == v) && (j < i));
    }
    flags[b * SS + i] = (rank < KSEL) ? 1 : 0;
}

__global__ __launch_bounds__(256)
void compact_kernel(const int* __restrict__ flags, int* __restrict__ idxg)
{
    __shared__ int sscan[SS];
    __shared__ int sidx[KSEL];
    const int b = blockIdx.x, t = threadIdx.x;
    for (int i = t; i < SS; i += 256) sscan[i] = flags[b * SS + i];
    __syncthreads();
    for (int off = 1; off < SS; off <<= 1) {
        int vals[SS/256];
        #pragma unroll
        for (int c = 0; c < SS/256; ++c) {
            const int i = t + c * 256;
            int v = sscan[i];
            if (i >= off) v += sscan[i - off];
            vals[c] = v;
        }
        __syncthreads();
        #pragma unroll
        for (int c = 0; c < SS/256; ++c) sscan[t + c * 256] = vals[c];
        __syncthreads();
    }
    for (int i = t; i < SS; i += 256) {
        const int f = flags[b * SS + i];
        if (f) sidx[sscan[i] - 1] = i;
    }
    __syncthreads();
    for (int p = t; p < KPAD; p += 256)
        idxg[b * KPAD + p] = sidx[min(p, KSEL - 1)];
}

// ---------------- one-shot K/V gather + fp32->bf16 + V transpose, CHUNK-CONTIGUOUS
__global__ __launch_bounds__(256)
void gather_kv(const float* __restrict__ QKV, const int* __restrict__ idxg,
               short* __restrict__ Kg, short* __restrict__ Vg)
{
    __shared__ short Vs[64*72];   // [d][key] padded
    const int t = threadIdx.x;
    const int c = blockIdx.x, h = blockIdx.y, b = blockIdx.z;
    const int srow = t >> 2;
    const int sq4  = t & 3;

    const size_t cbase = ((size_t)(b * HHD + h) * NCH + c) * 4096;

    const int krow = idxg[b * KPAD + c * 64 + srow];
    const float* kb = QKV + (size_t)(b * SS + krow) * QKVS + 1024 + h * HD + sq4 * 16;
    float4 k0 = *reinterpret_cast<const float4*>(kb);
    float4 k1 = *reinterpret_cast<const float4*>(kb + 4);
    float4 k2 = *reinterpret_cast<const float4*>(kb + 8);
    float4 k3 = *reinterpret_cast<const float4*>(kb + 12);
    short* kout = Kg + cbase + srow * HD + sq4 * 16;
    *reinterpret_cast<bf16x8*>(kout)     = pack8(k0, k1);
    *reinterpret_cast<bf16x8*>(kout + 8) = pack8(k2, k3);

    const float* vbp = kb + 1024;
    float4 v0 = *reinterpret_cast<const float4*>(vbp);
    float4 v1 = *reinterpret_cast<const float4*>(vbp + 4);
    float4 v2 = *reinterpret_cast<const float4*>(vbp + 8);
    float4 v3 = *reinterpret_cast<const float4*>(vbp + 12);
    float vv[16] = {v0.x,v0.y,v0.z,v0.w, v1.x,v1.y,v1.z,v1.w,
                    v2.x,v2.y,v2.z,v2.w, v3.x,v3.y,v3.z,v3.w};
    #pragma unroll
    for (int j = 0; j < 16; ++j)
        Vs[(sq4 * 16 + j) * 72 + srow] = bf16rne(vv[j]);
    __syncthreads();

    const int x = 8 * (srow >> 4);
    short* vout = Vg + cbase + srow * 64;
    *reinterpret_cast<bf16x8*>(vout + ((sq4 * 16)     ^ x)) = *reinterpret_cast<const bf16x8*>(&Vs[srow * 72 + sq4 * 16]);
    *reinterpret_cast<bf16x8*>(vout + ((sq4 * 16 + 8) ^ x)) = *reinterpret_cast<const bf16x8*>(&Vs[srow * 72 + sq4 * 16 + 8]);
}

// ---------------- MFMA sparse flash attention: no-max softmax (bounded scores),
// denominator via MFMA ones-column, double-buffered LDS
__global__ __launch_bounds__(256)
void attn_mfma(const float* __restrict__ QKV, const short* __restrict__ Kg,
               const short* __restrict__ Vg,
               short* __restrict__ AOhi, short* __restrict__ AOlo)
{
    __shared__ short Ks[2][64*72];
    __shared__ short Vs[2][64*72];
    __shared__ short Ps[4][16*72];

    const int t = threadIdx.x;
    const int lane = t & 63, w = t >> 6;
    const int g = lane >> 4, r = lane & 15;
    const int qt = blockIdx.x, h = blockIdx.y, b = blockIdx.z;
    const int q0 = qt * 64;
    short* Psw = &Ps[w][0];

    const int srow = t >> 2;
    const int scol = (t & 3) * 16;
    const short* kcbase = Kg + ((size_t)(b * HHD + h) * NCH) * 4096 + srow * 64 + scol;
    const short* vcbase = Vg + ((size_t)(b * HHD + h) * NCH) * 4096 + srow * 64 + scol;

    // Q fragments, pre-scaled by 1/8, plain bf16
    bf16x8 qh[2];
    {
        const float* qrow = QKV + (size_t)(b * SS + q0 + w * 16 + r) * QKVS + h * HD;
        #pragma unroll
        for (int ch = 0; ch < 2; ++ch) {
            float4 f0 = *reinterpret_cast<const float4*>(&qrow[ch*32 + 8*g]);
            float4 f1 = *reinterpret_cast<const float4*>(&qrow[ch*32 + 8*g + 4]);
            float v[8] = {f0.x, f0.y, f0.z, f0.w, f1.x, f1.y, f1.z, f1.w};
            #pragma unroll
            for (int e = 0; e < 8; ++e) qh[ch][e] = bf16rne(v[e] * 0.125f);
        }
    }

    bf16x8 ones;
    #pragma unroll
    for (int j = 0; j < 8; ++j) ones[j] = (short)0x3F80;   // bf16 1.0

    f32x4 oacc[4];
    #pragma unroll
    for (int dt = 0; dt < 4; ++dt) oacc[dt] = (f32x4){0.f, 0.f, 0.f, 0.f};
    f32x4 dacc = (f32x4){0.f, 0.f, 0.f, 0.f};

    // prologue: load chunk 0 into regs
    bf16x8 kreg0 = *reinterpret_cast<const bf16x8*>(kcbase);
    bf16x8 kreg1 = *reinterpret_cast<const bf16x8*>(kcbase + 8);
    bf16x8 vreg0 = *reinterpret_cast<const bf16x8*>(vcbase);
    bf16x8 vreg1 = *reinterpret_cast<const bf16x8*>(vcbase + 8);

    for (int c = 0; c < NCH; ++c) {
        const int cur = c & 1;
        *reinterpret_cast<bf16x8*>(&Ks[cur][srow*72 + scol])     = kreg0;
        *reinterpret_cast<bf16x8*>(&Ks[cur][srow*72 + scol + 8]) = kreg1;
        *reinterpret_cast<bf16x8*>(&Vs[cur][srow*72 + scol])     = vreg0;
        *reinterpret_cast<bf16x8*>(&Vs[cur][srow*72 + scol + 8]) = vreg1;
        if (c + 1 < NCH) {
            const short* kn = kcbase + (size_t)(c + 1) * 4096;
            const short* vn = vcbase + (size_t)(c + 1) * 4096;
            kreg0 = *reinterpret_cast<const bf16x8*>(kn);
            kreg1 = *reinterpret_cast<const bf16x8*>(kn + 8);
            vreg0 = *reinterpret_cast<const bf16x8*>(vn);
            vreg1 = *reinterpret_cast<const bf16x8*>(vn + 8);
        }
        __syncthreads();

        // ---- QK^T from LDS
        f32x4 sa[4];
        #pragma unroll
        for (int kt = 0; kt < 4; ++kt) {
            bf16x8 kf0 = *reinterpret_cast<const bf16x8*>(&Ks[cur][(kt*16 + r)*72 + 8*g]);
            bf16x8 kf1 = *reinterpret_cast<const bf16x8*>(&Ks[cur][(kt*16 + r)*72 + 32 + 8*g]);
            f32x4 s = (f32x4){0.f, 0.f, 0.f, 0.f};
            s = __builtin_amdgcn_mfma_f32_16x16x32_bf16(qh[0], kf0, s, 0, 0, 0);
            s = __builtin_amdgcn_mfma_f32_16x16x32_bf16(qh[1], kf1, s, 0, 0, 0);
            sa[kt] = s;
        }
        if (c == NCH - 1) {
            #pragma unroll
            for (int kt = 0; kt < 4; ++kt)
                if (c*64 + kt*16 + r >= KSEL)
                    sa[kt] = (f32x4){-INFINITY, -INFINITY, -INFINITY, -INFINITY};
        }

        // ---- p = exp(s) (scores bounded ~|s|<4, no max needed); bf16; transpose
        #pragma unroll
        for (int kt = 0; kt < 4; ++kt)
            #pragma unroll
            for (int e = 0; e < 4; ++e)
                Psw[(4*g + e)*72 + ((kt*16 + r) ^ (8*g))] = bf16rne(__expf(sa[kt][e]));

        // ---- PV + denominator (ones-column MFMA)
        #pragma unroll
        for (int kc = 0; kc < 2; ++kc) {
            bf16x8 pf = *reinterpret_cast<const bf16x8*>(&Psw[r*72 + kc*32 + 8*(g ^ (r >> 2))]);
            dacc = __builtin_amdgcn_mfma_f32_16x16x32_bf16(pf, ones, dacc, 0, 0, 0);
            #pragma unroll
            for (int dt = 0; dt < 4; ++dt) {
                bf16x8 vf = *reinterpret_cast<const bf16x8*>(&Vs[cur][(dt*16 + r)*72 + kc*32 + 8*(g ^ dt)]);
                oacc[dt] = __builtin_amdgcn_mfma_f32_16x16x32_bf16(pf, vf, oacc[dt], 0, 0, 0);
            }
        }
    }

    // ---- epilogue: normalize by dacc (consistent bf16 denominator), split, store
    #pragma unroll
    for (int dt = 0; dt < 4; ++dt)
        #pragma unroll
        for (int e = 0; e < 4; ++e) {
            const float o = oacc[dt][e] / dacc[e];
            short hh, ll;
            split1(o, hh, ll);
            const size_t a = (size_t)(b * SS + q0 + w*16 + 4*g + e) * DD + h * HD + dt*16 + r;
            AOhi[a] = hh; AOlo[a] = ll;
        }
}

extern "C" void kernel_launch(void* const* d_in, const int* in_sizes, int n_in,
                              void* d_out, int out_size, void* d_ws, size_t ws_size,
                              hipStream_t stream)
{
    const float* x   = (const float*)d_in[0];
    const float* wq  = (const float*)d_in[1];
    const float* bq  = (const float*)d_in[2];
    const float* wk  = (const float*)d_in[3];
    const float* bk  = (const float*)d_in[4];
    const float* wv  = (const float*)d_in[5];
    const float* bv  = (const float*)d_in[6];
    const float* wo  = (const float*)d_in[7];
    const float* bo  = (const float*)d_in[8];
    const float* wi1 = (const float*)d_in[9];
    const float* bi1 = (const float*)d_in[10];
    const float* wi2 = (const float*)d_in[11];
    const float* bi2 = (const float*)d_in[12];
    float* out = (float*)d_out;

    const size_t MB = 1ull << 20;
    char* W = (char*)d_ws;
    short* x_hi  = (short*)(W + 0);          // 16 MB
    short* x_lo  = (short*)(W + 16*MB);      // 16 MB
    float* QKV   = (float*)(W + 32*MB);      // 96 MB
    short* Bqk_hi= (short*)(W + 128*MB);     // 4 MB (2048 x 1024 bf16: wq,wk)
    short* Bv_hi = (short*)(W + 132*MB);     // 2 MB
    short* Bv_lo = (short*)(W + 134*MB);     // 2 MB
    short* wo_hi = (short*)(W + 136*MB);     // 2 MB
    short* wo_lo = (short*)(W + 138*MB);     // 2 MB
    float* Hw    = (float*)(W + 144*MB);     // 16 MB (dead after importance_kernel)
    float* bqk   = (float*)(W + 160*MB);
    float* imp   = (float*)(W + 160*MB + 64*1024);
    int*   flags = (int*)(W + 160*MB + 128*1024);
    int*   idxg  = (int*)(W + 160*MB + 192*1024);
    short* Wi_hi = (short*)(W + 32*MB);      // 1 MB (inside not-yet-written QKV)
    short* Wi_lo = (short*)(W + 33*MB);      // 1 MB
    short* Kg = (short*)(W + 144*MB);        // 5.25 MB (over dead Hw)
    short* Vg = (short*)(W + 150*MB);
    short* AO_hi = x_hi;
    short* AO_lo = x_lo;

    const size_t NM = (size_t)MTOT * DD;

    // 0. splits + fused bias
    split_convert<<<(NM/4 + 255)/256, 256, 0, stream>>>(x, x_hi, x_lo, NM/4);
    split_weights<<<dim3(DD*DD/4/256, 5), 256, 0, stream>>>(
        wq, wk, wv, wo, wi1, Bqk_hi, Bv_hi, Bv_lo, wo_hi, wo_lo, Wi_hi, Wi_lo);
    concat_bias<<<2048/256, 256, 0, stream>>>(bq, bk, bqk);

    // 1. indexer h = relu(x @ wi1^T + bi1)  -- 3-term split
    gemm_split<true><<<dim3(DH/128, MTOT/128), 256, 0, stream>>>(
        x_hi, x_lo, Wi_hi, Wi_lo, bi1, Hw, MTOT, DH, DD, DH);
    // 2-3. importance + top-k
    importance_kernel<<<MTOT/4, 256, 0, stream>>>(Hw, wi2, bi2, imp);
    rank_kernel<<<dim3(SS/256, BB), 256, 0, stream>>>(imp, flags);
    compact_kernel<<<BB, 256, 0, stream>>>(flags, idxg);

    // 4a. Q,K projection: pure bf16 -> QKV cols 0..2047
    gemm_bf16<<<dim3(2048/128, MTOT/128), 256, 0, stream>>>(
        x_hi, Bqk_hi, bqk, QKV, MTOT, 2048, DD, QKVS);
    // 4b. V projection: 3-term split -> QKV cols 2048..3071
    gemm_split<false><<<dim3(DD/128, MTOT/128), 256, 0, stream>>>(
        x_hi, x_lo, Bv_hi, Bv_lo, bv, QKV + 2048, MTOT, DD, DD, QKVS);

    // 4c. one-shot gather K/V -> bf16 chunk-contiguous (Hw region now dead)
    gather_kv<<<dim3(NCH, HHD, BB), 256, 0, stream>>>(QKV, idxg, Kg, Vg);

    // 5. no-max-softmax MFMA sparse flash attention -> bf16 hi/lo
    attn_mfma<<<dim3(SS/64, HHD, BB), 256, 0, stream>>>(QKV, Kg, Vg, AO_hi, AO_lo);

    // 6. output projection (3-term split)
    gemm_split<false><<<dim3(DD/128, MTOT/128), 256, 0, stream>>>(
        AO_hi, AO_lo, wo_hi, wo_lo, bo, out, MTOT, DD, DD, DD);
}

// Round 9
// 313.296 us; speedup vs baseline: 1.5618x; 1.2219x over previous
//
#include <hip/hip_runtime.h>
#include <math.h>

#define BB 4
#define SS 2048
#define DD 1024
#define HHD 16      // heads
#define HD 64       // head dim
#define DH 512      // indexer hidden
#define KSEL 614    // top-k count
#define KPAD 640    // padded to multiple of 64
#define MTOT (BB*SS)
#define QKVS 3072   // fused QKV row stride
#define NCH (KPAD/64)

typedef __attribute__((ext_vector_type(8))) short bf16x8;
typedef __attribute__((ext_vector_type(4))) float f32x4;

#define LDS_CAST(p) ((__attribute__((address_space(3))) void*)(p))
#define GLB_CAST(p) ((const __attribute__((address_space(1))) void*)(p))

// ---------------- fp32 -> bf16 helpers (RNE)
__device__ inline short bf16rne(float v)
{
    unsigned u = __builtin_bit_cast(unsigned, v);
    return (short)((u + 0x7FFFu + ((u >> 16) & 1u)) >> 16);
}

__device__ inline void split1(float v, short& h, short& l)
{
    unsigned u = __builtin_bit_cast(unsigned, v);
    unsigned hr = (u + 0x7FFFu + ((u >> 16) & 1u)) >> 16;
    h = (short)hr;
    float hf = __builtin_bit_cast(float, hr << 16);
    float res = v - hf;
    unsigned u2 = __builtin_bit_cast(unsigned, res);
    unsigned lr = (u2 + 0x7FFFu + ((u2 >> 16) & 1u)) >> 16;
    l = (short)lr;
}

__device__ inline bf16x8 pack8(float4 a, float4 b)
{
    bf16x8 o;
    o[0]=bf16rne(a.x); o[1]=bf16rne(a.y); o[2]=bf16rne(a.z); o[3]=bf16rne(a.w);
    o[4]=bf16rne(b.x); o[5]=bf16rne(b.y); o[6]=bf16rne(b.z); o[7]=bf16rne(b.w);
    return o;
}

__global__ __launch_bounds__(256)
void split_convert(const float* __restrict__ in, short* __restrict__ hi,
                   short* __restrict__ lo, int n4)
{
    const int i = blockIdx.x * 256 + threadIdx.x;
    if (i >= n4) return;
    float4 v = reinterpret_cast<const float4*>(in)[i];
    short4 h, l;
    split1(v.x, h.x, l.x);
    split1(v.y, h.y, l.y);
    split1(v.z, h.z, l.z);
    split1(v.w, h.w, l.w);
    reinterpret_cast<short4*>(hi)[i] = h;
    reinterpret_cast<short4*>(lo)[i] = l;
}

// fused weight splits: y=0 wq(hi), 1 wk(hi), 2 wv(hi+lo), 3 wo(hi+lo), 4 wi1(hi+lo)
__global__ __launch_bounds__(256)
void split_weights(const float* __restrict__ wq, const float* __restrict__ wk,
                   const float* __restrict__ wv, const float* __restrict__ wo,
                   const float* __restrict__ wi1,
                   short* __restrict__ Bqk_hi,
                   short* __restrict__ Bv_hi, short* __restrict__ Bv_lo,
                   short* __restrict__ wo_hi, short* __restrict__ wo_lo,
                   short* __restrict__ Wi_hi, short* __restrict__ Wi_lo)
{
    const int i = blockIdx.x * 256 + threadIdx.x;
    const int which = blockIdx.y;
    if (which == 0) {
        float4 v = reinterpret_cast<const float4*>(wq)[i];
        short4 hh;
        hh.x = bf16rne(v.x); hh.y = bf16rne(v.y); hh.z = bf16rne(v.z); hh.w = bf16rne(v.w);
        reinterpret_cast<short4*>(Bqk_hi)[i] = hh;
    } else if (which == 1) {
        float4 v = reinterpret_cast<const float4*>(wk)[i];
        short4 hh;
        hh.x = bf16rne(v.x); hh.y = bf16rne(v.y); hh.z = bf16rne(v.z); hh.w = bf16rne(v.w);
        reinterpret_cast<short4*>(Bqk_hi + DD*DD)[i] = hh;
    } else if (which == 2) {
        float4 v = reinterpret_cast<const float4*>(wv)[i];
        short4 h, l;
        split1(v.x, h.x, l.x); split1(v.y, h.y, l.y);
        split1(v.z, h.z, l.z); split1(v.w, h.w, l.w);
        reinterpret_cast<short4*>(Bv_hi)[i] = h;
        reinterpret_cast<short4*>(Bv_lo)[i] = l;
    } else if (which == 3) {
        float4 v = reinterpret_cast<const float4*>(wo)[i];
        short4 h, l;
        split1(v.x, h.x, l.x); split1(v.y, h.y, l.y);
        split1(v.z, h.z, l.z); split1(v.w, h.w, l.w);
        reinterpret_cast<short4*>(wo_hi)[i] = h;
        reinterpret_cast<short4*>(wo_lo)[i] = l;
    } else {
        if (i >= DH*DD/4) return;
        float4 v = reinterpret_cast<const float4*>(wi1)[i];
        short4 h, l;
        split1(v.x, h.x, l.x); split1(v.y, h.y, l.y);
        split1(v.z, h.z, l.z); split1(v.w, h.w, l.w);
        reinterpret_cast<short4*>(Wi_hi)[i] = h;
        reinterpret_cast<short4*>(Wi_lo)[i] = l;
    }
}

__global__ __launch_bounds__(256)
void concat_bias(const float* __restrict__ a, const float* __restrict__ b,
                 float* __restrict__ o)
{
    const int i = blockIdx.x * 256 + threadIdx.x;   // 2048
    o[i] = (i < 1024) ? a[i] : b[i - 1024];
}

// ---------------- plain bf16 MFMA GEMM: C[M,N] = Ahi @ Bhi^T + bias  (m97 structure)
__global__ __launch_bounds__(256)
void gemm_bf16(const short* __restrict__ Ahi, const short* __restrict__ Bhi,
               const float* __restrict__ bias, float* __restrict__ C,
               int M, int N, int K, int ldc)
{
    __shared__ short sAh[128*32];
    __shared__ short sBh[128*32];

    const int t = threadIdx.x;
    const int lane = t & 63, wid = t >> 6;
    const int wm = wid >> 1, wn = wid & 1;
    const int row0 = blockIdx.y * 128, col0 = blockIdx.x * 128;
    const int g = lane >> 4, r = lane & 15;
    const int sw = g ^ ((lane >> 2) & 3);
    const int srow = lane >> 2;
    const int sslot = lane & 3;

    f32x4 acc[4][4];
    #pragma unroll
    for (int mt = 0; mt < 4; ++mt)
        #pragma unroll
        for (int nt = 0; nt < 4; ++nt) acc[mt][nt] = (f32x4){0.f, 0.f, 0.f, 0.f};

    for (int k0 = 0; k0 < K; k0 += 32) {
        #pragma unroll
        for (int i = 0; i < 2; ++i) {
            const int rl = wid * 32 + i * 16 + srow;
            const int scol = k0 + ((sslot ^ ((rl >> 2) & 3)) << 3);
            const size_t ga = (size_t)(row0 + rl) * K + scol;
            const size_t gb = (size_t)(col0 + rl) * K + scol;
            const int ldso = (wid * 32 + i * 16) * 32;
            __builtin_amdgcn_global_load_lds(GLB_CAST(Ahi + ga), LDS_CAST(sAh + ldso), 16, 0, 0);
            __builtin_amdgcn_global_load_lds(GLB_CAST(Bhi + gb), LDS_CAST(sBh + ldso), 16, 0, 0);
        }
        __syncthreads();

        bf16x8 ah[4], bh[4];
        #pragma unroll
        for (int mt = 0; mt < 4; ++mt)
            ah[mt] = *reinterpret_cast<const bf16x8*>(sAh + (wm * 64 + mt * 16 + r) * 32 + sw * 8);
        #pragma unroll
        for (int nt = 0; nt < 4; ++nt)
            bh[nt] = *reinterpret_cast<const bf16x8*>(sBh + (wn * 64 + nt * 16 + r) * 32 + sw * 8);
        #pragma unroll
        for (int mt = 0; mt < 4; ++mt)
            #pragma unroll
            for (int nt = 0; nt < 4; ++nt)
                acc[mt][nt] = __builtin_amdgcn_mfma_f32_16x16x32_bf16(ah[mt], bh[nt], acc[mt][nt], 0, 0, 0);
        __syncthreads();
    }

    #pragma unroll
    for (int nt = 0; nt < 4; ++nt) {
        const int col = wn * 64 + nt * 16 + r;
        const float bv = bias[col0 + col];
        #pragma unroll
        for (int mt = 0; mt < 4; ++mt) {
            #pragma unroll
            for (int e = 0; e < 4; ++e) {
                const int row = row0 + wm * 64 + mt * 16 + 4 * g + e;
                C[(size_t)row * ldc + col0 + col] = acc[mt][nt][e] + bv;
            }
        }
    }
}

// ---------------- split-bf16 MFMA GEMM (3-term): C = (Ahi+Alo)@(Bhi+Blo)^T + bias
template<bool RELU>
__global__ __launch_bounds__(256)
void gemm_split(const short* __restrict__ Ahi, const short* __restrict__ Alo,
                const short* __restrict__ Bhi, const short* __restrict__ Blo,
                const float* __restrict__ bias, float* __restrict__ C,
                int M, int N, int K, int ldc)
{
    __shared__ short sAh[128*32];
    __shared__ short sAl[128*32];
    __shared__ short sBh[128*32];
    __shared__ short sBl[128*32];

    const int t = threadIdx.x;
    const int lane = t & 63, wid = t >> 6;
    const int wm = wid >> 1, wn = wid & 1;
    const int row0 = blockIdx.y * 128, col0 = blockIdx.x * 128;
    const int g = lane >> 4, r = lane & 15;
    const int sw = g ^ ((lane >> 2) & 3);
    const int srow = lane >> 2;
    const int sslot = lane & 3;

    f32x4 acc[4][4];
    #pragma unroll
    for (int mt = 0; mt < 4; ++mt)
        #pragma unroll
        for (int nt = 0; nt < 4; ++nt) acc[mt][nt] = (f32x4){0.f, 0.f, 0.f, 0.f};

    for (int k0 = 0; k0 < K; k0 += 32) {
        #pragma unroll
        for (int i = 0; i < 2; ++i) {
            const int rl = wid * 32 + i * 16 + srow;
            const int scol = k0 + ((sslot ^ ((rl >> 2) & 3)) << 3);
            const size_t ga = (size_t)(row0 + rl) * K + scol;
            const size_t gb = (size_t)(col0 + rl) * K + scol;
            const int ldso = (wid * 32 + i * 16) * 32;
            __builtin_amdgcn_global_load_lds(GLB_CAST(Ahi + ga), LDS_CAST(sAh + ldso), 16, 0, 0);
            __builtin_amdgcn_global_load_lds(GLB_CAST(Alo + ga), LDS_CAST(sAl + ldso), 16, 0, 0);
            __builtin_amdgcn_global_load_lds(GLB_CAST(Bhi + gb), LDS_CAST(sBh + ldso), 16, 0, 0);
            __builtin_amdgcn_global_load_lds(GLB_CAST(Blo + gb), LDS_CAST(sBl + ldso), 16, 0, 0);
        }
        __syncthreads();

        bf16x8 ah[4], al[4], bh[4], bl[4];
        #pragma unroll
        for (int mt = 0; mt < 4; ++mt) {
            const int row = wm * 64 + mt * 16 + r;
            ah[mt] = *reinterpret_cast<const bf16x8*>(sAh + row * 32 + sw * 8);
            al[mt] = *reinterpret_cast<const bf16x8*>(sAl + row * 32 + sw * 8);
        }
        #pragma unroll
        for (int nt = 0; nt < 4; ++nt) {
            const int row = wn * 64 + nt * 16 + r;
            bh[nt] = *reinterpret_cast<const bf16x8*>(sBh + row * 32 + sw * 8);
            bl[nt] = *reinterpret_cast<const bf16x8*>(sBl + row * 32 + sw * 8);
        }
        #pragma unroll
        for (int mt = 0; mt < 4; ++mt)
            #pragma unroll
            for (int nt = 0; nt < 4; ++nt) {
                acc[mt][nt] = __builtin_amdgcn_mfma_f32_16x16x32_bf16(ah[mt], bh[nt], acc[mt][nt], 0, 0, 0);
                acc[mt][nt] = __builtin_amdgcn_mfma_f32_16x16x32_bf16(ah[mt], bl[nt], acc[mt][nt], 0, 0, 0);
                acc[mt][nt] = __builtin_amdgcn_mfma_f32_16x16x32_bf16(al[mt], bh[nt], acc[mt][nt], 0, 0, 0);
            }
        __syncthreads();
    }

    #pragma unroll
    for (int nt = 0; nt < 4; ++nt) {
        const int col = wn * 64 + nt * 16 + r;
        const float bv = bias[col0 + col];
        #pragma unroll
        for (int mt = 0; mt < 4; ++mt) {
            #pragma unroll
            for (int e = 0; e < 4; ++e) {
                const int row = row0 + wm * 64 + mt * 16 + 4 * g + e;
                float v = acc[mt][nt][e] + bv;
                if (RELU) v = fmaxf(v, 0.f);
                C[(size_t)row * ldc + col0 + col] = v;
            }
        }
    }
}

// ---------------- importance / top-k
__global__ __launch_bounds__(256)
void importance_kernel(const float* __restrict__ h, const float* __restrict__ wi2,
                       const float* __restrict__ bi2, float* __restrict__ imp)
{
    const int wid = threadIdx.x >> 6, lane = threadIdx.x & 63;
    const int row = blockIdx.x * 4 + wid;
    const float* hr = h + (size_t)row * DH;
    float s = 0.f;
    #pragma unroll
    for (int i = 0; i < DH/64; ++i)
        s = fmaf(hr[lane + i*64], wi2[lane + i*64], s);
    #pragma unroll
    for (int off = 32; off; off >>= 1) s += __shfl_down(s, off);
    if (lane == 0) imp[row] = s + bi2[0];
}

// top-k rank: LDS-staged, 8 threads per position, exact lax.top_k tie-break
__global__ __launch_bounds__(256)
void rank_kernel(const float* __restrict__ imp, int* __restrict__ flags)
{
    __shared__ float simp[SS];
    const int b = blockIdx.y;
    const int t = threadIdx.x;
    const float* bimp = imp + b * SS;
    for (int i = t; i < SS/4; i += 256)
        reinterpret_cast<float4*>(simp)[i] = reinterpret_cast<const float4*>(bimp)[i];
    __syncthreads();

    const int i = blockIdx.x * 32 + (t >> 3);   // position
    const int part = t & 7;                     // slice 0..7
    const float v = simp[i];
    const float4* slice = reinterpret_cast<const float4*>(simp + part * (SS/8));
    const int jb = part * (SS/8);
    int rank = 0;
    #pragma unroll 8
    for (int jj = 0; jj < SS/32; ++jj) {        // 64 float4 iterations
        const float4 u4 = slice[jj];
        const int j = jb + jj * 4;
        rank += (u4.x > v) || ((u4.x == v) && (j + 0 < i));
        rank += (u4.y > v) || ((u4.y == v) && (j + 1 < i));
        rank += (u4.z > v) || ((u4.z == v) && (j + 2 < i));
        rank += (u4.w > v) || ((u4.w == v) && (j + 3 < i));
    }
    rank += __shfl_xor(rank, 1);
    rank += __shfl_xor(rank, 2);
    rank += __shfl_xor(rank, 4);
    if (part == 0) flags[b * SS + i] = (rank < KSEL) ? 1 : 0;
}

__global__ __launch_bounds__(256)
void compact_kernel(const int* __restrict__ flags, int* __restrict__ idxg)
{
    __shared__ int sscan[SS];
    __shared__ int sidx[KSEL];
    const int b = blockIdx.x, t = threadIdx.x;
    for (int i = t; i < SS; i += 256) sscan[i] = flags[b * SS + i];
    __syncthreads();
    for (int off = 1; off < SS; off <<= 1) {
        int vals[SS/256];
        #pragma unroll
        for (int c = 0; c < SS/256; ++c) {
            const int i = t + c * 256;
            int v = sscan[i];
            if (i >= off) v += sscan[i - off];
            vals[c] = v;
        }
        __syncthreads();
        #pragma unroll
        for (int c = 0; c < SS/256; ++c) sscan[t + c * 256] = vals[c];
        __syncthreads();
    }
    for (int i = t; i < SS; i += 256) {
        const int f = flags[b * SS + i];
        if (f) sidx[sscan[i] - 1] = i;
    }
    __syncthreads();
    for (int p = t; p < KPAD; p += 256)
        idxg[b * KPAD + p] = sidx[min(p, KSEL - 1)];
}

// ---------------- one-shot K/V gather + fp32->bf16 + V transpose, CHUNK-CONTIGUOUS
__global__ __launch_bounds__(256)
void gather_kv(const float* __restrict__ QKV, const int* __restrict__ idxg,
               short* __restrict__ Kg, short* __restrict__ Vg)
{
    __shared__ short Vs[64*72];   // [d][key] padded
    const int t = threadIdx.x;
    const int c = blockIdx.x, h = blockIdx.y, b = blockIdx.z;
    const int srow = t >> 2;
    const int sq4  = t & 3;

    const size_t cbase = ((size_t)(b * HHD + h) * NCH + c) * 4096;

    const int krow = idxg[b * KPAD + c * 64 + srow];
    const float* kb = QKV + (size_t)(b * SS + krow) * QKVS + 1024 + h * HD + sq4 * 16;
    float4 k0 = *reinterpret_cast<const float4*>(kb);
    float4 k1 = *reinterpret_cast<const float4*>(kb + 4);
    float4 k2 = *reinterpret_cast<const float4*>(kb + 8);
    float4 k3 = *reinterpret_cast<const float4*>(kb + 12);
    short* kout = Kg + cbase + srow * HD + sq4 * 16;
    *reinterpret_cast<bf16x8*>(kout)     = pack8(k0, k1);
    *reinterpret_cast<bf16x8*>(kout + 8) = pack8(k2, k3);

    const float* vbp = kb + 1024;
    float4 v0 = *reinterpret_cast<const float4*>(vbp);
    float4 v1 = *reinterpret_cast<const float4*>(vbp + 4);
    float4 v2 = *reinterpret_cast<const float4*>(vbp + 8);
    float4 v3 = *reinterpret_cast<const float4*>(vbp + 12);
    float vv[16] = {v0.x,v0.y,v0.z,v0.w, v1.x,v1.y,v1.z,v1.w,
                    v2.x,v2.y,v2.z,v2.w, v3.x,v3.y,v3.z,v3.w};
    #pragma unroll
    for (int j = 0; j < 16; ++j)
        Vs[(sq4 * 16 + j) * 72 + srow] = bf16rne(vv[j]);
    __syncthreads();

    const int x = 8 * (srow >> 4);
    short* vout = Vg + cbase + srow * 64;
    *reinterpret_cast<bf16x8*>(vout + ((sq4 * 16)     ^ x)) = *reinterpret_cast<const bf16x8*>(&Vs[srow * 72 + sq4 * 16]);
    *reinterpret_cast<bf16x8*>(vout + ((sq4 * 16 + 8) ^ x)) = *reinterpret_cast<const bf16x8*>(&Vs[srow * 72 + sq4 * 16 + 8]);
}

// ---------------- MFMA sparse flash attention: no-max softmax (bounded scores),
// denominator via MFMA ones-column, double-buffered LDS
__global__ __launch_bounds__(256)
void attn_mfma(const float* __restrict__ QKV, const short* __restrict__ Kg,
               const short* __restrict__ Vg,
               short* __restrict__ AOhi, short* __restrict__ AOlo)
{
    __shared__ short Ks[2][64*72];
    __shared__ short Vs[2][64*72];
    __shared__ short Ps[4][16*72];

    const int t = threadIdx.x;
    const int lane = t & 63, w = t >> 6;
    const int g = lane >> 4, r = lane & 15;
    const int qt = blockIdx.x, h = blockIdx.y, b = blockIdx.z;
    const int q0 = qt * 64;
    short* Psw = &Ps[w][0];

    const int srow = t >> 2;
    const int scol = (t & 3) * 16;
    const short* kcbase = Kg + ((size_t)(b * HHD + h) * NCH) * 4096 + srow * 64 + scol;
    const short* vcbase = Vg + ((size_t)(b * HHD + h) * NCH) * 4096 + srow * 64 + scol;

    // Q fragments, pre-scaled by 1/8, plain bf16
    bf16x8 qh[2];
    {
        const float* qrow = QKV + (size_t)(b * SS + q0 + w * 16 + r) * QKVS + h * HD;
        #pragma unroll
        for (int ch = 0; ch < 2; ++ch) {
            float4 f0 = *reinterpret_cast<const float4*>(&qrow[ch*32 + 8*g]);
            float4 f1 = *reinterpret_cast<const float4*>(&qrow[ch*32 + 8*g + 4]);
            float v[8] = {f0.x, f0.y, f0.z, f0.w, f1.x, f1.y, f1.z, f1.w};
            #pragma unroll
            for (int e = 0; e < 8; ++e) qh[ch][e] = bf16rne(v[e] * 0.125f);
        }
    }

    bf16x8 ones;
    #pragma unroll
    for (int j = 0; j < 8; ++j) ones[j] = (short)0x3F80;   // bf16 1.0

    f32x4 oacc[4];
    #pragma unroll
    for (int dt = 0; dt < 4; ++dt) oacc[dt] = (f32x4){0.f, 0.f, 0.f, 0.f};
    f32x4 dacc = (f32x4){0.f, 0.f, 0.f, 0.f};

    // prologue: load chunk 0 into regs
    bf16x8 kreg0 = *reinterpret_cast<const bf16x8*>(kcbase);
    bf16x8 kreg1 = *reinterpret_cast<const bf16x8*>(kcbase + 8);
    bf16x8 vreg0 = *reinterpret_cast<const bf16x8*>(vcbase);
    bf16x8 vreg1 = *reinterpret_cast<const bf16x8*>(vcbase + 8);

    for (int c = 0; c < NCH; ++c) {
        const int cur = c & 1;
        *reinterpret_cast<bf16x8*>(&Ks[cur][srow*72 + scol])     = kreg0;
        *reinterpret_cast<bf16x8*>(&Ks[cur][srow*72 + scol + 8]) = kreg1;
        *reinterpret_cast<bf16x8*>(&Vs[cur][srow*72 + scol])     = vreg0;
        *reinterpret_cast<bf16x8*>(&Vs[cur][srow*72 + scol + 8]) = vreg1;
        if (c + 1 < NCH) {
            const short* kn = kcbase + (size_t)(c + 1) * 4096;
            const short* vn = vcbase + (size_t)(c + 1) * 4096;
            kreg0 = *reinterpret_cast<const bf16x8*>(kn);
            kreg1 = *reinterpret_cast<const bf16x8*>(kn + 8);
            vreg0 = *reinterpret_cast<const bf16x8*>(vn);
            vreg1 = *reinterpret_cast<const bf16x8*>(vn + 8);
        }
        __syncthreads();

        // ---- QK^T from LDS
        f32x4 sa[4];
        #pragma unroll
        for (int kt = 0; kt < 4; ++kt) {
            bf16x8 kf0 = *reinterpret_cast<const bf16x8*>(&Ks[cur][(kt*16 + r)*72 + 8*g]);
            bf16x8 kf1 = *reinterpret_cast<const bf16x8*>(&Ks[cur][(kt*16 + r)*72 + 32 + 8*g]);
            f32x4 s = (f32x4){0.f, 0.f, 0.f, 0.f};
            s = __builtin_amdgcn_mfma_f32_16x16x32_bf16(qh[0], kf0, s, 0, 0, 0);
            s = __builtin_amdgcn_mfma_f32_16x16x32_bf16(qh[1], kf1, s, 0, 0, 0);
            sa[kt] = s;
        }
        if (c == NCH - 1) {
            #pragma unroll
            for (int kt = 0; kt < 4; ++kt)
                if (c*64 + kt*16 + r >= KSEL)
                    sa[kt] = (f32x4){-INFINITY, -INFINITY, -INFINITY, -INFINITY};
        }

        // ---- p = exp(s) (scores bounded, no max needed); bf16; transpose
        #pragma unroll
        for (int kt = 0; kt < 4; ++kt)
            #pragma unroll
            for (int e = 0; e < 4; ++e)
                Psw[(4*g + e)*72 + ((kt*16 + r) ^ (8*g))] = bf16rne(__expf(sa[kt][e]));

        // ---- PV + denominator (ones-column MFMA)
        #pragma unroll
        for (int kc = 0; kc < 2; ++kc) {
            bf16x8 pf = *reinterpret_cast<const bf16x8*>(&Psw[r*72 + kc*32 + 8*(g ^ (r >> 2))]);
            dacc = __builtin_amdgcn_mfma_f32_16x16x32_bf16(pf, ones, dacc, 0, 0, 0);
            #pragma unroll
            for (int dt = 0; dt < 4; ++dt) {
                bf16x8 vf = *reinterpret_cast<const bf16x8*>(&Vs[cur][(dt*16 + r)*72 + kc*32 + 8*(g ^ dt)]);
                oacc[dt] = __builtin_amdgcn_mfma_f32_16x16x32_bf16(pf, vf, oacc[dt], 0, 0, 0);
            }
        }
    }

    // ---- epilogue: normalize by dacc, split, store
    #pragma unroll
    for (int dt = 0; dt < 4; ++dt)
        #pragma unroll
        for (int e = 0; e < 4; ++e) {
            const float o = oacc[dt][e] / dacc[e];
            short hh, ll;
            split1(o, hh, ll);
            const size_t a = (size_t)(b * SS + q0 + w*16 + 4*g + e) * DD + h * HD + dt*16 + r;
            AOhi[a] = hh; AOlo[a] = ll;
        }
}

extern "C" void kernel_launch(void* const* d_in, const int* in_sizes, int n_in,
                              void* d_out, int out_size, void* d_ws, size_t ws_size,
                              hipStream_t stream)
{
    const float* x   = (const float*)d_in[0];
    const float* wq  = (const float*)d_in[1];
    const float* bq  = (const float*)d_in[2];
    const float* wk  = (const float*)d_in[3];
    const float* bk  = (const float*)d_in[4];
    const float* wv  = (const float*)d_in[5];
    const float* bv  = (const float*)d_in[6];
    const float* wo  = (const float*)d_in[7];
    const float* bo  = (const float*)d_in[8];
    const float* wi1 = (const float*)d_in[9];
    const float* bi1 = (const float*)d_in[10];
    const float* wi2 = (const float*)d_in[11];
    const float* bi2 = (const float*)d_in[12];
    float* out = (float*)d_out;

    const size_t MB = 1ull << 20;
    char* W = (char*)d_ws;
    short* x_hi  = (short*)(W + 0);          // 16 MB
    short* x_lo  = (short*)(W + 16*MB);      // 16 MB
    float* QKV   = (float*)(W + 32*MB);      // 96 MB
    short* Bqk_hi= (short*)(W + 128*MB);     // 4 MB (2048 x 1024 bf16: wq,wk)
    short* Bv_hi = (short*)(W + 132*MB);     // 2 MB
    short* Bv_lo = (short*)(W + 134*MB);     // 2 MB
    short* wo_hi = (short*)(W + 136*MB);     // 2 MB
    short* wo_lo = (short*)(W + 138*MB);     // 2 MB
    float* Hw    = (float*)(W + 144*MB);     // 16 MB (dead after importance_kernel)
    float* bqk   = (float*)(W + 160*MB);
    float* imp   = (float*)(W + 160*MB + 64*1024);
    int*   flags = (int*)(W + 160*MB + 128*1024);
    int*   idxg  = (int*)(W + 160*MB + 192*1024);
    short* Wi_hi = (short*)(W + 32*MB);      // 1 MB (inside not-yet-written QKV)
    short* Wi_lo = (short*)(W + 33*MB);      // 1 MB
    short* Kg = (short*)(W + 144*MB);        // 5.25 MB (over dead Hw)
    short* Vg = (short*)(W + 150*MB);
    short* AO_hi = x_hi;
    short* AO_lo = x_lo;

    const size_t NM = (size_t)MTOT * DD;

    // 0. splits + fused bias
    split_convert<<<(NM/4 + 255)/256, 256, 0, stream>>>(x, x_hi, x_lo, NM/4);
    split_weights<<<dim3(DD*DD/4/256, 5), 256, 0, stream>>>(
        wq, wk, wv, wo, wi1, Bqk_hi, Bv_hi, Bv_lo, wo_hi, wo_lo, Wi_hi, Wi_lo);
    concat_bias<<<2048/256, 256, 0, stream>>>(bq, bk, bqk);

    // 1. indexer h = relu(x @ wi1^T + bi1)  -- 3-term split
    gemm_split<true><<<dim3(DH/128, MTOT/128), 256, 0, stream>>>(
        x_hi, x_lo, Wi_hi, Wi_lo, bi1, Hw, MTOT, DH, DD, DH);
    // 2-3. importance + top-k (parallel LDS-staged ranking)
    importance_kernel<<<MTOT/4, 256, 0, stream>>>(Hw, wi2, bi2, imp);
    rank_kernel<<<dim3(SS/32, BB), 256, 0, stream>>>(imp, flags);
    compact_kernel<<<BB, 256, 0, stream>>>(flags, idxg);

    // 4a. Q,K projection: pure bf16 -> QKV cols 0..2047
    gemm_bf16<<<dim3(2048/128, MTOT/128), 256, 0, stream>>>(
        x_hi, Bqk_hi, bqk, QKV, MTOT, 2048, DD, QKVS);
    // 4b. V projection: 3-term split -> QKV cols 2048..3071
    gemm_split<false><<<dim3(DD/128, MTOT/128), 256, 0, stream>>>(
        x_hi, x_lo, Bv_hi, Bv_lo, bv, QKV + 2048, MTOT, DD, DD, QKVS);

    // 4c. one-shot gather K/V -> bf16 chunk-contiguous (Hw region now dead)
    gather_kv<<<dim3(NCH, HHD, BB), 256, 0, stream>>>(QKV, idxg, Kg, Vg);

    // 5. no-max-softmax MFMA sparse flash attention -> bf16 hi/lo
    attn_mfma<<<dim3(SS/64, HHD, BB), 256, 0, stream>>>(QKV, Kg, Vg, AO_hi, AO_lo);

    // 6. output projection (3-term split)
    gemm_split<false><<<dim3(DD/128, MTOT/128), 256, 0, stream>>>(
        AO_hi, AO_lo, wo_hi, wo_lo, bo, out, MTOT, DD, DD, DD);
}

// Round 10
// 269.470 us; speedup vs baseline: 1.8158x; 1.1626x over previous
//
#include <hip/hip_runtime.h>
#include <math.h>

#define BB 4
#define SS 2048
#define DD 1024
#define HHD 16      // heads
#define HD 64       // head dim
#define DH 512      // indexer hidden
#define KSEL 614    // top-k count
#define KPAD 640    // padded to multiple of 64
#define MTOT (BB*SS)
#define QKVS 3072   // fused QKV row stride
#define NCH (KPAD/64)

typedef __attribute__((ext_vector_type(8))) short bf16x8;
typedef __attribute__((ext_vector_type(4))) float f32x4;

#define LDS_CAST(p) ((__attribute__((address_space(3))) void*)(p))
#define GLB_CAST(p) ((const __attribute__((address_space(1))) void*)(p))

// ---------------- fp32 -> bf16 helpers (RNE)
__device__ inline short bf16rne(float v)
{
    unsigned u = __builtin_bit_cast(unsigned, v);
    return (short)((u + 0x7FFFu + ((u >> 16) & 1u)) >> 16);
}

__device__ inline void split1(float v, short& h, short& l)
{
    unsigned u = __builtin_bit_cast(unsigned, v);
    unsigned hr = (u + 0x7FFFu + ((u >> 16) & 1u)) >> 16;
    h = (short)hr;
    float hf = __builtin_bit_cast(float, hr << 16);
    float res = v - hf;
    unsigned u2 = __builtin_bit_cast(unsigned, res);
    unsigned lr = (u2 + 0x7FFFu + ((u2 >> 16) & 1u)) >> 16;
    l = (short)lr;
}

__device__ inline bf16x8 pack8(float4 a, float4 b)
{
    bf16x8 o;
    o[0]=bf16rne(a.x); o[1]=bf16rne(a.y); o[2]=bf16rne(a.z); o[3]=bf16rne(a.w);
    o[4]=bf16rne(b.x); o[5]=bf16rne(b.y); o[6]=bf16rne(b.z); o[7]=bf16rne(b.w);
    return o;
}

__global__ __launch_bounds__(256)
void split_convert(const float* __restrict__ in, short* __restrict__ hi,
                   short* __restrict__ lo, int n4)
{
    const int i = blockIdx.x * 256 + threadIdx.x;
    if (i >= n4) return;
    float4 v = reinterpret_cast<const float4*>(in)[i];
    short4 h, l;
    split1(v.x, h.x, l.x);
    split1(v.y, h.y, l.y);
    split1(v.z, h.z, l.z);
    split1(v.w, h.w, l.w);
    reinterpret_cast<short4*>(hi)[i] = h;
    reinterpret_cast<short4*>(lo)[i] = l;
}

// fused weight splits: y=0 wq(hi), 1 wk(hi), 2 wv(hi), 3 wo(hi+lo), 4 wi1(hi+lo)
__global__ __launch_bounds__(256)
void split_weights(const float* __restrict__ wq, const float* __restrict__ wk,
                   const float* __restrict__ wv, const float* __restrict__ wo,
                   const float* __restrict__ wi1,
                   short* __restrict__ Bqkv_hi,
                   short* __restrict__ wo_hi, short* __restrict__ wo_lo,
                   short* __restrict__ Wi_hi, short* __restrict__ Wi_lo)
{
    const int i = blockIdx.x * 256 + threadIdx.x;
    const int which = blockIdx.y;
    if (which == 0) {
        float4 v = reinterpret_cast<const float4*>(wq)[i];
        short4 hh;
        hh.x = bf16rne(v.x); hh.y = bf16rne(v.y); hh.z = bf16rne(v.z); hh.w = bf16rne(v.w);
        reinterpret_cast<short4*>(Bqkv_hi)[i] = hh;
    } else if (which == 1) {
        float4 v = reinterpret_cast<const float4*>(wk)[i];
        short4 hh;
        hh.x = bf16rne(v.x); hh.y = bf16rne(v.y); hh.z = bf16rne(v.z); hh.w = bf16rne(v.w);
        reinterpret_cast<short4*>(Bqkv_hi + DD*DD)[i] = hh;
    } else if (which == 2) {
        float4 v = reinterpret_cast<const float4*>(wv)[i];
        short4 hh;
        hh.x = bf16rne(v.x); hh.y = bf16rne(v.y); hh.z = bf16rne(v.z); hh.w = bf16rne(v.w);
        reinterpret_cast<short4*>(Bqkv_hi + 2*DD*DD)[i] = hh;
    } else if (which == 3) {
        float4 v = reinterpret_cast<const float4*>(wo)[i];
        short4 h, l;
        split1(v.x, h.x, l.x); split1(v.y, h.y, l.y);
        split1(v.z, h.z, l.z); split1(v.w, h.w, l.w);
        reinterpret_cast<short4*>(wo_hi)[i] = h;
        reinterpret_cast<short4*>(wo_lo)[i] = l;
    } else {
        if (i >= DH*DD/4) return;
        float4 v = reinterpret_cast<const float4*>(wi1)[i];
        short4 h, l;
        split1(v.x, h.x, l.x); split1(v.y, h.y, l.y);
        split1(v.z, h.z, l.z); split1(v.w, h.w, l.w);
        reinterpret_cast<short4*>(Wi_hi)[i] = h;
        reinterpret_cast<short4*>(Wi_lo)[i] = l;
    }
}

__global__ __launch_bounds__(256)
void concat_bias3(const float* __restrict__ a, const float* __restrict__ b,
                  const float* __restrict__ c, float* __restrict__ o)
{
    const int i = blockIdx.x * 256 + threadIdx.x;   // 3072
    o[i] = (i < 1024) ? a[i] : ((i < 2048) ? b[i - 1024] : c[i - 2048]);
}

// ---------------- plain bf16 MFMA GEMM, BK=64: C[M,N] = Ahi @ Bhi^T + bias
// 128x128 tile, 4 waves, 32 MFMA/barrier. 8-slot XOR swizzle (slot ^= row&7):
// staging issues contiguous 1KB (8 rows x 64 cols) with pre-swizzled global src;
// frag reads spread 16 lanes over 8 distinct 16B regions (2-way = free).
__global__ __launch_bounds__(256)
void gemm_bf16(const short* __restrict__ Ahi, const short* __restrict__ Bhi,
               const float* __restrict__ bias, float* __restrict__ C,
               int M, int N, int K, int ldc)
{
    __shared__ short sAh[128*64];
    __shared__ short sBh[128*64];

    const int t = threadIdx.x;
    const int lane = t & 63, wid = t >> 6;
    const int wm = wid >> 1, wn = wid & 1;
    const int row0 = blockIdx.y * 128, col0 = blockIdx.x * 128;
    const int g = lane >> 4, r = lane & 15;
    const int lrow = lane >> 3;    // 0..7 (staging row within 8-row strip)
    const int lslot = lane & 7;    // 0..7 (staging 8-elem slot)

    f32x4 acc[4][4];
    #pragma unroll
    for (int mt = 0; mt < 4; ++mt)
        #pragma unroll
        for (int nt = 0; nt < 4; ++nt) acc[mt][nt] = (f32x4){0.f, 0.f, 0.f, 0.f};

    for (int k0 = 0; k0 < K; k0 += 64) {
        #pragma unroll
        for (int e = 0; e < 4; ++e) {
            const int rl = wid * 32 + e * 8 + lrow;
            const int scol = k0 + ((lslot ^ (rl & 7)) << 3);   // pre-swizzled source col
            const size_t ga = (size_t)(row0 + rl) * K + scol;
            const size_t gb = (size_t)(col0 + rl) * K + scol;
            const int ldso = (wid * 32 + e * 8) * 64;          // uniform 1KB strip base
            __builtin_amdgcn_global_load_lds(GLB_CAST(Ahi + ga), LDS_CAST(sAh + ldso), 16, 0, 0);
            __builtin_amdgcn_global_load_lds(GLB_CAST(Bhi + gb), LDS_CAST(sBh + ldso), 16, 0, 0);
        }
        __syncthreads();

        #pragma unroll
        for (int kk = 0; kk < 2; ++kk) {
            bf16x8 ah[4], bh[4];
            #pragma unroll
            for (int mt = 0; mt < 4; ++mt) {
                const int rw = wm * 64 + mt * 16 + r;
                ah[mt] = *reinterpret_cast<const bf16x8*>(sAh + rw * 64 + (((kk*4 + g) ^ (rw & 7)) << 3));
            }
            #pragma unroll
            for (int nt = 0; nt < 4; ++nt) {
                const int rw = wn * 64 + nt * 16 + r;
                bh[nt] = *reinterpret_cast<const bf16x8*>(sBh + rw * 64 + (((kk*4 + g) ^ (rw & 7)) << 3));
            }
            #pragma unroll
            for (int mt = 0; mt < 4; ++mt)
                #pragma unroll
                for (int nt = 0; nt < 4; ++nt)
                    acc[mt][nt] = __builtin_amdgcn_mfma_f32_16x16x32_bf16(ah[mt], bh[nt], acc[mt][nt], 0, 0, 0);
        }
        __syncthreads();
    }

    #pragma unroll
    for (int nt = 0; nt < 4; ++nt) {
        const int col = wn * 64 + nt * 16 + r;
        const float bv = bias[col0 + col];
        #pragma unroll
        for (int mt = 0; mt < 4; ++mt) {
            #pragma unroll
            for (int e = 0; e < 4; ++e) {
                const int row = row0 + wm * 64 + mt * 16 + 4 * g + e;
                C[(size_t)row * ldc + col0 + col] = acc[mt][nt][e] + bv;
            }
        }
    }
}

// ---------------- split-bf16 MFMA GEMM (3-term): C = (Ahi+Alo)@(Bhi+Blo)^T + bias
template<bool RELU>
__global__ __launch_bounds__(256)
void gemm_split(const short* __restrict__ Ahi, const short* __restrict__ Alo,
                const short* __restrict__ Bhi, const short* __restrict__ Blo,
                const float* __restrict__ bias, float* __restrict__ C,
                int M, int N, int K, int ldc)
{
    __shared__ short sAh[128*32];
    __shared__ short sAl[128*32];
    __shared__ short sBh[128*32];
    __shared__ short sBl[128*32];

    const int t = threadIdx.x;
    const int lane = t & 63, wid = t >> 6;
    const int wm = wid >> 1, wn = wid & 1;
    const int row0 = blockIdx.y * 128, col0 = blockIdx.x * 128;
    const int g = lane >> 4, r = lane & 15;
    const int sw = g ^ ((lane >> 2) & 3);
    const int srow = lane >> 2;
    const int sslot = lane & 3;

    f32x4 acc[4][4];
    #pragma unroll
    for (int mt = 0; mt < 4; ++mt)
        #pragma unroll
        for (int nt = 0; nt < 4; ++nt) acc[mt][nt] = (f32x4){0.f, 0.f, 0.f, 0.f};

    for (int k0 = 0; k0 < K; k0 += 32) {
        #pragma unroll
        for (int i = 0; i < 2; ++i) {
            const int rl = wid * 32 + i * 16 + srow;
            const int scol = k0 + ((sslot ^ ((rl >> 2) & 3)) << 3);
            const size_t ga = (size_t)(row0 + rl) * K + scol;
            const size_t gb = (size_t)(col0 + rl) * K + scol;
            const int ldso = (wid * 32 + i * 16) * 32;
            __builtin_amdgcn_global_load_lds(GLB_CAST(Ahi + ga), LDS_CAST(sAh + ldso), 16, 0, 0);
            __builtin_amdgcn_global_load_lds(GLB_CAST(Alo + ga), LDS_CAST(sAl + ldso), 16, 0, 0);
            __builtin_amdgcn_global_load_lds(GLB_CAST(Bhi + gb), LDS_CAST(sBh + ldso), 16, 0, 0);
            __builtin_amdgcn_global_load_lds(GLB_CAST(Blo + gb), LDS_CAST(sBl + ldso), 16, 0, 0);
        }
        __syncthreads();

        bf16x8 ah[4], al[4], bh[4], bl[4];
        #pragma unroll
        for (int mt = 0; mt < 4; ++mt) {
            const int row = wm * 64 + mt * 16 + r;
            ah[mt] = *reinterpret_cast<const bf16x8*>(sAh + row * 32 + sw * 8);
            al[mt] = *reinterpret_cast<const bf16x8*>(sAl + row * 32 + sw * 8);
        }
        #pragma unroll
        for (int nt = 0; nt < 4; ++nt) {
            const int row = wn * 64 + nt * 16 + r;
            bh[nt] = *reinterpret_cast<const bf16x8*>(sBh + row * 32 + sw * 8);
            bl[nt] = *reinterpret_cast<const bf16x8*>(sBl + row * 32 + sw * 8);
        }
        #pragma unroll
        for (int mt = 0; mt < 4; ++mt)
            #pragma unroll
            for (int nt = 0; nt < 4; ++nt) {
                acc[mt][nt] = __builtin_amdgcn_mfma_f32_16x16x32_bf16(ah[mt], bh[nt], acc[mt][nt], 0, 0, 0);
                acc[mt][nt] = __builtin_amdgcn_mfma_f32_16x16x32_bf16(ah[mt], bl[nt], acc[mt][nt], 0, 0, 0);
                acc[mt][nt] = __builtin_amdgcn_mfma_f32_16x16x32_bf16(al[mt], bh[nt], acc[mt][nt], 0, 0, 0);
            }
        __syncthreads();
    }

    #pragma unroll
    for (int nt = 0; nt < 4; ++nt) {
        const int col = wn * 64 + nt * 16 + r;
        const float bv = bias[col0 + col];
        #pragma unroll
        for (int mt = 0; mt < 4; ++mt) {
            #pragma unroll
            for (int e = 0; e < 4; ++e) {
                const int row = row0 + wm * 64 + mt * 16 + 4 * g + e;
                float v = acc[mt][nt][e] + bv;
                if (RELU) v = fmaxf(v, 0.f);
                C[(size_t)row * ldc + col0 + col] = v;
            }
        }
    }
}

// ---------------- importance / top-k
__global__ __launch_bounds__(256)
void importance_kernel(const float* __restrict__ h, const float* __restrict__ wi2,
                       const float* __restrict__ bi2, float* __restrict__ imp)
{
    const int wid = threadIdx.x >> 6, lane = threadIdx.x & 63;
    const int row = blockIdx.x * 4 + wid;
    const float* hr = h + (size_t)row * DH;
    float s = 0.f;
    #pragma unroll
    for (int i = 0; i < DH/64; ++i)
        s = fmaf(hr[lane + i*64], wi2[lane + i*64], s);
    #pragma unroll
    for (int off = 32; off; off >>= 1) s += __shfl_down(s, off);
    if (lane == 0) imp[row] = s + bi2[0];
}

// top-k rank: LDS-staged, 8 threads per position, exact lax.top_k tie-break
__global__ __launch_bounds__(256)
void rank_kernel(const float* __restrict__ imp, int* __restrict__ flags)
{
    __shared__ float simp[SS];
    const int b = blockIdx.y;
    const int t = threadIdx.x;
    const float* bimp = imp + b * SS;
    for (int i = t; i < SS/4; i += 256)
        reinterpret_cast<float4*>(simp)[i] = reinterpret_cast<const float4*>(bimp)[i];
    __syncthreads();

    const int i = blockIdx.x * 32 + (t >> 3);
    const int part = t & 7;
    const float v = simp[i];
    const float4* slice = reinterpret_cast<const float4*>(simp + part * (SS/8));
    const int jb = part * (SS/8);
    int rank = 0;
    #pragma unroll 8
    for (int jj = 0; jj < SS/32; ++jj) {
        const float4 u4 = slice[jj];
        const int j = jb + jj * 4;
        rank += (u4.x > v) || ((u4.x == v) && (j + 0 < i));
        rank += (u4.y > v) || ((u4.y == v) && (j + 1 < i));
        rank += (u4.z > v) || ((u4.z == v) && (j + 2 < i));
        rank += (u4.w > v) || ((u4.w == v) && (j + 3 < i));
    }
    rank += __shfl_xor(rank, 1);
    rank += __shfl_xor(rank, 2);
    rank += __shfl_xor(rank, 4);
    if (part == 0) flags[b * SS + i] = (rank < KSEL) ? 1 : 0;
}

__global__ __launch_bounds__(256)
void compact_kernel(const int* __restrict__ flags, int* __restrict__ idxg)
{
    __shared__ int sscan[SS];
    __shared__ int sidx[KSEL];
    const int b = blockIdx.x, t = threadIdx.x;
    for (int i = t; i < SS; i += 256) sscan[i] = flags[b * SS + i];
    __syncthreads();
    for (int off = 1; off < SS; off <<= 1) {
        int vals[SS/256];
        #pragma unroll
        for (int c = 0; c < SS/256; ++c) {
            const int i = t + c * 256;
            int v = sscan[i];
            if (i >= off) v += sscan[i - off];
            vals[c] = v;
        }
        __syncthreads();
        #pragma unroll
        for (int c = 0; c < SS/256; ++c) sscan[t + c * 256] = vals[c];
        __syncthreads();
    }
    for (int i = t; i < SS; i += 256) {
        const int f = flags[b * SS + i];
        if (f) sidx[sscan[i] - 1] = i;
    }
    __syncthreads();
    for (int p = t; p < KPAD; p += 256)
        idxg[b * KPAD + p] = sidx[min(p, KSEL - 1)];
}

// ---------------- one-shot K/V gather + fp32->bf16 + V transpose, CHUNK-CONTIGUOUS
__global__ __launch_bounds__(256)
void gather_kv(const float* __restrict__ QKV, const int* __restrict__ idxg,
               short* __restrict__ Kg, short* __restrict__ Vg)
{
    __shared__ short Vs[64*72];   // [d][key] padded
    const int t = threadIdx.x;
    const int c = blockIdx.x, h = blockIdx.y, b = blockIdx.z;
    const int srow = t >> 2;
    const int sq4  = t & 3;

    const size_t cbase = ((size_t)(b * HHD + h) * NCH + c) * 4096;

    const int krow = idxg[b * KPAD + c * 64 + srow];
    const float* kb = QKV + (size_t)(b * SS + krow) * QKVS + 1024 + h * HD + sq4 * 16;
    float4 k0 = *reinterpret_cast<const float4*>(kb);
    float4 k1 = *reinterpret_cast<const float4*>(kb + 4);
    float4 k2 = *reinterpret_cast<const float4*>(kb + 8);
    float4 k3 = *reinterpret_cast<const float4*>(kb + 12);
    short* kout = Kg + cbase + srow * HD + sq4 * 16;
    *reinterpret_cast<bf16x8*>(kout)     = pack8(k0, k1);
    *reinterpret_cast<bf16x8*>(kout + 8) = pack8(k2, k3);

    const float* vbp = kb + 1024;
    float4 v0 = *reinterpret_cast<const float4*>(vbp);
    float4 v1 = *reinterpret_cast<const float4*>(vbp + 4);
    float4 v2 = *reinterpret_cast<const float4*>(vbp + 8);
    float4 v3 = *reinterpret_cast<const float4*>(vbp + 12);
    float vv[16] = {v0.x,v0.y,v0.z,v0.w, v1.x,v1.y,v1.z,v1.w,
                    v2.x,v2.y,v2.z,v2.w, v3.x,v3.y,v3.z,v3.w};
    #pragma unroll
    for (int j = 0; j < 16; ++j)
        Vs[(sq4 * 16 + j) * 72 + srow] = bf16rne(vv[j]);
    __syncthreads();

    const int x = 8 * (srow >> 4);
    short* vout = Vg + cbase + srow * 64;
    *reinterpret_cast<bf16x8*>(vout + ((sq4 * 16)     ^ x)) = *reinterpret_cast<const bf16x8*>(&Vs[srow * 72 + sq4 * 16]);
    *reinterpret_cast<bf16x8*>(vout + ((sq4 * 16 + 8) ^ x)) = *reinterpret_cast<const bf16x8*>(&Vs[srow * 72 + sq4 * 16 + 8]);
}

// ---------------- MFMA sparse flash attention: no-max softmax, ones-column denom,
// double-buffered LDS
__global__ __launch_bounds__(256)
void attn_mfma(const float* __restrict__ QKV, const short* __restrict__ Kg,
               const short* __restrict__ Vg,
               short* __restrict__ AOhi, short* __restrict__ AOlo)
{
    __shared__ short Ks[2][64*72];
    __shared__ short Vs[2][64*72];
    __shared__ short Ps[4][16*72];

    const int t = threadIdx.x;
    const int lane = t & 63, w = t >> 6;
    const int g = lane >> 4, r = lane & 15;
    const int qt = blockIdx.x, h = blockIdx.y, b = blockIdx.z;
    const int q0 = qt * 64;
    short* Psw = &Ps[w][0];

    const int srow = t >> 2;
    const int scol = (t & 3) * 16;
    const short* kcbase = Kg + ((size_t)(b * HHD + h) * NCH) * 4096 + srow * 64 + scol;
    const short* vcbase = Vg + ((size_t)(b * HHD + h) * NCH) * 4096 + srow * 64 + scol;

    bf16x8 qh[2];
    {
        const float* qrow = QKV + (size_t)(b * SS + q0 + w * 16 + r) * QKVS + h * HD;
        #pragma unroll
        for (int ch = 0; ch < 2; ++ch) {
            float4 f0 = *reinterpret_cast<const float4*>(&qrow[ch*32 + 8*g]);
            float4 f1 = *reinterpret_cast<const float4*>(&qrow[ch*32 + 8*g + 4]);
            float v[8] = {f0.x, f0.y, f0.z, f0.w, f1.x, f1.y, f1.z, f1.w};
            #pragma unroll
            for (int e = 0; e < 8; ++e) qh[ch][e] = bf16rne(v[e] * 0.125f);
        }
    }

    bf16x8 ones;
    #pragma unroll
    for (int j = 0; j < 8; ++j) ones[j] = (short)0x3F80;

    f32x4 oacc[4];
    #pragma unroll
    for (int dt = 0; dt < 4; ++dt) oacc[dt] = (f32x4){0.f, 0.f, 0.f, 0.f};
    f32x4 dacc = (f32x4){0.f, 0.f, 0.f, 0.f};

    bf16x8 kreg0 = *reinterpret_cast<const bf16x8*>(kcbase);
    bf16x8 kreg1 = *reinterpret_cast<const bf16x8*>(kcbase + 8);
    bf16x8 vreg0 = *reinterpret_cast<const bf16x8*>(vcbase);
    bf16x8 vreg1 = *reinterpret_cast<const bf16x8*>(vcbase + 8);

    for (int c = 0; c < NCH; ++c) {
        const int cur = c & 1;
        *reinterpret_cast<bf16x8*>(&Ks[cur][srow*72 + scol])     = kreg0;
        *reinterpret_cast<bf16x8*>(&Ks[cur][srow*72 + scol + 8]) = kreg1;
        *reinterpret_cast<bf16x8*>(&Vs[cur][srow*72 + scol])     = vreg0;
        *reinterpret_cast<bf16x8*>(&Vs[cur][srow*72 + scol + 8]) = vreg1;
        if (c + 1 < NCH) {
            const short* kn = kcbase + (size_t)(c + 1) * 4096;
            const short* vn = vcbase + (size_t)(c + 1) * 4096;
            kreg0 = *reinterpret_cast<const bf16x8*>(kn);
            kreg1 = *reinterpret_cast<const bf16x8*>(kn + 8);
            vreg0 = *reinterpret_cast<const bf16x8*>(vn);
            vreg1 = *reinterpret_cast<const bf16x8*>(vn + 8);
        }
        __syncthreads();

        f32x4 sa[4];
        #pragma unroll
        for (int kt = 0; kt < 4; ++kt) {
            bf16x8 kf0 = *reinterpret_cast<const bf16x8*>(&Ks[cur][(kt*16 + r)*72 + 8*g]);
            bf16x8 kf1 = *reinterpret_cast<const bf16x8*>(&Ks[cur][(kt*16 + r)*72 + 32 + 8*g]);
            f32x4 s = (f32x4){0.f, 0.f, 0.f, 0.f};
            s = __builtin_amdgcn_mfma_f32_16x16x32_bf16(qh[0], kf0, s, 0, 0, 0);
            s = __builtin_amdgcn_mfma_f32_16x16x32_bf16(qh[1], kf1, s, 0, 0, 0);
            sa[kt] = s;
        }
        if (c == NCH - 1) {
            #pragma unroll
            for (int kt = 0; kt < 4; ++kt)
                if (c*64 + kt*16 + r >= KSEL)
                    sa[kt] = (f32x4){-INFINITY, -INFINITY, -INFINITY, -INFINITY};
        }

        #pragma unroll
        for (int kt = 0; kt < 4; ++kt)
            #pragma unroll
            for (int e = 0; e < 4; ++e)
                Psw[(4*g + e)*72 + ((kt*16 + r) ^ (8*g))] = bf16rne(__expf(sa[kt][e]));

        #pragma unroll
        for (int kc = 0; kc < 2; ++kc) {
            bf16x8 pf = *reinterpret_cast<const bf16x8*>(&Psw[r*72 + kc*32 + 8*(g ^ (r >> 2))]);
            dacc = __builtin_amdgcn_mfma_f32_16x16x32_bf16(pf, ones, dacc, 0, 0, 0);
            #pragma unroll
            for (int dt = 0; dt < 4; ++dt) {
                bf16x8 vf = *reinterpret_cast<const bf16x8*>(&Vs[cur][(dt*16 + r)*72 + kc*32 + 8*(g ^ dt)]);
                oacc[dt] = __builtin_amdgcn_mfma_f32_16x16x32_bf16(pf, vf, oacc[dt], 0, 0, 0);
            }
        }
    }

    #pragma unroll
    for (int dt = 0; dt < 4; ++dt)
        #pragma unroll
        for (int e = 0; e < 4; ++e) {
            const float o = oacc[dt][e] / dacc[e];
            short hh, ll;
            split1(o, hh, ll);
            const size_t a = (size_t)(b * SS + q0 + w*16 + 4*g + e) * DD + h * HD + dt*16 + r;
            AOhi[a] = hh; AOlo[a] = ll;
        }
}

extern "C" void kernel_launch(void* const* d_in, const int* in_sizes, int n_in,
                              void* d_out, int out_size, void* d_ws, size_t ws_size,
                              hipStream_t stream)
{
    const float* x   = (const float*)d_in[0];
    const float* wq  = (const float*)d_in[1];
    const float* bq  = (const float*)d_in[2];
    const float* wk  = (const float*)d_in[3];
    const float* bk  = (const float*)d_in[4];
    const float* wv  = (const float*)d_in[5];
    const float* bv  = (const float*)d_in[6];
    const float* wo  = (const float*)d_in[7];
    const float* bo  = (const float*)d_in[8];
    const float* wi1 = (const float*)d_in[9];
    const float* bi1 = (const float*)d_in[10];
    const float* wi2 = (const float*)d_in[11];
    const float* bi2 = (const float*)d_in[12];
    float* out = (float*)d_out;

    const size_t MB = 1ull << 20;
    char* W = (char*)d_ws;
    short* x_hi  = (short*)(W + 0);          // 16 MB
    short* x_lo  = (short*)(W + 16*MB);      // 16 MB
    float* QKV   = (float*)(W + 32*MB);      // 96 MB
    short* Bqkv_hi=(short*)(W + 128*MB);     // 6 MB (3072 x 1024 bf16: wq,wk,wv)
    short* wo_hi = (short*)(W + 134*MB);     // 2 MB
    short* wo_lo = (short*)(W + 136*MB);     // 2 MB
    float* Hw    = (float*)(W + 144*MB);     // 16 MB (dead after importance_kernel)
    float* bqkv  = (float*)(W + 160*MB);
    float* imp   = (float*)(W + 160*MB + 64*1024);
    int*   flags = (int*)(W + 160*MB + 128*1024);
    int*   idxg  = (int*)(W + 160*MB + 192*1024);
    short* Wi_hi = (short*)(W + 32*MB);      // 1 MB (inside not-yet-written QKV)
    short* Wi_lo = (short*)(W + 33*MB);      // 1 MB
    short* Kg = (short*)(W + 144*MB);        // 5.25 MB (over dead Hw)
    short* Vg = (short*)(W + 150*MB);
    short* AO_hi = x_hi;
    short* AO_lo = x_lo;

    const size_t NM = (size_t)MTOT * DD;

    // 0. splits + fused bias
    split_convert<<<(NM/4 + 255)/256, 256, 0, stream>>>(x, x_hi, x_lo, NM/4);
    split_weights<<<dim3(DD*DD/4/256, 5), 256, 0, stream>>>(
        wq, wk, wv, wo, wi1, Bqkv_hi, wo_hi, wo_lo, Wi_hi, Wi_lo);
    concat_bias3<<<QKVS/256, 256, 0, stream>>>(bq, bk, bv, bqkv);

    // 1. indexer h = relu(x @ wi1^T + bi1)  -- 3-term split (top-k critical)
    gemm_split<true><<<dim3(DH/128, MTOT/128), 256, 0, stream>>>(
        x_hi, x_lo, Wi_hi, Wi_lo, bi1, Hw, MTOT, DH, DD, DH);
    // 2-3. importance + top-k
    importance_kernel<<<MTOT/4, 256, 0, stream>>>(Hw, wi2, bi2, imp);
    rank_kernel<<<dim3(SS/32, BB), 256, 0, stream>>>(imp, flags);
    compact_kernel<<<BB, 256, 0, stream>>>(flags, idxg);

    // 4. fused QKV projection: 1-term bf16, BK=64 (V pre-bf16-rounding error negligible)
    gemm_bf16<<<dim3(QKVS/128, MTOT/128), 256, 0, stream>>>(
        x_hi, Bqkv_hi, bqkv, QKV, MTOT, QKVS, DD, QKVS);

    // 4c. one-shot gather K/V -> bf16 chunk-contiguous (Hw region now dead)
    gather_kv<<<dim3(NCH, HHD, BB), 256, 0, stream>>>(QKV, idxg, Kg, Vg);

    // 5. no-max-softmax MFMA sparse flash attention -> bf16 hi/lo
    attn_mfma<<<dim3(SS/64, HHD, BB), 256, 0, stream>>>(QKV, Kg, Vg, AO_hi, AO_lo);

    // 6. output projection (3-term split)
    gemm_split<false><<<dim3(DD/128, MTOT/128), 256, 0, stream>>>(
        AO_hi, AO_lo, wo_hi, wo_lo, bo, out, MTOT, DD, DD, DD);
}

// Round 11
// 230.651 us; speedup vs baseline: 2.1214x; 1.1683x over previous
//
#include <hip/hip_runtime.h>
#include <math.h>

#define BB 4
#define SS 2048
#define DD 1024
#define HHD 16      // heads
#define HD 64       // head dim
#define DH 512      // indexer hidden
#define KSEL 614    // top-k count
#define KPAD 640    // padded to multiple of 64
#define MTOT (BB*SS)
#define QKVS 3072   // fused QKV row stride (bf16 elements)
#define NCH (KPAD/64)

typedef __attribute__((ext_vector_type(8))) short bf16x8;
typedef __attribute__((ext_vector_type(4))) float f32x4;

#define LDS_CAST(p) ((__attribute__((address_space(3))) void*)(p))
#define GLB_CAST(p) ((const __attribute__((address_space(1))) void*)(p))

// ---------------- fp32 -> bf16 helpers (RNE)
__device__ inline short bf16rne(float v)
{
    unsigned u = __builtin_bit_cast(unsigned, v);
    return (short)((u + 0x7FFFu + ((u >> 16) & 1u)) >> 16);
}

__device__ inline void split1(float v, short& h, short& l)
{
    unsigned u = __builtin_bit_cast(unsigned, v);
    unsigned hr = (u + 0x7FFFu + ((u >> 16) & 1u)) >> 16;
    h = (short)hr;
    float hf = __builtin_bit_cast(float, hr << 16);
    float res = v - hf;
    unsigned u2 = __builtin_bit_cast(unsigned, res);
    unsigned lr = (u2 + 0x7FFFu + ((u2 >> 16) & 1u)) >> 16;
    l = (short)lr;
}

__global__ __launch_bounds__(256)
void split_convert(const float* __restrict__ in, short* __restrict__ hi,
                   short* __restrict__ lo, int n4)
{
    const int i = blockIdx.x * 256 + threadIdx.x;
    if (i >= n4) return;
    float4 v = reinterpret_cast<const float4*>(in)[i];
    short4 h, l;
    split1(v.x, h.x, l.x);
    split1(v.y, h.y, l.y);
    split1(v.z, h.z, l.z);
    split1(v.w, h.w, l.w);
    reinterpret_cast<short4*>(hi)[i] = h;
    reinterpret_cast<short4*>(lo)[i] = l;
}

// fused weight splits: y=0 wq(hi), 1 wk(hi), 2 wv(hi), 3 wo(hi), 4 wi1(hi+lo)
__global__ __launch_bounds__(256)
void split_weights(const float* __restrict__ wq, const float* __restrict__ wk,
                   const float* __restrict__ wv, const float* __restrict__ wo,
                   const float* __restrict__ wi1,
                   short* __restrict__ Bqkv_hi, short* __restrict__ wo_hi,
                   short* __restrict__ Wi_hi, short* __restrict__ Wi_lo)
{
    const int i = blockIdx.x * 256 + threadIdx.x;
    const int which = blockIdx.y;
    if (which < 4) {
        const float* src = (which == 0) ? wq : (which == 1) ? wk : (which == 2) ? wv : wo;
        short* dst = (which == 3) ? wo_hi : (Bqkv_hi + (size_t)which * DD * DD);
        float4 v = reinterpret_cast<const float4*>(src)[i];
        short4 hh;
        hh.x = bf16rne(v.x); hh.y = bf16rne(v.y); hh.z = bf16rne(v.z); hh.w = bf16rne(v.w);
        reinterpret_cast<short4*>(dst)[i] = hh;
    } else {
        if (i >= DH*DD/4) return;
        float4 v = reinterpret_cast<const float4*>(wi1)[i];
        short4 h, l;
        split1(v.x, h.x, l.x); split1(v.y, h.y, l.y);
        split1(v.z, h.z, l.z); split1(v.w, h.w, l.w);
        reinterpret_cast<short4*>(Wi_hi)[i] = h;
        reinterpret_cast<short4*>(Wi_lo)[i] = l;
    }
}

__global__ __launch_bounds__(256)
void concat_bias3(const float* __restrict__ a, const float* __restrict__ b,
                  const float* __restrict__ c, float* __restrict__ o)
{
    const int i = blockIdx.x * 256 + threadIdx.x;   // 3072
    o[i] = (i < 1024) ? a[i] : ((i < 2048) ? b[i - 1024] : c[i - 2048]);
}

// ---------------- plain bf16 MFMA GEMM, BK=64: C = A @ B^T + bias
// 128x128 tile, 4 waves, 32 MFMA/barrier, 8-slot XOR swizzle (conflict-free, r10-verified).
// BF16_OUT: emit bf16 (QKV). QSCALE: cols<1024 scaled by 1/8 before rounding (Q).
template<bool BF16_OUT, bool QSCALE>
__global__ __launch_bounds__(256)
void gemm_bf16(const short* __restrict__ Ahi, const short* __restrict__ Bhi,
               const float* __restrict__ bias, void* __restrict__ Cv,
               int M, int N, int K, int ldc)
{
    __shared__ short sAh[128*64];
    __shared__ short sBh[128*64];

    const int t = threadIdx.x;
    const int lane = t & 63, wid = t >> 6;
    const int wm = wid >> 1, wn = wid & 1;
    const int row0 = blockIdx.y * 128, col0 = blockIdx.x * 128;
    const int g = lane >> 4, r = lane & 15;
    const int lrow = lane >> 3;
    const int lslot = lane & 7;

    f32x4 acc[4][4];
    #pragma unroll
    for (int mt = 0; mt < 4; ++mt)
        #pragma unroll
        for (int nt = 0; nt < 4; ++nt) acc[mt][nt] = (f32x4){0.f, 0.f, 0.f, 0.f};

    for (int k0 = 0; k0 < K; k0 += 64) {
        #pragma unroll
        for (int e = 0; e < 4; ++e) {
            const int rl = wid * 32 + e * 8 + lrow;
            const int scol = k0 + ((lslot ^ (rl & 7)) << 3);
            const size_t ga = (size_t)(row0 + rl) * K + scol;
            const size_t gb = (size_t)(col0 + rl) * K + scol;
            const int ldso = (wid * 32 + e * 8) * 64;
            __builtin_amdgcn_global_load_lds(GLB_CAST(Ahi + ga), LDS_CAST(sAh + ldso), 16, 0, 0);
            __builtin_amdgcn_global_load_lds(GLB_CAST(Bhi + gb), LDS_CAST(sBh + ldso), 16, 0, 0);
        }
        __syncthreads();

        #pragma unroll
        for (int kk = 0; kk < 2; ++kk) {
            bf16x8 ah[4], bh[4];
            #pragma unroll
            for (int mt = 0; mt < 4; ++mt) {
                const int rw = wm * 64 + mt * 16 + r;
                ah[mt] = *reinterpret_cast<const bf16x8*>(sAh + rw * 64 + (((kk*4 + g) ^ (rw & 7)) << 3));
            }
            #pragma unroll
            for (int nt = 0; nt < 4; ++nt) {
                const int rw = wn * 64 + nt * 16 + r;
                bh[nt] = *reinterpret_cast<const bf16x8*>(sBh + rw * 64 + (((kk*4 + g) ^ (rw & 7)) << 3));
            }
            #pragma unroll
            for (int mt = 0; mt < 4; ++mt)
                #pragma unroll
                for (int nt = 0; nt < 4; ++nt)
                    acc[mt][nt] = __builtin_amdgcn_mfma_f32_16x16x32_bf16(ah[mt], bh[nt], acc[mt][nt], 0, 0, 0);
        }
        __syncthreads();
    }

    #pragma unroll
    for (int nt = 0; nt < 4; ++nt) {
        const int col = wn * 64 + nt * 16 + r;
        const float bv = bias[col0 + col];
        const bool qs = QSCALE && (col0 + col) < 1024;
        #pragma unroll
        for (int mt = 0; mt < 4; ++mt) {
            #pragma unroll
            for (int e = 0; e < 4; ++e) {
                const int row = row0 + wm * 64 + mt * 16 + 4 * g + e;
                float v = acc[mt][nt][e] + bv;
                if (qs) v *= 0.125f;
                if (BF16_OUT)
                    ((short*)Cv)[(size_t)row * ldc + col0 + col] = bf16rne(v);
                else
                    ((float*)Cv)[(size_t)row * ldc + col0 + col] = v;
            }
        }
    }
}

// ---------------- split-bf16 MFMA GEMM (3-term): indexer only
template<bool RELU>
__global__ __launch_bounds__(256)
void gemm_split(const short* __restrict__ Ahi, const short* __restrict__ Alo,
                const short* __restrict__ Bhi, const short* __restrict__ Blo,
                const float* __restrict__ bias, float* __restrict__ C,
                int M, int N, int K, int ldc)
{
    __shared__ short sAh[128*32];
    __shared__ short sAl[128*32];
    __shared__ short sBh[128*32];
    __shared__ short sBl[128*32];

    const int t = threadIdx.x;
    const int lane = t & 63, wid = t >> 6;
    const int wm = wid >> 1, wn = wid & 1;
    const int row0 = blockIdx.y * 128, col0 = blockIdx.x * 128;
    const int g = lane >> 4, r = lane & 15;
    const int sw = g ^ ((lane >> 2) & 3);
    const int srow = lane >> 2;
    const int sslot = lane & 3;

    f32x4 acc[4][4];
    #pragma unroll
    for (int mt = 0; mt < 4; ++mt)
        #pragma unroll
        for (int nt = 0; nt < 4; ++nt) acc[mt][nt] = (f32x4){0.f, 0.f, 0.f, 0.f};

    for (int k0 = 0; k0 < K; k0 += 32) {
        #pragma unroll
        for (int i = 0; i < 2; ++i) {
            const int rl = wid * 32 + i * 16 + srow;
            const int scol = k0 + ((sslot ^ ((rl >> 2) & 3)) << 3);
            const size_t ga = (size_t)(row0 + rl) * K + scol;
            const size_t gb = (size_t)(col0 + rl) * K + scol;
            const int ldso = (wid * 32 + i * 16) * 32;
            __builtin_amdgcn_global_load_lds(GLB_CAST(Ahi + ga), LDS_CAST(sAh + ldso), 16, 0, 0);
            __builtin_amdgcn_global_load_lds(GLB_CAST(Alo + ga), LDS_CAST(sAl + ldso), 16, 0, 0);
            __builtin_amdgcn_global_load_lds(GLB_CAST(Bhi + gb), LDS_CAST(sBh + ldso), 16, 0, 0);
            __builtin_amdgcn_global_load_lds(GLB_CAST(Blo + gb), LDS_CAST(sBl + ldso), 16, 0, 0);
        }
        __syncthreads();

        bf16x8 ah[4], al[4], bh[4], bl[4];
        #pragma unroll
        for (int mt = 0; mt < 4; ++mt) {
            const int row = wm * 64 + mt * 16 + r;
            ah[mt] = *reinterpret_cast<const bf16x8*>(sAh + row * 32 + sw * 8);
            al[mt] = *reinterpret_cast<const bf16x8*>(sAl + row * 32 + sw * 8);
        }
        #pragma unroll
        for (int nt = 0; nt < 4; ++nt) {
            const int row = wn * 64 + nt * 16 + r;
            bh[nt] = *reinterpret_cast<const bf16x8*>(sBh + row * 32 + sw * 8);
            bl[nt] = *reinterpret_cast<const bf16x8*>(sBl + row * 32 + sw * 8);
        }
        #pragma unroll
        for (int mt = 0; mt < 4; ++mt)
            #pragma unroll
            for (int nt = 0; nt < 4; ++nt) {
                acc[mt][nt] = __builtin_amdgcn_mfma_f32_16x16x32_bf16(ah[mt], bh[nt], acc[mt][nt], 0, 0, 0);
                acc[mt][nt] = __builtin_amdgcn_mfma_f32_16x16x32_bf16(ah[mt], bl[nt], acc[mt][nt], 0, 0, 0);
                acc[mt][nt] = __builtin_amdgcn_mfma_f32_16x16x32_bf16(al[mt], bh[nt], acc[mt][nt], 0, 0, 0);
            }
        __syncthreads();
    }

    #pragma unroll
    for (int nt = 0; nt < 4; ++nt) {
        const int col = wn * 64 + nt * 16 + r;
        const float bv = bias[col0 + col];
        #pragma unroll
        for (int mt = 0; mt < 4; ++mt) {
            #pragma unroll
            for (int e = 0; e < 4; ++e) {
                const int row = row0 + wm * 64 + mt * 16 + 4 * g + e;
                float v = acc[mt][nt][e] + bv;
                if (RELU) v = fmaxf(v, 0.f);
                C[(size_t)row * ldc + col0 + col] = v;
            }
        }
    }
}

// ---------------- importance / top-k
__global__ __launch_bounds__(256)
void importance_kernel(const float* __restrict__ h, const float* __restrict__ wi2,
                       const float* __restrict__ bi2, float* __restrict__ imp)
{
    const int wid = threadIdx.x >> 6, lane = threadIdx.x & 63;
    const int row = blockIdx.x * 4 + wid;
    const float* hr = h + (size_t)row * DH;
    float s = 0.f;
    #pragma unroll
    for (int i = 0; i < DH/64; ++i)
        s = fmaf(hr[lane + i*64], wi2[lane + i*64], s);
    #pragma unroll
    for (int off = 32; off; off >>= 1) s += __shfl_down(s, off);
    if (lane == 0) imp[row] = s + bi2[0];
}

__global__ __launch_bounds__(256)
void rank_kernel(const float* __restrict__ imp, int* __restrict__ flags)
{
    __shared__ float simp[SS];
    const int b = blockIdx.y;
    const int t = threadIdx.x;
    const float* bimp = imp + b * SS;
    for (int i = t; i < SS/4; i += 256)
        reinterpret_cast<float4*>(simp)[i] = reinterpret_cast<const float4*>(bimp)[i];
    __syncthreads();

    const int i = blockIdx.x * 32 + (t >> 3);
    const int part = t & 7;
    const float v = simp[i];
    const float4* slice = reinterpret_cast<const float4*>(simp + part * (SS/8));
    const int jb = part * (SS/8);
    int rank = 0;
    #pragma unroll 8
    for (int jj = 0; jj < SS/32; ++jj) {
        const float4 u4 = slice[jj];
        const int j = jb + jj * 4;
        rank += (u4.x > v) || ((u4.x == v) && (j + 0 < i));
        rank += (u4.y > v) || ((u4.y == v) && (j + 1 < i));
        rank += (u4.z > v) || ((u4.z == v) && (j + 2 < i));
        rank += (u4.w > v) || ((u4.w == v) && (j + 3 < i));
    }
    rank += __shfl_xor(rank, 1);
    rank += __shfl_xor(rank, 2);
    rank += __shfl_xor(rank, 4);
    if (part == 0) flags[b * SS + i] = (rank < KSEL) ? 1 : 0;
}

__global__ __launch_bounds__(256)
void compact_kernel(const int* __restrict__ flags, int* __restrict__ idxg)
{
    __shared__ int sscan[SS];
    __shared__ int sidx[KSEL];
    const int b = blockIdx.x, t = threadIdx.x;
    for (int i = t; i < SS; i += 256) sscan[i] = flags[b * SS + i];
    __syncthreads();
    for (int off = 1; off < SS; off <<= 1) {
        int vals[SS/256];
        #pragma unroll
        for (int c = 0; c < SS/256; ++c) {
            const int i = t + c * 256;
            int v = sscan[i];
            if (i >= off) v += sscan[i - off];
            vals[c] = v;
        }
        __syncthreads();
        #pragma unroll
        for (int c = 0; c < SS/256; ++c) sscan[t + c * 256] = vals[c];
        __syncthreads();
    }
    for (int i = t; i < SS; i += 256) {
        const int f = flags[b * SS + i];
        if (f) sidx[sscan[i] - 1] = i;
    }
    __syncthreads();
    for (int p = t; p < KPAD; p += 256)
        idxg[b * KPAD + p] = sidx[min(p, KSEL - 1)];
}

// ---------------- one-shot K/V gather (bf16 source) + V transpose, CHUNK-CONTIGUOUS
// Kg[b][h][c][64 keys][64 d] ; Vg[b][h][c][64 d][64 keys] with key-col swizzle ^(8*(d>>4))
__global__ __launch_bounds__(256)
void gather_kv(const short* __restrict__ QKVb, const int* __restrict__ idxg,
               short* __restrict__ Kg, short* __restrict__ Vg)
{
    __shared__ short Vs[64*72];   // [d][key] padded
    const int t = threadIdx.x;
    const int c = blockIdx.x, h = blockIdx.y, b = blockIdx.z;
    const int srow = t >> 2;
    const int sq4  = t & 3;

    const size_t cbase = ((size_t)(b * HHD + h) * NCH + c) * 4096;

    const int krow = idxg[b * KPAD + c * 64 + srow];
    const short* kb = QKVb + (size_t)(b * SS + krow) * QKVS + 1024 + h * HD + sq4 * 16;
    bf16x8 k0 = *reinterpret_cast<const bf16x8*>(kb);
    bf16x8 k1 = *reinterpret_cast<const bf16x8*>(kb + 8);
    short* kout = Kg + cbase + srow * HD + sq4 * 16;
    *reinterpret_cast<bf16x8*>(kout)     = k0;
    *reinterpret_cast<bf16x8*>(kout + 8) = k1;

    const short* vbp = kb + 1024;
    bf16x8 v0 = *reinterpret_cast<const bf16x8*>(vbp);
    bf16x8 v1 = *reinterpret_cast<const bf16x8*>(vbp + 8);
    #pragma unroll
    for (int j = 0; j < 8; ++j) {
        Vs[(sq4 * 16 + j) * 72 + srow]     = v0[j];
        Vs[(sq4 * 16 + 8 + j) * 72 + srow] = v1[j];
    }
    __syncthreads();

    const int x = 8 * (srow >> 4);
    short* vout = Vg + cbase + srow * 64;
    *reinterpret_cast<bf16x8*>(vout + ((sq4 * 16)     ^ x)) = *reinterpret_cast<const bf16x8*>(&Vs[srow * 72 + sq4 * 16]);
    *reinterpret_cast<bf16x8*>(vout + ((sq4 * 16 + 8) ^ x)) = *reinterpret_cast<const bf16x8*>(&Vs[srow * 72 + sq4 * 16 + 8]);
}

// ---------------- MFMA sparse flash attention: no-max softmax, ones-column denom,
// double-buffered LDS; Q pre-scaled bf16 straight from global; bf16 output only
__global__ __launch_bounds__(256)
void attn_mfma(const short* __restrict__ QKVb, const short* __restrict__ Kg,
               const short* __restrict__ Vg, short* __restrict__ AOhi)
{
    __shared__ short Ks[2][64*72];
    __shared__ short Vs[2][64*72];
    __shared__ short Ps[4][16*72];

    const int t = threadIdx.x;
    const int lane = t & 63, w = t >> 6;
    const int g = lane >> 4, r = lane & 15;
    const int qt = blockIdx.x, h = blockIdx.y, b = blockIdx.z;
    const int q0 = qt * 64;
    short* Psw = &Ps[w][0];

    const int srow = t >> 2;
    const int scol = (t & 3) * 16;
    const short* kcbase = Kg + ((size_t)(b * HHD + h) * NCH) * 4096 + srow * 64 + scol;
    const short* vcbase = Vg + ((size_t)(b * HHD + h) * NCH) * 4096 + srow * 64 + scol;

    // Q fragments: already bf16 and pre-scaled by 1/8 in the QKV GEMM epilogue
    bf16x8 qh[2];
    {
        const short* qrow = QKVb + (size_t)(b * SS + q0 + w * 16 + r) * QKVS + h * HD;
        qh[0] = *reinterpret_cast<const bf16x8*>(qrow + 8 * g);
        qh[1] = *reinterpret_cast<const bf16x8*>(qrow + 32 + 8 * g);
    }

    bf16x8 ones;
    #pragma unroll
    for (int j = 0; j < 8; ++j) ones[j] = (short)0x3F80;

    f32x4 oacc[4];
    #pragma unroll
    for (int dt = 0; dt < 4; ++dt) oacc[dt] = (f32x4){0.f, 0.f, 0.f, 0.f};
    f32x4 dacc = (f32x4){0.f, 0.f, 0.f, 0.f};

    bf16x8 kreg0 = *reinterpret_cast<const bf16x8*>(kcbase);
    bf16x8 kreg1 = *reinterpret_cast<const bf16x8*>(kcbase + 8);
    bf16x8 vreg0 = *reinterpret_cast<const bf16x8*>(vcbase);
    bf16x8 vreg1 = *reinterpret_cast<const bf16x8*>(vcbase + 8);

    for (int c = 0; c < NCH; ++c) {
        const int cur = c & 1;
        *reinterpret_cast<bf16x8*>(&Ks[cur][srow*72 + scol])     = kreg0;
        *reinterpret_cast<bf16x8*>(&Ks[cur][srow*72 + scol + 8]) = kreg1;
        *reinterpret_cast<bf16x8*>(&Vs[cur][srow*72 + scol])     = vreg0;
        *reinterpret_cast<bf16x8*>(&Vs[cur][srow*72 + scol + 8]) = vreg1;
        if (c + 1 < NCH) {
            const short* kn = kcbase + (size_t)(c + 1) * 4096;
            const short* vn = vcbase + (size_t)(c + 1) * 4096;
            kreg0 = *reinterpret_cast<const bf16x8*>(kn);
            kreg1 = *reinterpret_cast<const bf16x8*>(kn + 8);
            vreg0 = *reinterpret_cast<const bf16x8*>(vn);
            vreg1 = *reinterpret_cast<const bf16x8*>(vn + 8);
        }
        __syncthreads();

        f32x4 sa[4];
        #pragma unroll
        for (int kt = 0; kt < 4; ++kt) {
            bf16x8 kf0 = *reinterpret_cast<const bf16x8*>(&Ks[cur][(kt*16 + r)*72 + 8*g]);
            bf16x8 kf1 = *reinterpret_cast<const bf16x8*>(&Ks[cur][(kt*16 + r)*72 + 32 + 8*g]);
            f32x4 s = (f32x4){0.f, 0.f, 0.f, 0.f};
            s = __builtin_amdgcn_mfma_f32_16x16x32_bf16(qh[0], kf0, s, 0, 0, 0);
            s = __builtin_amdgcn_mfma_f32_16x16x32_bf16(qh[1], kf1, s, 0, 0, 0);
            sa[kt] = s;
        }
        if (c == NCH - 1) {
            #pragma unroll
            for (int kt = 0; kt < 4; ++kt)
                if (c*64 + kt*16 + r >= KSEL)
                    sa[kt] = (f32x4){-INFINITY, -INFINITY, -INFINITY, -INFINITY};
        }

        #pragma unroll
        for (int kt = 0; kt < 4; ++kt)
            #pragma unroll
            for (int e = 0; e < 4; ++e)
                Psw[(4*g + e)*72 + ((kt*16 + r) ^ (8*g))] = bf16rne(__expf(sa[kt][e]));

        #pragma unroll
        for (int kc = 0; kc < 2; ++kc) {
            bf16x8 pf = *reinterpret_cast<const bf16x8*>(&Psw[r*72 + kc*32 + 8*(g ^ (r >> 2))]);
            dacc = __builtin_amdgcn_mfma_f32_16x16x32_bf16(pf, ones, dacc, 0, 0, 0);
            #pragma unroll
            for (int dt = 0; dt < 4; ++dt) {
                bf16x8 vf = *reinterpret_cast<const bf16x8*>(&Vs[cur][(dt*16 + r)*72 + kc*32 + 8*(g ^ dt)]);
                oacc[dt] = __builtin_amdgcn_mfma_f32_16x16x32_bf16(pf, vf, oacc[dt], 0, 0, 0);
            }
        }
    }

    #pragma unroll
    for (int dt = 0; dt < 4; ++dt)
        #pragma unroll
        for (int e = 0; e < 4; ++e) {
            const size_t a = (size_t)(b * SS + q0 + w*16 + 4*g + e) * DD + h * HD + dt*16 + r;
            AOhi[a] = bf16rne(oacc[dt][e] / dacc[e]);
        }
}

extern "C" void kernel_launch(void* const* d_in, const int* in_sizes, int n_in,
                              void* d_out, int out_size, void* d_ws, size_t ws_size,
                              hipStream_t stream)
{
    const float* x   = (const float*)d_in[0];
    const float* wq  = (const float*)d_in[1];
    const float* bq  = (const float*)d_in[2];
    const float* wk  = (const float*)d_in[3];
    const float* bk  = (const float*)d_in[4];
    const float* wv  = (const float*)d_in[5];
    const float* bv  = (const float*)d_in[6];
    const float* wo  = (const float*)d_in[7];
    const float* bo  = (const float*)d_in[8];
    const float* wi1 = (const float*)d_in[9];
    const float* bi1 = (const float*)d_in[10];
    const float* wi2 = (const float*)d_in[11];
    const float* bi2 = (const float*)d_in[12];
    float* out = (float*)d_out;

    const size_t MB = 1ull << 20;
    char* W = (char*)d_ws;
    short* x_hi  = (short*)(W + 0);          // 16 MB
    short* x_lo  = (short*)(W + 16*MB);      // 16 MB
    short* QKVb  = (short*)(W + 32*MB);      // 48 MB (8192 x 3072 bf16)
    short* Bqkv_hi=(short*)(W + 128*MB);     // 6 MB (wq,wk,wv hi)
    short* wo_hi = (short*)(W + 134*MB);     // 2 MB
    float* Hw    = (float*)(W + 144*MB);     // 16 MB (dead after importance_kernel)
    float* bqkv  = (float*)(W + 160*MB);
    float* imp   = (float*)(W + 160*MB + 64*1024);
    int*   flags = (int*)(W + 160*MB + 128*1024);
    int*   idxg  = (int*)(W + 160*MB + 192*1024);
    short* Wi_hi = (short*)(W + 96*MB);      // 1 MB (dead region after QKV sizing)
    short* Wi_lo = (short*)(W + 97*MB);      // 1 MB
    short* Kg = (short*)(W + 144*MB);        // 5.25 MB (over dead Hw)
    short* Vg = (short*)(W + 150*MB);
    short* AO_hi = x_hi;                     // x_hi dead after QKV projection

    const size_t NM = (size_t)MTOT * DD;

    // 0. splits + fused bias
    split_convert<<<(NM/4 + 255)/256, 256, 0, stream>>>(x, x_hi, x_lo, NM/4);
    split_weights<<<dim3(DD*DD/4/256, 5), 256, 0, stream>>>(
        wq, wk, wv, wo, wi1, Bqkv_hi, wo_hi, Wi_hi, Wi_lo);
    concat_bias3<<<QKVS/256, 256, 0, stream>>>(bq, bk, bv, bqkv);

    // 1. indexer h = relu(x @ wi1^T + bi1)  -- 3-term split (top-k critical)
    gemm_split<true><<<dim3(DH/128, MTOT/128), 256, 0, stream>>>(
        x_hi, x_lo, Wi_hi, Wi_lo, bi1, Hw, MTOT, DH, DD, DH);
    // 2-3. importance + top-k
    importance_kernel<<<MTOT/4, 256, 0, stream>>>(Hw, wi2, bi2, imp);
    rank_kernel<<<dim3(SS/32, BB), 256, 0, stream>>>(imp, flags);
    compact_kernel<<<BB, 256, 0, stream>>>(flags, idxg);

    // 4. fused QKV projection: 1-term bf16, BK=64, bf16 output, Q cols pre-scaled by 1/8
    gemm_bf16<true, true><<<dim3(QKVS/128, MTOT/128), 256, 0, stream>>>(
        x_hi, Bqkv_hi, bqkv, QKVb, MTOT, QKVS, DD, QKVS);

    // 4c. one-shot gather K/V (bf16) chunk-contiguous (Hw region now dead)
    gather_kv<<<dim3(NCH, HHD, BB), 256, 0, stream>>>(QKVb, idxg, Kg, Vg);

    // 5. no-max-softmax MFMA sparse flash attention -> bf16
    attn_mfma<<<dim3(SS/64, HHD, BB), 256, 0, stream>>>(QKVb, Kg, Vg, AO_hi);

    // 6. output projection: 1-term bf16 BK=64 (input-rounding error ~1.4e-4, below floor)
    gemm_bf16<false, false><<<dim3(DD/128, MTOT/128), 256, 0, stream>>>(
        AO_hi, wo_hi, bo, out, MTOT, DD, DD, DD);
}

// Round 12
// 211.525 us; speedup vs baseline: 2.3133x; 1.0904x over previous
//
#include <hip/hip_runtime.h>
#include <math.h>

#define BB 4
#define SS 2048
#define DD 1024
#define HHD 16      // heads
#define HD 64       // head dim
#define DH 512      // indexer hidden
#define KSEL 614    // top-k count
#define KPAD 640    // padded to multiple of 64
#define MTOT (BB*SS)
#define NCH (KPAD/64)
#define MKV (BB*KPAD)   // 2560 gathered K/V rows

typedef __attribute__((ext_vector_type(8))) short bf16x8;
typedef __attribute__((ext_vector_type(4))) float f32x4;

#define LDS_CAST(p) ((__attribute__((address_space(3))) void*)(p))
#define GLB_CAST(p) ((const __attribute__((address_space(1))) void*)(p))

// ---------------- fp32 -> bf16 helpers (RNE)
__device__ inline short bf16rne(float v)
{
    unsigned u = __builtin_bit_cast(unsigned, v);
    return (short)((u + 0x7FFFu + ((u >> 16) & 1u)) >> 16);
}

__device__ inline void split1(float v, short& h, short& l)
{
    unsigned u = __builtin_bit_cast(unsigned, v);
    unsigned hr = (u + 0x7FFFu + ((u >> 16) & 1u)) >> 16;
    h = (short)hr;
    float hf = __builtin_bit_cast(float, hr << 16);
    float res = v - hf;
    unsigned u2 = __builtin_bit_cast(unsigned, res);
    unsigned lr = (u2 + 0x7FFFu + ((u2 >> 16) & 1u)) >> 16;
    l = (short)lr;
}

__global__ __launch_bounds__(256)
void split_convert(const float* __restrict__ in, short* __restrict__ hi,
                   short* __restrict__ lo, int n4)
{
    const int i = blockIdx.x * 256 + threadIdx.x;
    if (i >= n4) return;
    float4 v = reinterpret_cast<const float4*>(in)[i];
    short4 h, l;
    split1(v.x, h.x, l.x);
    split1(v.y, h.y, l.y);
    split1(v.z, h.z, l.z);
    split1(v.w, h.w, l.w);
    reinterpret_cast<short4*>(hi)[i] = h;
    reinterpret_cast<short4*>(lo)[i] = l;
}

// fused weight splits: y=0 wq(hi), 1 wk(hi), 2 wv(hi), 3 wo(hi), 4 wi1(hi+lo)
__global__ __launch_bounds__(256)
void split_weights(const float* __restrict__ wq, const float* __restrict__ wk,
                   const float* __restrict__ wv, const float* __restrict__ wo,
                   const float* __restrict__ wi1,
                   short* __restrict__ Bqkv_hi, short* __restrict__ wo_hi,
                   short* __restrict__ Wi_hi, short* __restrict__ Wi_lo)
{
    const int i = blockIdx.x * 256 + threadIdx.x;
    const int which = blockIdx.y;
    if (which < 4) {
        const float* src = (which == 0) ? wq : (which == 1) ? wk : (which == 2) ? wv : wo;
        short* dst = (which == 3) ? wo_hi : (Bqkv_hi + (size_t)which * DD * DD);
        float4 v = reinterpret_cast<const float4*>(src)[i];
        short4 hh;
        hh.x = bf16rne(v.x); hh.y = bf16rne(v.y); hh.z = bf16rne(v.z); hh.w = bf16rne(v.w);
        reinterpret_cast<short4*>(dst)[i] = hh;
    } else {
        if (i >= DH*DD/4) return;
        float4 v = reinterpret_cast<const float4*>(wi1)[i];
        short4 h, l;
        split1(v.x, h.x, l.x); split1(v.y, h.y, l.y);
        split1(v.z, h.z, l.z); split1(v.w, h.w, l.w);
        reinterpret_cast<short4*>(Wi_hi)[i] = h;
        reinterpret_cast<short4*>(Wi_lo)[i] = l;
    }
}

__global__ __launch_bounds__(256)
void concat_bias2(const float* __restrict__ a, const float* __restrict__ b,
                  float* __restrict__ o)
{
    const int i = blockIdx.x * 256 + threadIdx.x;   // 2048
    o[i] = (i < 1024) ? a[i] : b[i - 1024];
}

// ---------------- plain bf16 MFMA GEMM, BK=64: C = A @ B^T + bias
// 128x128 tile, 4 waves, 32 MFMA/barrier, 8-slot XOR swizzle (conflict-free, r10-verified).
// BF16_OUT: emit bf16. QSCALE: cols<1024 scaled by 1/8 before rounding (Q-proj).
template<bool BF16_OUT, bool QSCALE>
__global__ __launch_bounds__(256)
void gemm_bf16(const short* __restrict__ Ahi, const short* __restrict__ Bhi,
               const float* __restrict__ bias, void* __restrict__ Cv,
               int M, int N, int K, int ldc)
{
    __shared__ short sAh[128*64];
    __shared__ short sBh[128*64];

    const int t = threadIdx.x;
    const int lane = t & 63, wid = t >> 6;
    const int wm = wid >> 1, wn = wid & 1;
    const int row0 = blockIdx.y * 128, col0 = blockIdx.x * 128;
    const int g = lane >> 4, r = lane & 15;
    const int lrow = lane >> 3;
    const int lslot = lane & 7;

    f32x4 acc[4][4];
    #pragma unroll
    for (int mt = 0; mt < 4; ++mt)
        #pragma unroll
        for (int nt = 0; nt < 4; ++nt) acc[mt][nt] = (f32x4){0.f, 0.f, 0.f, 0.f};

    for (int k0 = 0; k0 < K; k0 += 64) {
        #pragma unroll
        for (int e = 0; e < 4; ++e) {
            const int rl = wid * 32 + e * 8 + lrow;
            const int scol = k0 + ((lslot ^ (rl & 7)) << 3);
            const size_t ga = (size_t)(row0 + rl) * K + scol;
            const size_t gb = (size_t)(col0 + rl) * K + scol;
            const int ldso = (wid * 32 + e * 8) * 64;
            __builtin_amdgcn_global_load_lds(GLB_CAST(Ahi + ga), LDS_CAST(sAh + ldso), 16, 0, 0);
            __builtin_amdgcn_global_load_lds(GLB_CAST(Bhi + gb), LDS_CAST(sBh + ldso), 16, 0, 0);
        }
        __syncthreads();

        #pragma unroll
        for (int kk = 0; kk < 2; ++kk) {
            bf16x8 ah[4], bh[4];
            #pragma unroll
            for (int mt = 0; mt < 4; ++mt) {
                const int rw = wm * 64 + mt * 16 + r;
                ah[mt] = *reinterpret_cast<const bf16x8*>(sAh + rw * 64 + (((kk*4 + g) ^ (rw & 7)) << 3));
            }
            #pragma unroll
            for (int nt = 0; nt < 4; ++nt) {
                const int rw = wn * 64 + nt * 16 + r;
                bh[nt] = *reinterpret_cast<const bf16x8*>(sBh + rw * 64 + (((kk*4 + g) ^ (rw & 7)) << 3));
            }
            #pragma unroll
            for (int mt = 0; mt < 4; ++mt)
                #pragma unroll
                for (int nt = 0; nt < 4; ++nt)
                    acc[mt][nt] = __builtin_amdgcn_mfma_f32_16x16x32_bf16(ah[mt], bh[nt], acc[mt][nt], 0, 0, 0);
        }
        __syncthreads();
    }

    #pragma unroll
    for (int nt = 0; nt < 4; ++nt) {
        const int col = wn * 64 + nt * 16 + r;
        const float bv = bias[col0 + col];
        const bool qs = QSCALE && (col0 + col) < 1024;
        #pragma unroll
        for (int mt = 0; mt < 4; ++mt) {
            #pragma unroll
            for (int e = 0; e < 4; ++e) {
                const int row = row0 + wm * 64 + mt * 16 + 4 * g + e;
                float v = acc[mt][nt][e] + bv;
                if (qs) v *= 0.125f;
                if (BF16_OUT)
                    ((short*)Cv)[(size_t)row * ldc + col0 + col] = bf16rne(v);
                else
                    ((float*)Cv)[(size_t)row * ldc + col0 + col] = v;
            }
        }
    }
}

// ---------------- gathered KV GEMM: C[MKV,2048] = x_hi[idx rows] @ [wk;wv]^T + bias
// Same BK=64 swizzled structure; A rows gathered via idxg (per-lane global src).
__global__ __launch_bounds__(256)
void gemm_kv_gather(const short* __restrict__ Ahi, const short* __restrict__ Bhi,
                    const int* __restrict__ idxg, const float* __restrict__ bias,
                    short* __restrict__ C)
{
    __shared__ short sAh[128*64];
    __shared__ short sBh[128*64];

    const int K = DD, N = 2048;
    const int t = threadIdx.x;
    const int lane = t & 63, wid = t >> 6;
    const int wm = wid >> 1, wn = wid & 1;
    const int row0 = blockIdx.y * 128, col0 = blockIdx.x * 128;
    const int g = lane >> 4, r = lane & 15;
    const int lrow = lane >> 3;
    const int lslot = lane & 7;

    // gathered A-row base offsets (4 staged rows per thread, fixed across K)
    size_t garow[4];
    #pragma unroll
    for (int e = 0; e < 4; ++e) {
        const int rl = row0 + wid * 32 + e * 8 + lrow;    // 0..2559
        const int grow = (rl / KPAD) * SS + idxg[rl];
        garow[e] = (size_t)grow * K;
    }

    f32x4 acc[4][4];
    #pragma unroll
    for (int mt = 0; mt < 4; ++mt)
        #pragma unroll
        for (int nt = 0; nt < 4; ++nt) acc[mt][nt] = (f32x4){0.f, 0.f, 0.f, 0.f};

    for (int k0 = 0; k0 < K; k0 += 64) {
        #pragma unroll
        for (int e = 0; e < 4; ++e) {
            const int rl = wid * 32 + e * 8 + lrow;
            const int scol = k0 + ((lslot ^ (rl & 7)) << 3);
            const size_t gb = (size_t)(col0 + rl) * K + scol;
            const int ldso = (wid * 32 + e * 8) * 64;
            __builtin_amdgcn_global_load_lds(GLB_CAST(Ahi + garow[e] + scol), LDS_CAST(sAh + ldso), 16, 0, 0);
            __builtin_amdgcn_global_load_lds(GLB_CAST(Bhi + gb), LDS_CAST(sBh + ldso), 16, 0, 0);
        }
        __syncthreads();

        #pragma unroll
        for (int kk = 0; kk < 2; ++kk) {
            bf16x8 ah[4], bh[4];
            #pragma unroll
            for (int mt = 0; mt < 4; ++mt) {
                const int rw = wm * 64 + mt * 16 + r;
                ah[mt] = *reinterpret_cast<const bf16x8*>(sAh + rw * 64 + (((kk*4 + g) ^ (rw & 7)) << 3));
            }
            #pragma unroll
            for (int nt = 0; nt < 4; ++nt) {
                const int rw = wn * 64 + nt * 16 + r;
                bh[nt] = *reinterpret_cast<const bf16x8*>(sBh + rw * 64 + (((kk*4 + g) ^ (rw & 7)) << 3));
            }
            #pragma unroll
            for (int mt = 0; mt < 4; ++mt)
                #pragma unroll
                for (int nt = 0; nt < 4; ++nt)
                    acc[mt][nt] = __builtin_amdgcn_mfma_f32_16x16x32_bf16(ah[mt], bh[nt], acc[mt][nt], 0, 0, 0);
        }
        __syncthreads();
    }

    #pragma unroll
    for (int nt = 0; nt < 4; ++nt) {
        const int col = wn * 64 + nt * 16 + r;
        const float bv = bias[col0 + col];
        #pragma unroll
        for (int mt = 0; mt < 4; ++mt) {
            #pragma unroll
            for (int e = 0; e < 4; ++e) {
                const int row = row0 + wm * 64 + mt * 16 + 4 * g + e;
                C[(size_t)row * N + col0 + col] = bf16rne(acc[mt][nt][e] + bv);
            }
        }
    }
}

// ---------------- split-bf16 MFMA GEMM (3-term): indexer only
template<bool RELU>
__global__ __launch_bounds__(256)
void gemm_split(const short* __restrict__ Ahi, const short* __restrict__ Alo,
                const short* __restrict__ Bhi, const short* __restrict__ Blo,
                const float* __restrict__ bias, float* __restrict__ C,
                int M, int N, int K, int ldc)
{
    __shared__ short sAh[128*32];
    __shared__ short sAl[128*32];
    __shared__ short sBh[128*32];
    __shared__ short sBl[128*32];

    const int t = threadIdx.x;
    const int lane = t & 63, wid = t >> 6;
    const int wm = wid >> 1, wn = wid & 1;
    const int row0 = blockIdx.y * 128, col0 = blockIdx.x * 128;
    const int g = lane >> 4, r = lane & 15;
    const int sw = g ^ ((lane >> 2) & 3);
    const int srow = lane >> 2;
    const int sslot = lane & 3;

    f32x4 acc[4][4];
    #pragma unroll
    for (int mt = 0; mt < 4; ++mt)
        #pragma unroll
        for (int nt = 0; nt < 4; ++nt) acc[mt][nt] = (f32x4){0.f, 0.f, 0.f, 0.f};

    for (int k0 = 0; k0 < K; k0 += 32) {
        #pragma unroll
        for (int i = 0; i < 2; ++i) {
            const int rl = wid * 32 + i * 16 + srow;
            const int scol = k0 + ((sslot ^ ((rl >> 2) & 3)) << 3);
            const size_t ga = (size_t)(row0 + rl) * K + scol;
            const size_t gb = (size_t)(col0 + rl) * K + scol;
            const int ldso = (wid * 32 + i * 16) * 32;
            __builtin_amdgcn_global_load_lds(GLB_CAST(Ahi + ga), LDS_CAST(sAh + ldso), 16, 0, 0);
            __builtin_amdgcn_global_load_lds(GLB_CAST(Alo + ga), LDS_CAST(sAl + ldso), 16, 0, 0);
            __builtin_amdgcn_global_load_lds(GLB_CAST(Bhi + gb), LDS_CAST(sBh + ldso), 16, 0, 0);
            __builtin_amdgcn_global_load_lds(GLB_CAST(Blo + gb), LDS_CAST(sBl + ldso), 16, 0, 0);
        }
        __syncthreads();

        bf16x8 ah[4], al[4], bh[4], bl[4];
        #pragma unroll
        for (int mt = 0; mt < 4; ++mt) {
            const int row = wm * 64 + mt * 16 + r;
            ah[mt] = *reinterpret_cast<const bf16x8*>(sAh + row * 32 + sw * 8);
            al[mt] = *reinterpret_cast<const bf16x8*>(sAl + row * 32 + sw * 8);
        }
        #pragma unroll
        for (int nt = 0; nt < 4; ++nt) {
            const int row = wn * 64 + nt * 16 + r;
            bh[nt] = *reinterpret_cast<const bf16x8*>(sBh + row * 32 + sw * 8);
            bl[nt] = *reinterpret_cast<const bf16x8*>(sBl + row * 32 + sw * 8);
        }
        #pragma unroll
        for (int mt = 0; mt < 4; ++mt)
            #pragma unroll
            for (int nt = 0; nt < 4; ++nt) {
                acc[mt][nt] = __builtin_amdgcn_mfma_f32_16x16x32_bf16(ah[mt], bh[nt], acc[mt][nt], 0, 0, 0);
                acc[mt][nt] = __builtin_amdgcn_mfma_f32_16x16x32_bf16(ah[mt], bl[nt], acc[mt][nt], 0, 0, 0);
                acc[mt][nt] = __builtin_amdgcn_mfma_f32_16x16x32_bf16(al[mt], bh[nt], acc[mt][nt], 0, 0, 0);
            }
        __syncthreads();
    }

    #pragma unroll
    for (int nt = 0; nt < 4; ++nt) {
        const int col = wn * 64 + nt * 16 + r;
        const float bv = bias[col0 + col];
        #pragma unroll
        for (int mt = 0; mt < 4; ++mt) {
            #pragma unroll
            for (int e = 0; e < 4; ++e) {
                const int row = row0 + wm * 64 + mt * 16 + 4 * g + e;
                float v = acc[mt][nt][e] + bv;
                if (RELU) v = fmaxf(v, 0.f);
                C[(size_t)row * ldc + col0 + col] = v;
            }
        }
    }
}

// ---------------- importance / top-k
__global__ __launch_bounds__(256)
void importance_kernel(const float* __restrict__ h, const float* __restrict__ wi2,
                       const float* __restrict__ bi2, float* __restrict__ imp)
{
    const int wid = threadIdx.x >> 6, lane = threadIdx.x & 63;
    const int row = blockIdx.x * 4 + wid;
    const float* hr = h + (size_t)row * DH;
    float s = 0.f;
    #pragma unroll
    for (int i = 0; i < DH/64; ++i)
        s = fmaf(hr[lane + i*64], wi2[lane + i*64], s);
    #pragma unroll
    for (int off = 32; off; off >>= 1) s += __shfl_down(s, off);
    if (lane == 0) imp[row] = s + bi2[0];
}

__global__ __launch_bounds__(256)
void rank_kernel(const float* __restrict__ imp, int* __restrict__ flags)
{
    __shared__ float simp[SS];
    const int b = blockIdx.y;
    const int t = threadIdx.x;
    const float* bimp = imp + b * SS;
    for (int i = t; i < SS/4; i += 256)
        reinterpret_cast<float4*>(simp)[i] = reinterpret_cast<const float4*>(bimp)[i];
    __syncthreads();

    const int i = blockIdx.x * 32 + (t >> 3);
    const int part = t & 7;
    const float v = simp[i];
    const float4* slice = reinterpret_cast<const float4*>(simp + part * (SS/8));
    const int jb = part * (SS/8);
    int rank = 0;
    #pragma unroll 8
    for (int jj = 0; jj < SS/32; ++jj) {
        const float4 u4 = slice[jj];
        const int j = jb + jj * 4;
        rank += (u4.x > v) || ((u4.x == v) && (j + 0 < i));
        rank += (u4.y > v) || ((u4.y == v) && (j + 1 < i));
        rank += (u4.z > v) || ((u4.z == v) && (j + 2 < i));
        rank += (u4.w > v) || ((u4.w == v) && (j + 3 < i));
    }
    rank += __shfl_xor(rank, 1);
    rank += __shfl_xor(rank, 2);
    rank += __shfl_xor(rank, 4);
    if (part == 0) flags[b * SS + i] = (rank < KSEL) ? 1 : 0;
}

__global__ __launch_bounds__(256)
void compact_kernel(const int* __restrict__ flags, int* __restrict__ idxg)
{
    __shared__ int sscan[SS];
    __shared__ int sidx[KSEL];
    const int b = blockIdx.x, t = threadIdx.x;
    for (int i = t; i < SS; i += 256) sscan[i] = flags[b * SS + i];
    __syncthreads();
    for (int off = 1; off < SS; off <<= 1) {
        int vals[SS/256];
        #pragma unroll
        for (int c = 0; c < SS/256; ++c) {
            const int i = t + c * 256;
            int v = sscan[i];
            if (i >= off) v += sscan[i - off];
            vals[c] = v;
        }
        __syncthreads();
        #pragma unroll
        for (int c = 0; c < SS/256; ++c) sscan[t + c * 256] = vals[c];
        __syncthreads();
    }
    for (int i = t; i < SS; i += 256) {
        const int f = flags[b * SS + i];
        if (f) sidx[sscan[i] - 1] = i;
    }
    __syncthreads();
    for (int p = t; p < KPAD; p += 256)
        idxg[b * KPAD + p] = sidx[min(p, KSEL - 1)];
}

// ---------------- K/V relayout from compact KVc: chunk-contiguous Kg + transposed/swizzled Vg
// KVc[b*KPAD + p][2048]: cols 0..1023 = K, 1024..2047 = V
__global__ __launch_bounds__(256)
void gather_kv(const short* __restrict__ KVc, short* __restrict__ Kg,
               short* __restrict__ Vg)
{
    __shared__ short Vs[64*72];   // [d][key] padded
    const int t = threadIdx.x;
    const int c = blockIdx.x, h = blockIdx.y, b = blockIdx.z;
    const int srow = t >> 2;
    const int sq4  = t & 3;

    const size_t cbase = ((size_t)(b * HHD + h) * NCH + c) * 4096;

    const short* kb = KVc + (size_t)(b * KPAD + c * 64 + srow) * 2048 + h * HD + sq4 * 16;
    bf16x8 k0 = *reinterpret_cast<const bf16x8*>(kb);
    bf16x8 k1 = *reinterpret_cast<const bf16x8*>(kb + 8);
    short* kout = Kg + cbase + srow * HD + sq4 * 16;
    *reinterpret_cast<bf16x8*>(kout)     = k0;
    *reinterpret_cast<bf16x8*>(kout + 8) = k1;

    const short* vbp = kb + 1024;
    bf16x8 v0 = *reinterpret_cast<const bf16x8*>(vbp);
    bf16x8 v1 = *reinterpret_cast<const bf16x8*>(vbp + 8);
    #pragma unroll
    for (int j = 0; j < 8; ++j) {
        Vs[(sq4 * 16 + j) * 72 + srow]     = v0[j];
        Vs[(sq4 * 16 + 8 + j) * 72 + srow] = v1[j];
    }
    __syncthreads();

    const int x = 8 * (srow >> 4);
    short* vout = Vg + cbase + srow * 64;
    *reinterpret_cast<bf16x8*>(vout + ((sq4 * 16)     ^ x)) = *reinterpret_cast<const bf16x8*>(&Vs[srow * 72 + sq4 * 16]);
    *reinterpret_cast<bf16x8*>(vout + ((sq4 * 16 + 8) ^ x)) = *reinterpret_cast<const bf16x8*>(&Vs[srow * 72 + sq4 * 16 + 8]);
}

// ---------------- MFMA sparse flash attention: no-max softmax, ones-column denom,
// double-buffered LDS; Q pre-scaled bf16 from Qb; bf16 output
__global__ __launch_bounds__(256)
void attn_mfma(const short* __restrict__ Qb, const short* __restrict__ Kg,
               const short* __restrict__ Vg, short* __restrict__ AOhi)
{
    __shared__ short Ks[2][64*72];
    __shared__ short Vs[2][64*72];
    __shared__ short Ps[4][16*72];

    const int t = threadIdx.x;
    const int lane = t & 63, w = t >> 6;
    const int g = lane >> 4, r = lane & 15;
    const int qt = blockIdx.x, h = blockIdx.y, b = blockIdx.z;
    const int q0 = qt * 64;
    short* Psw = &Ps[w][0];

    const int srow = t >> 2;
    const int scol = (t & 3) * 16;
    const short* kcbase = Kg + ((size_t)(b * HHD + h) * NCH) * 4096 + srow * 64 + scol;
    const short* vcbase = Vg + ((size_t)(b * HHD + h) * NCH) * 4096 + srow * 64 + scol;

    bf16x8 qh[2];
    {
        const short* qrow = Qb + (size_t)(b * SS + q0 + w * 16 + r) * DD + h * HD;
        qh[0] = *reinterpret_cast<const bf16x8*>(qrow + 8 * g);
        qh[1] = *reinterpret_cast<const bf16x8*>(qrow + 32 + 8 * g);
    }

    bf16x8 ones;
    #pragma unroll
    for (int j = 0; j < 8; ++j) ones[j] = (short)0x3F80;

    f32x4 oacc[4];
    #pragma unroll
    for (int dt = 0; dt < 4; ++dt) oacc[dt] = (f32x4){0.f, 0.f, 0.f, 0.f};
    f32x4 dacc = (f32x4){0.f, 0.f, 0.f, 0.f};

    bf16x8 kreg0 = *reinterpret_cast<const bf16x8*>(kcbase);
    bf16x8 kreg1 = *reinterpret_cast<const bf16x8*>(kcbase + 8);
    bf16x8 vreg0 = *reinterpret_cast<const bf16x8*>(vcbase);
    bf16x8 vreg1 = *reinterpret_cast<const bf16x8*>(vcbase + 8);

    for (int c = 0; c < NCH; ++c) {
        const int cur = c & 1;
        *reinterpret_cast<bf16x8*>(&Ks[cur][srow*72 + scol])     = kreg0;
        *reinterpret_cast<bf16x8*>(&Ks[cur][srow*72 + scol + 8]) = kreg1;
        *reinterpret_cast<bf16x8*>(&Vs[cur][srow*72 + scol])     = vreg0;
        *reinterpret_cast<bf16x8*>(&Vs[cur][srow*72 + scol + 8]) = vreg1;
        if (c + 1 < NCH) {
            const short* kn = kcbase + (size_t)(c + 1) * 4096;
            const short* vn = vcbase + (size_t)(c + 1) * 4096;
            kreg0 = *reinterpret_cast<const bf16x8*>(kn);
            kreg1 = *reinterpret_cast<const bf16x8*>(kn + 8);
            vreg0 = *reinterpret_cast<const bf16x8*>(vn);
            vreg1 = *reinterpret_cast<const bf16x8*>(vn + 8);
        }
        __syncthreads();

        f32x4 sa[4];
        #pragma unroll
        for (int kt = 0; kt < 4; ++kt) {
            bf16x8 kf0 = *reinterpret_cast<const bf16x8*>(&Ks[cur][(kt*16 + r)*72 + 8*g]);
            bf16x8 kf1 = *reinterpret_cast<const bf16x8*>(&Ks[cur][(kt*16 + r)*72 + 32 + 8*g]);
            f32x4 s = (f32x4){0.f, 0.f, 0.f, 0.f};
            s = __builtin_amdgcn_mfma_f32_16x16x32_bf16(qh[0], kf0, s, 0, 0, 0);
            s = __builtin_amdgcn_mfma_f32_16x16x32_bf16(qh[1], kf1, s, 0, 0, 0);
            sa[kt] = s;
        }
        if (c == NCH - 1) {
            #pragma unroll
            for (int kt = 0; kt < 4; ++kt)
                if (c*64 + kt*16 + r >= KSEL)
                    sa[kt] = (f32x4){-INFINITY, -INFINITY, -INFINITY, -INFINITY};
        }

        #pragma unroll
        for (int kt = 0; kt < 4; ++kt)
            #pragma unroll
            for (int e = 0; e < 4; ++e)
                Psw[(4*g + e)*72 + ((kt*16 + r) ^ (8*g))] = bf16rne(__expf(sa[kt][e]));

        #pragma unroll
        for (int kc = 0; kc < 2; ++kc) {
            bf16x8 pf = *reinterpret_cast<const bf16x8*>(&Psw[r*72 + kc*32 + 8*(g ^ (r >> 2))]);
            dacc = __builtin_amdgcn_mfma_f32_16x16x32_bf16(pf, ones, dacc, 0, 0, 0);
            #pragma unroll
            for (int dt = 0; dt < 4; ++dt) {
                bf16x8 vf = *reinterpret_cast<const bf16x8*>(&Vs[cur][(dt*16 + r)*72 + kc*32 + 8*(g ^ dt)]);
                oacc[dt] = __builtin_amdgcn_mfma_f32_16x16x32_bf16(pf, vf, oacc[dt], 0, 0, 0);
            }
        }
    }

    #pragma unroll
    for (int dt = 0; dt < 4; ++dt)
        #pragma unroll
        for (int e = 0; e < 4; ++e) {
            const size_t a = (size_t)(b * SS + q0 + w*16 + 4*g + e) * DD + h * HD + dt*16 + r;
            AOhi[a] = bf16rne(oacc[dt][e] / dacc[e]);
        }
}

extern "C" void kernel_launch(void* const* d_in, const int* in_sizes, int n_in,
                              void* d_out, int out_size, void* d_ws, size_t ws_size,
                              hipStream_t stream)
{
    const float* x   = (const float*)d_in[0];
    const float* wq  = (const float*)d_in[1];
    const float* bq  = (const float*)d_in[2];
    const float* wk  = (const float*)d_in[3];
    const float* bk  = (const float*)d_in[4];
    const float* wv  = (const float*)d_in[5];
    const float* bv  = (const float*)d_in[6];
    const float* wo  = (const float*)d_in[7];
    const float* bo  = (const float*)d_in[8];
    const float* wi1 = (const float*)d_in[9];
    const float* bi1 = (const float*)d_in[10];
    const float* wi2 = (const float*)d_in[11];
    const float* bi2 = (const float*)d_in[12];
    float* out = (float*)d_out;

    const size_t MB = 1ull << 20;
    char* W = (char*)d_ws;
    short* x_hi  = (short*)(W + 0);          // 16 MB
    short* x_lo  = (short*)(W + 16*MB);      // 16 MB
    short* Qb    = (short*)(W + 32*MB);      // 16 MB (8192 x 1024 bf16, pre-scaled 1/8)
    short* KVc   = (short*)(W + 48*MB);      // 10.5 MB (2560 x 2048 bf16)
    short* Wi_hi = (short*)(W + 96*MB);      // 1 MB
    short* Wi_lo = (short*)(W + 97*MB);      // 1 MB
    short* Bqkv_hi=(short*)(W + 128*MB);     // 6 MB (wq,wk,wv hi, stacked)
    short* wo_hi = (short*)(W + 134*MB);     // 2 MB
    float* Hw    = (float*)(W + 144*MB);     // 16 MB (dead after importance_kernel)
    short* Kg    = (short*)(W + 144*MB);     // 5.25 MB (over dead Hw)
    short* Vg    = (short*)(W + 150*MB);     // 5.25 MB
    float* bkv   = (float*)(W + 160*MB);
    float* imp   = (float*)(W + 160*MB + 64*1024);
    int*   flags = (int*)(W + 160*MB + 128*1024);
    int*   idxg  = (int*)(W + 160*MB + 192*1024);
    short* AO_hi = x_hi;                     // x_hi dead after projections

    const size_t NM = (size_t)MTOT * DD;

    // 0. splits + fused bias
    split_convert<<<(NM/4 + 255)/256, 256, 0, stream>>>(x, x_hi, x_lo, NM/4);
    split_weights<<<dim3(DD*DD/4/256, 5), 256, 0, stream>>>(
        wq, wk, wv, wo, wi1, Bqkv_hi, wo_hi, Wi_hi, Wi_lo);
    concat_bias2<<<2048/256, 256, 0, stream>>>(bk, bv, bkv);

    // 1. indexer h = relu(x @ wi1^T + bi1)  -- 3-term split (top-k critical)
    gemm_split<true><<<dim3(DH/128, MTOT/128), 256, 0, stream>>>(
        x_hi, x_lo, Wi_hi, Wi_lo, bi1, Hw, MTOT, DH, DD, DH);
    // 2-3. importance + top-k
    importance_kernel<<<MTOT/4, 256, 0, stream>>>(Hw, wi2, bi2, imp);
    rank_kernel<<<dim3(SS/32, BB), 256, 0, stream>>>(imp, flags);
    compact_kernel<<<BB, 256, 0, stream>>>(flags, idxg);

    // 4a. Q projection: 1-term bf16, pre-scaled by 1/8 (all cols < 1024 -> QSCALE hits all)
    gemm_bf16<true, true><<<dim3(DD/128, MTOT/128), 256, 0, stream>>>(
        x_hi, Bqkv_hi, bq, Qb, MTOT, DD, DD, DD);
    // 4b. gathered K/V projection: only the 2560 selected rows (30% of full work)
    gemm_kv_gather<<<dim3(2048/128, MKV/128), 256, 0, stream>>>(
        x_hi, Bqkv_hi + (size_t)DD*DD, idxg, bkv, KVc);

    // 4c. relayout K/V chunk-contiguous (direct rows, no indirection; Hw dead)
    gather_kv<<<dim3(NCH, HHD, BB), 256, 0, stream>>>(KVc, Kg, Vg);

    // 5. no-max-softmax MFMA sparse flash attention -> bf16
    attn_mfma<<<dim3(SS/64, HHD, BB), 256, 0, stream>>>(Qb, Kg, Vg, AO_hi);

    // 6. output projection: 1-term bf16 BK=64
    gemm_bf16<false, false><<<dim3(DD/128, MTOT/128), 256, 0, stream>>>(
        AO_hi, wo_hi, bo, out, MTOT, DD, DD, DD);
}

// Round 13
// 204.289 us; speedup vs baseline: 2.3952x; 1.0354x over previous
//
#include <hip/hip_runtime.h>
#include <math.h>

#define BB 4
#define SS 2048
#define DD 1024
#define HHD 16      // heads
#define HD 64       // head dim
#define DH 512      // indexer hidden
#define KSEL 614    // top-k count
#define KPAD 640    // padded to multiple of 64
#define MTOT (BB*SS)
#define NCH (KPAD/64)
#define MKV (BB*KPAD)   // 2560 gathered K/V rows

typedef __attribute__((ext_vector_type(8))) short bf16x8;
typedef __attribute__((ext_vector_type(4))) float f32x4;

#define LDS_CAST(p) ((__attribute__((address_space(3))) void*)(p))
#define GLB_CAST(p) ((const __attribute__((address_space(1))) void*)(p))

// ---------------- fp32 -> bf16 helpers (RNE)
__device__ inline short bf16rne(float v)
{
    unsigned u = __builtin_bit_cast(unsigned, v);
    return (short)((u + 0x7FFFu + ((u >> 16) & 1u)) >> 16);
}

__device__ inline void split1(float v, short& h, short& l)
{
    unsigned u = __builtin_bit_cast(unsigned, v);
    unsigned hr = (u + 0x7FFFu + ((u >> 16) & 1u)) >> 16;
    h = (short)hr;
    float hf = __builtin_bit_cast(float, hr << 16);
    float res = v - hf;
    unsigned u2 = __builtin_bit_cast(unsigned, res);
    unsigned lr = (u2 + 0x7FFFu + ((u2 >> 16) & 1u)) >> 16;
    l = (short)lr;
}

__global__ __launch_bounds__(256)
void split_convert(const float* __restrict__ in, short* __restrict__ hi,
                   short* __restrict__ lo, int n4)
{
    const int i = blockIdx.x * 256 + threadIdx.x;
    if (i >= n4) return;
    float4 v = reinterpret_cast<const float4*>(in)[i];
    short4 h, l;
    split1(v.x, h.x, l.x);
    split1(v.y, h.y, l.y);
    split1(v.z, h.z, l.z);
    split1(v.w, h.w, l.w);
    reinterpret_cast<short4*>(hi)[i] = h;
    reinterpret_cast<short4*>(lo)[i] = l;
}

// fused weight splits: y=0 wq(hi), 1 wk(hi), 2 wv(hi), 3 wo(hi), 4 wi1(hi+lo)
__global__ __launch_bounds__(256)
void split_weights(const float* __restrict__ wq, const float* __restrict__ wk,
                   const float* __restrict__ wv, const float* __restrict__ wo,
                   const float* __restrict__ wi1,
                   short* __restrict__ Bqkv_hi, short* __restrict__ wo_hi,
                   short* __restrict__ Wi_hi, short* __restrict__ Wi_lo)
{
    const int i = blockIdx.x * 256 + threadIdx.x;
    const int which = blockIdx.y;
    if (which < 4) {
        const float* src = (which == 0) ? wq : (which == 1) ? wk : (which == 2) ? wv : wo;
        short* dst = (which == 3) ? wo_hi : (Bqkv_hi + (size_t)which * DD * DD);
        float4 v = reinterpret_cast<const float4*>(src)[i];
        short4 hh;
        hh.x = bf16rne(v.x); hh.y = bf16rne(v.y); hh.z = bf16rne(v.z); hh.w = bf16rne(v.w);
        reinterpret_cast<short4*>(dst)[i] = hh;
    } else {
        if (i >= DH*DD/4) return;
        float4 v = reinterpret_cast<const float4*>(wi1)[i];
        short4 h, l;
        split1(v.x, h.x, l.x); split1(v.y, h.y, l.y);
        split1(v.z, h.z, l.z); split1(v.w, h.w, l.w);
        reinterpret_cast<short4*>(Wi_hi)[i] = h;
        reinterpret_cast<short4*>(Wi_lo)[i] = l;
    }
}

__global__ __launch_bounds__(256)
void concat_bias2(const float* __restrict__ a, const float* __restrict__ b,
                  float* __restrict__ o)
{
    const int i = blockIdx.x * 256 + threadIdx.x;   // 2048
    o[i] = (i < 1024) ? a[i] : b[i - 1024];
}

// ---------------- plain bf16 MFMA GEMM, BK=64: C = A @ B^T + bias
// 128x128 tile, 4 waves, 32 MFMA/barrier, 8-slot XOR swizzle (conflict-free, r10-verified).
template<bool BF16_OUT, bool QSCALE>
__global__ __launch_bounds__(256)
void gemm_bf16(const short* __restrict__ Ahi, const short* __restrict__ Bhi,
               const float* __restrict__ bias, void* __restrict__ Cv,
               int M, int N, int K, int ldc)
{
    __shared__ short sAh[128*64];
    __shared__ short sBh[128*64];

    const int t = threadIdx.x;
    const int lane = t & 63, wid = t >> 6;
    const int wm = wid >> 1, wn = wid & 1;
    const int row0 = blockIdx.y * 128, col0 = blockIdx.x * 128;
    const int g = lane >> 4, r = lane & 15;
    const int lrow = lane >> 3;
    const int lslot = lane & 7;

    f32x4 acc[4][4];
    #pragma unroll
    for (int mt = 0; mt < 4; ++mt)
        #pragma unroll
        for (int nt = 0; nt < 4; ++nt) acc[mt][nt] = (f32x4){0.f, 0.f, 0.f, 0.f};

    for (int k0 = 0; k0 < K; k0 += 64) {
        #pragma unroll
        for (int e = 0; e < 4; ++e) {
            const int rl = wid * 32 + e * 8 + lrow;
            const int scol = k0 + ((lslot ^ (rl & 7)) << 3);
            const size_t ga = (size_t)(row0 + rl) * K + scol;
            const size_t gb = (size_t)(col0 + rl) * K + scol;
            const int ldso = (wid * 32 + e * 8) * 64;
            __builtin_amdgcn_global_load_lds(GLB_CAST(Ahi + ga), LDS_CAST(sAh + ldso), 16, 0, 0);
            __builtin_amdgcn_global_load_lds(GLB_CAST(Bhi + gb), LDS_CAST(sBh + ldso), 16, 0, 0);
        }
        __syncthreads();

        #pragma unroll
        for (int kk = 0; kk < 2; ++kk) {
            bf16x8 ah[4], bh[4];
            #pragma unroll
            for (int mt = 0; mt < 4; ++mt) {
                const int rw = wm * 64 + mt * 16 + r;
                ah[mt] = *reinterpret_cast<const bf16x8*>(sAh + rw * 64 + (((kk*4 + g) ^ (rw & 7)) << 3));
            }
            #pragma unroll
            for (int nt = 0; nt < 4; ++nt) {
                const int rw = wn * 64 + nt * 16 + r;
                bh[nt] = *reinterpret_cast<const bf16x8*>(sBh + rw * 64 + (((kk*4 + g) ^ (rw & 7)) << 3));
            }
            #pragma unroll
            for (int mt = 0; mt < 4; ++mt)
                #pragma unroll
                for (int nt = 0; nt < 4; ++nt)
                    acc[mt][nt] = __builtin_amdgcn_mfma_f32_16x16x32_bf16(ah[mt], bh[nt], acc[mt][nt], 0, 0, 0);
        }
        __syncthreads();
    }

    #pragma unroll
    for (int nt = 0; nt < 4; ++nt) {
        const int col = wn * 64 + nt * 16 + r;
        const float bv = bias[col0 + col];
        const bool qs = QSCALE && (col0 + col) < 1024;
        #pragma unroll
        for (int mt = 0; mt < 4; ++mt) {
            #pragma unroll
            for (int e = 0; e < 4; ++e) {
                const int row = row0 + wm * 64 + mt * 16 + 4 * g + e;
                float v = acc[mt][nt][e] + bv;
                if (qs) v *= 0.125f;
                if (BF16_OUT)
                    ((short*)Cv)[(size_t)row * ldc + col0 + col] = bf16rne(v);
                else
                    ((float*)Cv)[(size_t)row * ldc + col0 + col] = v;
            }
        }
    }
}

// ---------------- gathered KV GEMM: C[MKV,2048] = x_hi[idx rows] @ [wk;wv]^T + bias
__global__ __launch_bounds__(256)
void gemm_kv_gather(const short* __restrict__ Ahi, const short* __restrict__ Bhi,
                    const int* __restrict__ idxg, const float* __restrict__ bias,
                    short* __restrict__ C)
{
    __shared__ short sAh[128*64];
    __shared__ short sBh[128*64];

    const int K = DD, N = 2048;
    const int t = threadIdx.x;
    const int lane = t & 63, wid = t >> 6;
    const int wm = wid >> 1, wn = wid & 1;
    const int row0 = blockIdx.y * 128, col0 = blockIdx.x * 128;
    const int g = lane >> 4, r = lane & 15;
    const int lrow = lane >> 3;
    const int lslot = lane & 7;

    size_t garow[4];
    #pragma unroll
    for (int e = 0; e < 4; ++e) {
        const int rl = row0 + wid * 32 + e * 8 + lrow;
        const int grow = (rl / KPAD) * SS + idxg[rl];
        garow[e] = (size_t)grow * K;
    }

    f32x4 acc[4][4];
    #pragma unroll
    for (int mt = 0; mt < 4; ++mt)
        #pragma unroll
        for (int nt = 0; nt < 4; ++nt) acc[mt][nt] = (f32x4){0.f, 0.f, 0.f, 0.f};

    for (int k0 = 0; k0 < K; k0 += 64) {
        #pragma unroll
        for (int e = 0; e < 4; ++e) {
            const int rl = wid * 32 + e * 8 + lrow;
            const int scol = k0 + ((lslot ^ (rl & 7)) << 3);
            const size_t gb = (size_t)(col0 + rl) * K + scol;
            const int ldso = (wid * 32 + e * 8) * 64;
            __builtin_amdgcn_global_load_lds(GLB_CAST(Ahi + garow[e] + scol), LDS_CAST(sAh + ldso), 16, 0, 0);
            __builtin_amdgcn_global_load_lds(GLB_CAST(Bhi + gb), LDS_CAST(sBh + ldso), 16, 0, 0);
        }
        __syncthreads();

        #pragma unroll
        for (int kk = 0; kk < 2; ++kk) {
            bf16x8 ah[4], bh[4];
            #pragma unroll
            for (int mt = 0; mt < 4; ++mt) {
                const int rw = wm * 64 + mt * 16 + r;
                ah[mt] = *reinterpret_cast<const bf16x8*>(sAh + rw * 64 + (((kk*4 + g) ^ (rw & 7)) << 3));
            }
            #pragma unroll
            for (int nt = 0; nt < 4; ++nt) {
                const int rw = wn * 64 + nt * 16 + r;
                bh[nt] = *reinterpret_cast<const bf16x8*>(sBh + rw * 64 + (((kk*4 + g) ^ (rw & 7)) << 3));
            }
            #pragma unroll
            for (int mt = 0; mt < 4; ++mt)
                #pragma unroll
                for (int nt = 0; nt < 4; ++nt)
                    acc[mt][nt] = __builtin_amdgcn_mfma_f32_16x16x32_bf16(ah[mt], bh[nt], acc[mt][nt], 0, 0, 0);
        }
        __syncthreads();
    }

    #pragma unroll
    for (int nt = 0; nt < 4; ++nt) {
        const int col = wn * 64 + nt * 16 + r;
        const float bv = bias[col0 + col];
        #pragma unroll
        for (int mt = 0; mt < 4; ++mt) {
            #pragma unroll
            for (int e = 0; e < 4; ++e) {
                const int row = row0 + wm * 64 + mt * 16 + 4 * g + e;
                C[(size_t)row * N + col0 + col] = bf16rne(acc[mt][nt][e] + bv);
            }
        }
    }
}

// ---------------- split-bf16 MFMA GEMM (3-term), 64x128 tile for occupancy:
// grid (N/128, M/64) = 512 blocks = 2 blocks/CU. Each wave: all 64 rows x 32 cols.
// Same BK=32, same 4-slot swizzle, same K-summation order as the 128-tile version
// (bit-identical output -> identical top-k).
template<bool RELU>
__global__ __launch_bounds__(256)
void gemm_split64(const short* __restrict__ Ahi, const short* __restrict__ Alo,
                  const short* __restrict__ Bhi, const short* __restrict__ Blo,
                  const float* __restrict__ bias, float* __restrict__ C,
                  int M, int N, int K, int ldc)
{
    __shared__ short sAh[64*32];
    __shared__ short sAl[64*32];
    __shared__ short sBh[128*32];
    __shared__ short sBl[128*32];

    const int t = threadIdx.x;
    const int lane = t & 63, wid = t >> 6;
    const int row0 = blockIdx.y * 64, col0 = blockIdx.x * 128;
    const int g = lane >> 4, r = lane & 15;
    const int srow = lane >> 2;    // 0..15
    const int sslot = lane & 3;    // 0..3

    f32x4 acc[4][2];
    #pragma unroll
    for (int mt = 0; mt < 4; ++mt)
        #pragma unroll
        for (int nt = 0; nt < 2; ++nt) acc[mt][nt] = (f32x4){0.f, 0.f, 0.f, 0.f};

    for (int k0 = 0; k0 < K; k0 += 32) {
        // A: 64 rows, 1 issue per buffer (wave w covers rows w*16..w*16+15)
        {
            const int rl = wid * 16 + srow;
            const int scol = k0 + ((sslot ^ ((rl >> 2) & 3)) << 3);
            const size_t ga = (size_t)(row0 + rl) * K + scol;
            const int ldso = (wid * 16) * 32;
            __builtin_amdgcn_global_load_lds(GLB_CAST(Ahi + ga), LDS_CAST(sAh + ldso), 16, 0, 0);
            __builtin_amdgcn_global_load_lds(GLB_CAST(Alo + ga), LDS_CAST(sAl + ldso), 16, 0, 0);
        }
        // B: 128 rows, 2 issues per buffer
        #pragma unroll
        for (int i = 0; i < 2; ++i) {
            const int rl = i * 64 + wid * 16 + srow;
            const int scol = k0 + ((sslot ^ ((rl >> 2) & 3)) << 3);
            const size_t gb = (size_t)(col0 + rl) * K + scol;
            const int ldso = (i * 64 + wid * 16) * 32;
            __builtin_amdgcn_global_load_lds(GLB_CAST(Bhi + gb), LDS_CAST(sBh + ldso), 16, 0, 0);
            __builtin_amdgcn_global_load_lds(GLB_CAST(Blo + gb), LDS_CAST(sBl + ldso), 16, 0, 0);
        }
        __syncthreads();

        bf16x8 ah[4], al[4], bh[2], bl[2];
        #pragma unroll
        for (int mt = 0; mt < 4; ++mt) {
            const int row = mt * 16 + r;
            const int sw = g ^ ((row >> 2) & 3);
            ah[mt] = *reinterpret_cast<const bf16x8*>(sAh + row * 32 + sw * 8);
            al[mt] = *reinterpret_cast<const bf16x8*>(sAl + row * 32 + sw * 8);
        }
        #pragma unroll
        for (int nt = 0; nt < 2; ++nt) {
            const int row = wid * 32 + nt * 16 + r;
            const int sw = g ^ ((row >> 2) & 3);
            bh[nt] = *reinterpret_cast<const bf16x8*>(sBh + row * 32 + sw * 8);
            bl[nt] = *reinterpret_cast<const bf16x8*>(sBl + row * 32 + sw * 8);
        }
        #pragma unroll
        for (int mt = 0; mt < 4; ++mt)
            #pragma unroll
            for (int nt = 0; nt < 2; ++nt) {
                acc[mt][nt] = __builtin_amdgcn_mfma_f32_16x16x32_bf16(ah[mt], bh[nt], acc[mt][nt], 0, 0, 0);
                acc[mt][nt] = __builtin_amdgcn_mfma_f32_16x16x32_bf16(ah[mt], bl[nt], acc[mt][nt], 0, 0, 0);
                acc[mt][nt] = __builtin_amdgcn_mfma_f32_16x16x32_bf16(al[mt], bh[nt], acc[mt][nt], 0, 0, 0);
            }
        __syncthreads();
    }

    #pragma unroll
    for (int nt = 0; nt < 2; ++nt) {
        const int col = wid * 32 + nt * 16 + r;
        const float bv = bias[col0 + col];
        #pragma unroll
        for (int mt = 0; mt < 4; ++mt) {
            #pragma unroll
            for (int e = 0; e < 4; ++e) {
                const int row = row0 + mt * 16 + 4 * g + e;
                float v = acc[mt][nt][e] + bv;
                if (RELU) v = fmaxf(v, 0.f);
                C[(size_t)row * ldc + col0 + col] = v;
            }
        }
    }
}

// ---------------- importance / top-k
__global__ __launch_bounds__(256)
void importance_kernel(const float* __restrict__ h, const float* __restrict__ wi2,
                       const float* __restrict__ bi2, float* __restrict__ imp)
{
    const int wid = threadIdx.x >> 6, lane = threadIdx.x & 63;
    const int row = blockIdx.x * 4 + wid;
    const float* hr = h + (size_t)row * DH;
    float s = 0.f;
    #pragma unroll
    for (int i = 0; i < DH/64; ++i)
        s = fmaf(hr[lane + i*64], wi2[lane + i*64], s);
    #pragma unroll
    for (int off = 32; off; off >>= 1) s += __shfl_down(s, off);
    if (lane == 0) imp[row] = s + bi2[0];
}

__global__ __launch_bounds__(256)
void rank_kernel(const float* __restrict__ imp, int* __restrict__ flags)
{
    __shared__ float simp[SS];
    const int b = blockIdx.y;
    const int t = threadIdx.x;
    const float* bimp = imp + b * SS;
    for (int i = t; i < SS/4; i += 256)
        reinterpret_cast<float4*>(simp)[i] = reinterpret_cast<const float4*>(bimp)[i];
    __syncthreads();

    const int i = blockIdx.x * 32 + (t >> 3);
    const int part = t & 7;
    const float v = simp[i];
    const float4* slice = reinterpret_cast<const float4*>(simp + part * (SS/8));
    const int jb = part * (SS/8);
    int rank = 0;
    #pragma unroll 8
    for (int jj = 0; jj < SS/32; ++jj) {
        const float4 u4 = slice[jj];
        const int j = jb + jj * 4;
        rank += (u4.x > v) || ((u4.x == v) && (j + 0 < i));
        rank += (u4.y > v) || ((u4.y == v) && (j + 1 < i));
        rank += (u4.z > v) || ((u4.z == v) && (j + 2 < i));
        rank += (u4.w > v) || ((u4.w == v) && (j + 3 < i));
    }
    rank += __shfl_xor(rank, 1);
    rank += __shfl_xor(rank, 2);
    rank += __shfl_xor(rank, 4);
    if (part == 0) flags[b * SS + i] = (rank < KSEL) ? 1 : 0;
}

__global__ __launch_bounds__(256)
void compact_kernel(const int* __restrict__ flags, int* __restrict__ idxg)
{
    __shared__ int sscan[SS];
    __shared__ int sidx[KSEL];
    const int b = blockIdx.x, t = threadIdx.x;
    for (int i = t; i < SS; i += 256) sscan[i] = flags[b * SS + i];
    __syncthreads();
    for (int off = 1; off < SS; off <<= 1) {
        int vals[SS/256];
        #pragma unroll
        for (int c = 0; c < SS/256; ++c) {
            const int i = t + c * 256;
            int v = sscan[i];
            if (i >= off) v += sscan[i - off];
            vals[c] = v;
        }
        __syncthreads();
        #pragma unroll
        for (int c = 0; c < SS/256; ++c) sscan[t + c * 256] = vals[c];
        __syncthreads();
    }
    for (int i = t; i < SS; i += 256) {
        const int f = flags[b * SS + i];
        if (f) sidx[sscan[i] - 1] = i;
    }
    __syncthreads();
    for (int p = t; p < KPAD; p += 256)
        idxg[b * KPAD + p] = sidx[min(p, KSEL - 1)];
}

// ---------------- K/V relayout from compact KVc
__global__ __launch_bounds__(256)
void gather_kv(const short* __restrict__ KVc, short* __restrict__ Kg,
               short* __restrict__ Vg)
{
    __shared__ short Vs[64*72];
    const int t = threadIdx.x;
    const int c = blockIdx.x, h = blockIdx.y, b = blockIdx.z;
    const int srow = t >> 2;
    const int sq4  = t & 3;

    const size_t cbase = ((size_t)(b * HHD + h) * NCH + c) * 4096;

    const short* kb = KVc + (size_t)(b * KPAD + c * 64 + srow) * 2048 + h * HD + sq4 * 16;
    bf16x8 k0 = *reinterpret_cast<const bf16x8*>(kb);
    bf16x8 k1 = *reinterpret_cast<const bf16x8*>(kb + 8);
    short* kout = Kg + cbase + srow * HD + sq4 * 16;
    *reinterpret_cast<bf16x8*>(kout)     = k0;
    *reinterpret_cast<bf16x8*>(kout + 8) = k1;

    const short* vbp = kb + 1024;
    bf16x8 v0 = *reinterpret_cast<const bf16x8*>(vbp);
    bf16x8 v1 = *reinterpret_cast<const bf16x8*>(vbp + 8);
    #pragma unroll
    for (int j = 0; j < 8; ++j) {
        Vs[(sq4 * 16 + j) * 72 + srow]     = v0[j];
        Vs[(sq4 * 16 + 8 + j) * 72 + srow] = v1[j];
    }
    __syncthreads();

    const int x = 8 * (srow >> 4);
    short* vout = Vg + cbase + srow * 64;
    *reinterpret_cast<bf16x8*>(vout + ((sq4 * 16)     ^ x)) = *reinterpret_cast<const bf16x8*>(&Vs[srow * 72 + sq4 * 16]);
    *reinterpret_cast<bf16x8*>(vout + ((sq4 * 16 + 8) ^ x)) = *reinterpret_cast<const bf16x8*>(&Vs[srow * 72 + sq4 * 16 + 8]);
}

// ---------------- MFMA sparse flash attention
__global__ __launch_bounds__(256)
void attn_mfma(const short* __restrict__ Qb, const short* __restrict__ Kg,
               const short* __restrict__ Vg, short* __restrict__ AOhi)
{
    __shared__ short Ks[2][64*72];
    __shared__ short Vs[2][64*72];
    __shared__ short Ps[4][16*72];

    const int t = threadIdx.x;
    const int lane = t & 63, w = t >> 6;
    const int g = lane >> 4, r = lane & 15;
    const int qt = blockIdx.x, h = blockIdx.y, b = blockIdx.z;
    const int q0 = qt * 64;
    short* Psw = &Ps[w][0];

    const int srow = t >> 2;
    const int scol = (t & 3) * 16;
    const short* kcbase = Kg + ((size_t)(b * HHD + h) * NCH) * 4096 + srow * 64 + scol;
    const short* vcbase = Vg + ((size_t)(b * HHD + h) * NCH) * 4096 + srow * 64 + scol;

    bf16x8 qh[2];
    {
        const short* qrow = Qb + (size_t)(b * SS + q0 + w * 16 + r) * DD + h * HD;
        qh[0] = *reinterpret_cast<const bf16x8*>(qrow + 8 * g);
        qh[1] = *reinterpret_cast<const bf16x8*>(qrow + 32 + 8 * g);
    }

    bf16x8 ones;
    #pragma unroll
    for (int j = 0; j < 8; ++j) ones[j] = (short)0x3F80;

    f32x4 oacc[4];
    #pragma unroll
    for (int dt = 0; dt < 4; ++dt) oacc[dt] = (f32x4){0.f, 0.f, 0.f, 0.f};
    f32x4 dacc = (f32x4){0.f, 0.f, 0.f, 0.f};

    bf16x8 kreg0 = *reinterpret_cast<const bf16x8*>(kcbase);
    bf16x8 kreg1 = *reinterpret_cast<const bf16x8*>(kcbase + 8);
    bf16x8 vreg0 = *reinterpret_cast<const bf16x8*>(vcbase);
    bf16x8 vreg1 = *reinterpret_cast<const bf16x8*>(vcbase + 8);

    for (int c = 0; c < NCH; ++c) {
        const int cur = c & 1;
        *reinterpret_cast<bf16x8*>(&Ks[cur][srow*72 + scol])     = kreg0;
        *reinterpret_cast<bf16x8*>(&Ks[cur][srow*72 + scol + 8]) = kreg1;
        *reinterpret_cast<bf16x8*>(&Vs[cur][srow*72 + scol])     = vreg0;
        *reinterpret_cast<bf16x8*>(&Vs[cur][srow*72 + scol + 8]) = vreg1;
        if (c + 1 < NCH) {
            const short* kn = kcbase + (size_t)(c + 1) * 4096;
            const short* vn = vcbase + (size_t)(c + 1) * 4096;
            kreg0 = *reinterpret_cast<const bf16x8*>(kn);
            kreg1 = *reinterpret_cast<const bf16x8*>(kn + 8);
            vreg0 = *reinterpret_cast<const bf16x8*>(vn);
            vreg1 = *reinterpret_cast<const bf16x8*>(vn + 8);
        }
        __syncthreads();

        f32x4 sa[4];
        #pragma unroll
        for (int kt = 0; kt < 4; ++kt) {
            bf16x8 kf0 = *reinterpret_cast<const bf16x8*>(&Ks[cur][(kt*16 + r)*72 + 8*g]);
            bf16x8 kf1 = *reinterpret_cast<const bf16x8*>(&Ks[cur][(kt*16 + r)*72 + 32 + 8*g]);
            f32x4 s = (f32x4){0.f, 0.f, 0.f, 0.f};
            s = __builtin_amdgcn_mfma_f32_16x16x32_bf16(qh[0], kf0, s, 0, 0, 0);
            s = __builtin_amdgcn_mfma_f32_16x16x32_bf16(qh[1], kf1, s, 0, 0, 0);
            sa[kt] = s;
        }
        if (c == NCH - 1) {
            #pragma unroll
            for (int kt = 0; kt < 4; ++kt)
                if (c*64 + kt*16 + r >= KSEL)
                    sa[kt] = (f32x4){-INFINITY, -INFINITY, -INFINITY, -INFINITY};
        }

        #pragma unroll
        for (int kt = 0; kt < 4; ++kt)
            #pragma unroll
            for (int e = 0; e < 4; ++e)
                Psw[(4*g + e)*72 + ((kt*16 + r) ^ (8*g))] = bf16rne(__expf(sa[kt][e]));

        #pragma unroll
        for (int kc = 0; kc < 2; ++kc) {
            bf16x8 pf = *reinterpret_cast<const bf16x8*>(&Psw[r*72 + kc*32 + 8*(g ^ (r >> 2))]);
            dacc = __builtin_amdgcn_mfma_f32_16x16x32_bf16(pf, ones, dacc, 0, 0, 0);
            #pragma unroll
            for (int dt = 0; dt < 4; ++dt) {
                bf16x8 vf = *reinterpret_cast<const bf16x8*>(&Vs[cur][(dt*16 + r)*72 + kc*32 + 8*(g ^ dt)]);
                oacc[dt] = __builtin_amdgcn_mfma_f32_16x16x32_bf16(pf, vf, oacc[dt], 0, 0, 0);
            }
        }
    }

    #pragma unroll
    for (int dt = 0; dt < 4; ++dt)
        #pragma unroll
        for (int e = 0; e < 4; ++e) {
            const size_t a = (size_t)(b * SS + q0 + w*16 + 4*g + e) * DD + h * HD + dt*16 + r;
            AOhi[a] = bf16rne(oacc[dt][e] / dacc[e]);
        }
}

extern "C" void kernel_launch(void* const* d_in, const int* in_sizes, int n_in,
                              void* d_out, int out_size, void* d_ws, size_t ws_size,
                              hipStream_t stream)
{
    const float* x   = (const float*)d_in[0];
    const float* wq  = (const float*)d_in[1];
    const float* bq  = (const float*)d_in[2];
    const float* wk  = (const float*)d_in[3];
    const float* bk  = (const float*)d_in[4];
    const float* wv  = (const float*)d_in[5];
    const float* bv  = (const float*)d_in[6];
    const float* wo  = (const float*)d_in[7];
    const float* bo  = (const float*)d_in[8];
    const float* wi1 = (const float*)d_in[9];
    const float* bi1 = (const float*)d_in[10];
    const float* wi2 = (const float*)d_in[11];
    const float* bi2 = (const float*)d_in[12];
    float* out = (float*)d_out;

    const size_t MB = 1ull << 20;
    char* W = (char*)d_ws;
    short* x_hi  = (short*)(W + 0);          // 16 MB
    short* x_lo  = (short*)(W + 16*MB);      // 16 MB
    short* Qb    = (short*)(W + 32*MB);      // 16 MB (8192 x 1024 bf16, pre-scaled 1/8)
    short* KVc   = (short*)(W + 48*MB);      // 10.5 MB (2560 x 2048 bf16)
    short* Wi_hi = (short*)(W + 96*MB);      // 1 MB
    short* Wi_lo = (short*)(W + 97*MB);      // 1 MB
    short* Bqkv_hi=(short*)(W + 128*MB);     // 6 MB (wq,wk,wv hi, stacked)
    short* wo_hi = (short*)(W + 134*MB);     // 2 MB
    float* Hw    = (float*)(W + 144*MB);     // 16 MB (dead after importance_kernel)
    short* Kg    = (short*)(W + 144*MB);     // 5.25 MB (over dead Hw)
    short* Vg    = (short*)(W + 150*MB);     // 5.25 MB
    float* bkv   = (float*)(W + 160*MB);
    float* imp   = (float*)(W + 160*MB + 64*1024);
    int*   flags = (int*)(W + 160*MB + 128*1024);
    int*   idxg  = (int*)(W + 160*MB + 192*1024);
    short* AO_hi = x_hi;                     // x_hi dead after projections

    const size_t NM = (size_t)MTOT * DD;

    // 0. splits + fused bias
    split_convert<<<(NM/4 + 255)/256, 256, 0, stream>>>(x, x_hi, x_lo, NM/4);
    split_weights<<<dim3(DD*DD/4/256, 5), 256, 0, stream>>>(
        wq, wk, wv, wo, wi1, Bqkv_hi, wo_hi, Wi_hi, Wi_lo);
    concat_bias2<<<2048/256, 256, 0, stream>>>(bk, bv, bkv);

    // 1. indexer h = relu(x @ wi1^T + bi1)  -- 3-term split, 64x128 tiles (2 blocks/CU)
    gemm_split64<true><<<dim3(DH/128, MTOT/64), 256, 0, stream>>>(
        x_hi, x_lo, Wi_hi, Wi_lo, bi1, Hw, MTOT, DH, DD, DH);
    // 2-3. importance + top-k
    importance_kernel<<<MTOT/4, 256, 0, stream>>>(Hw, wi2, bi2, imp);
    rank_kernel<<<dim3(SS/32, BB), 256, 0, stream>>>(imp, flags);
    compact_kernel<<<BB, 256, 0, stream>>>(flags, idxg);

    // 4a. Q projection: 1-term bf16, pre-scaled by 1/8
    gemm_bf16<true, true><<<dim3(DD/128, MTOT/128), 256, 0, stream>>>(
        x_hi, Bqkv_hi, bq, Qb, MTOT, DD, DD, DD);
    // 4b. gathered K/V projection: only the 2560 selected rows
    gemm_kv_gather<<<dim3(2048/128, MKV/128), 256, 0, stream>>>(
        x_hi, Bqkv_hi + (size_t)DD*DD, idxg, bkv, KVc);

    // 4c. relayout K/V chunk-contiguous
    gather_kv<<<dim3(NCH, HHD, BB), 256, 0, stream>>>(KVc, Kg, Vg);

    // 5. no-max-softmax MFMA sparse flash attention -> bf16
    attn_mfma<<<dim3(SS/64, HHD, BB), 256, 0, stream>>>(Qb, Kg, Vg, AO_hi);

    // 6. output projection: 1-term bf16 BK=64
    gemm_bf16<false, false><<<dim3(DD/128, MTOT/128), 256, 0, stream>>>(
        AO_hi, wo_hi, bo, out, MTOT, DD, DD, DD);
}

// Round 14
// 200.500 us; speedup vs baseline: 2.4405x; 1.0189x over previous
//
#include <hip/hip_runtime.h>
#include <math.h>

#define BB 4
#define SS 2048
#define DD 1024
#define HHD 16      // heads
#define HD 64       // head dim
#define DH 512      // indexer hidden
#define KSEL 614    // top-k count
#define KPAD 640    // padded to multiple of 64
#define MTOT (BB*SS)
#define NCH (KPAD/64)
#define MKV (BB*KPAD)   // 2560 gathered K/V rows

typedef __attribute__((ext_vector_type(8))) short bf16x8;
typedef __attribute__((ext_vector_type(4))) float f32x4;

#define LDS_CAST(p) ((__attribute__((address_space(3))) void*)(p))
#define GLB_CAST(p) ((const __attribute__((address_space(1))) void*)(p))

// Q pre-scale: (1/8) * log2(e) so attention can use exp2 directly
#define QK_SCALE 0.18033688011112042f

// ---------------- fp32 -> bf16 helpers (RNE)
__device__ inline short bf16rne(float v)
{
    unsigned u = __builtin_bit_cast(unsigned, v);
    return (short)((u + 0x7FFFu + ((u >> 16) & 1u)) >> 16);
}

__device__ inline void split1(float v, short& h, short& l)
{
    unsigned u = __builtin_bit_cast(unsigned, v);
    unsigned hr = (u + 0x7FFFu + ((u >> 16) & 1u)) >> 16;
    h = (short)hr;
    float hf = __builtin_bit_cast(float, hr << 16);
    float res = v - hf;
    unsigned u2 = __builtin_bit_cast(unsigned, res);
    unsigned lr = (u2 + 0x7FFFu + ((u2 >> 16) & 1u)) >> 16;
    l = (short)lr;
}

__global__ __launch_bounds__(256)
void split_convert(const float* __restrict__ in, short* __restrict__ hi,
                   short* __restrict__ lo, int n4)
{
    const int i = blockIdx.x * 256 + threadIdx.x;
    if (i >= n4) return;
    float4 v = reinterpret_cast<const float4*>(in)[i];
    short4 h, l;
    split1(v.x, h.x, l.x);
    split1(v.y, h.y, l.y);
    split1(v.z, h.z, l.z);
    split1(v.w, h.w, l.w);
    reinterpret_cast<short4*>(hi)[i] = h;
    reinterpret_cast<short4*>(lo)[i] = l;
}

// fused weight splits: y=0 wq(hi), 1 wk(hi), 2 wv(hi), 3 wo(hi), 4 wi1(hi+lo)
__global__ __launch_bounds__(256)
void split_weights(const float* __restrict__ wq, const float* __restrict__ wk,
                   const float* __restrict__ wv, const float* __restrict__ wo,
                   const float* __restrict__ wi1,
                   short* __restrict__ Bqkv_hi, short* __restrict__ wo_hi,
                   short* __restrict__ Wi_hi, short* __restrict__ Wi_lo)
{
    const int i = blockIdx.x * 256 + threadIdx.x;
    const int which = blockIdx.y;
    if (which < 4) {
        const float* src = (which == 0) ? wq : (which == 1) ? wk : (which == 2) ? wv : wo;
        short* dst = (which == 3) ? wo_hi : (Bqkv_hi + (size_t)which * DD * DD);
        float4 v = reinterpret_cast<const float4*>(src)[i];
        short4 hh;
        hh.x = bf16rne(v.x); hh.y = bf16rne(v.y); hh.z = bf16rne(v.z); hh.w = bf16rne(v.w);
        reinterpret_cast<short4*>(dst)[i] = hh;
    } else {
        if (i >= DH*DD/4) return;
        float4 v = reinterpret_cast<const float4*>(wi1)[i];
        short4 h, l;
        split1(v.x, h.x, l.x); split1(v.y, h.y, l.y);
        split1(v.z, h.z, l.z); split1(v.w, h.w, l.w);
        reinterpret_cast<short4*>(Wi_hi)[i] = h;
        reinterpret_cast<short4*>(Wi_lo)[i] = l;
    }
}

__global__ __launch_bounds__(256)
void concat_bias2(const float* __restrict__ a, const float* __restrict__ b,
                  float* __restrict__ o)
{
    const int i = blockIdx.x * 256 + threadIdx.x;   // 2048
    o[i] = (i < 1024) ? a[i] : b[i - 1024];
}

// ---------------- plain bf16 MFMA GEMM, BK=64: C = A @ B^T + bias
// 128x128 tile, 4 waves, 32 MFMA/barrier, 8-slot XOR swizzle (conflict-free, r10-verified).
template<bool BF16_OUT, bool QSCALE>
__global__ __launch_bounds__(256)
void gemm_bf16(const short* __restrict__ Ahi, const short* __restrict__ Bhi,
               const float* __restrict__ bias, void* __restrict__ Cv,
               int M, int N, int K, int ldc)
{
    __shared__ short sAh[128*64];
    __shared__ short sBh[128*64];

    const int t = threadIdx.x;
    const int lane = t & 63, wid = t >> 6;
    const int wm = wid >> 1, wn = wid & 1;
    const int row0 = blockIdx.y * 128, col0 = blockIdx.x * 128;
    const int g = lane >> 4, r = lane & 15;
    const int lrow = lane >> 3;
    const int lslot = lane & 7;

    f32x4 acc[4][4];
    #pragma unroll
    for (int mt = 0; mt < 4; ++mt)
        #pragma unroll
        for (int nt = 0; nt < 4; ++nt) acc[mt][nt] = (f32x4){0.f, 0.f, 0.f, 0.f};

    for (int k0 = 0; k0 < K; k0 += 64) {
        #pragma unroll
        for (int e = 0; e < 4; ++e) {
            const int rl = wid * 32 + e * 8 + lrow;
            const int scol = k0 + ((lslot ^ (rl & 7)) << 3);
            const size_t ga = (size_t)(row0 + rl) * K + scol;
            const size_t gb = (size_t)(col0 + rl) * K + scol;
            const int ldso = (wid * 32 + e * 8) * 64;
            __builtin_amdgcn_global_load_lds(GLB_CAST(Ahi + ga), LDS_CAST(sAh + ldso), 16, 0, 0);
            __builtin_amdgcn_global_load_lds(GLB_CAST(Bhi + gb), LDS_CAST(sBh + ldso), 16, 0, 0);
        }
        __syncthreads();

        #pragma unroll
        for (int kk = 0; kk < 2; ++kk) {
            bf16x8 ah[4], bh[4];
            #pragma unroll
            for (int mt = 0; mt < 4; ++mt) {
                const int rw = wm * 64 + mt * 16 + r;
                ah[mt] = *reinterpret_cast<const bf16x8*>(sAh + rw * 64 + (((kk*4 + g) ^ (rw & 7)) << 3));
            }
            #pragma unroll
            for (int nt = 0; nt < 4; ++nt) {
                const int rw = wn * 64 + nt * 16 + r;
                bh[nt] = *reinterpret_cast<const bf16x8*>(sBh + rw * 64 + (((kk*4 + g) ^ (rw & 7)) << 3));
            }
            #pragma unroll
            for (int mt = 0; mt < 4; ++mt)
                #pragma unroll
                for (int nt = 0; nt < 4; ++nt)
                    acc[mt][nt] = __builtin_amdgcn_mfma_f32_16x16x32_bf16(ah[mt], bh[nt], acc[mt][nt], 0, 0, 0);
        }
        __syncthreads();
    }

    #pragma unroll
    for (int nt = 0; nt < 4; ++nt) {
        const int col = wn * 64 + nt * 16 + r;
        const float bv = bias[col0 + col];
        const bool qs = QSCALE && (col0 + col) < 1024;
        #pragma unroll
        for (int mt = 0; mt < 4; ++mt) {
            #pragma unroll
            for (int e = 0; e < 4; ++e) {
                const int row = row0 + wm * 64 + mt * 16 + 4 * g + e;
                float v = acc[mt][nt][e] + bv;
                if (qs) v *= QK_SCALE;
                if (BF16_OUT)
                    ((short*)Cv)[(size_t)row * ldc + col0 + col] = bf16rne(v);
                else
                    ((float*)Cv)[(size_t)row * ldc + col0 + col] = v;
            }
        }
    }
}

// ---------------- gathered KV GEMM: C[MKV,2048] = x_hi[idx rows] @ [wk;wv]^T + bias
__global__ __launch_bounds__(256)
void gemm_kv_gather(const short* __restrict__ Ahi, const short* __restrict__ Bhi,
                    const int* __restrict__ idxg, const float* __restrict__ bias,
                    short* __restrict__ C)
{
    __shared__ short sAh[128*64];
    __shared__ short sBh[128*64];

    const int K = DD, N = 2048;
    const int t = threadIdx.x;
    const int lane = t & 63, wid = t >> 6;
    const int wm = wid >> 1, wn = wid & 1;
    const int row0 = blockIdx.y * 128, col0 = blockIdx.x * 128;
    const int g = lane >> 4, r = lane & 15;
    const int lrow = lane >> 3;
    const int lslot = lane & 7;

    size_t garow[4];
    #pragma unroll
    for (int e = 0; e < 4; ++e) {
        const int rl = row0 + wid * 32 + e * 8 + lrow;
        const int grow = (rl / KPAD) * SS + idxg[rl];
        garow[e] = (size_t)grow * K;
    }

    f32x4 acc[4][4];
    #pragma unroll
    for (int mt = 0; mt < 4; ++mt)
        #pragma unroll
        for (int nt = 0; nt < 4; ++nt) acc[mt][nt] = (f32x4){0.f, 0.f, 0.f, 0.f};

    for (int k0 = 0; k0 < K; k0 += 64) {
        #pragma unroll
        for (int e = 0; e < 4; ++e) {
            const int rl = wid * 32 + e * 8 + lrow;
            const int scol = k0 + ((lslot ^ (rl & 7)) << 3);
            const size_t gb = (size_t)(col0 + rl) * K + scol;
            const int ldso = (wid * 32 + e * 8) * 64;
            __builtin_amdgcn_global_load_lds(GLB_CAST(Ahi + garow[e] + scol), LDS_CAST(sAh + ldso), 16, 0, 0);
            __builtin_amdgcn_global_load_lds(GLB_CAST(Bhi + gb), LDS_CAST(sBh + ldso), 16, 0, 0);
        }
        __syncthreads();

        #pragma unroll
        for (int kk = 0; kk < 2; ++kk) {
            bf16x8 ah[4], bh[4];
            #pragma unroll
            for (int mt = 0; mt < 4; ++mt) {
                const int rw = wm * 64 + mt * 16 + r;
                ah[mt] = *reinterpret_cast<const bf16x8*>(sAh + rw * 64 + (((kk*4 + g) ^ (rw & 7)) << 3));
            }
            #pragma unroll
            for (int nt = 0; nt < 4; ++nt) {
                const int rw = wn * 64 + nt * 16 + r;
                bh[nt] = *reinterpret_cast<const bf16x8*>(sBh + rw * 64 + (((kk*4 + g) ^ (rw & 7)) << 3));
            }
            #pragma unroll
            for (int mt = 0; mt < 4; ++mt)
                #pragma unroll
                for (int nt = 0; nt < 4; ++nt)
                    acc[mt][nt] = __builtin_amdgcn_mfma_f32_16x16x32_bf16(ah[mt], bh[nt], acc[mt][nt], 0, 0, 0);
        }
        __syncthreads();
    }

    #pragma unroll
    for (int nt = 0; nt < 4; ++nt) {
        const int col = wn * 64 + nt * 16 + r;
        const float bv = bias[col0 + col];
        #pragma unroll
        for (int mt = 0; mt < 4; ++mt) {
            #pragma unroll
            for (int e = 0; e < 4; ++e) {
                const int row = row0 + wm * 64 + mt * 16 + 4 * g + e;
                C[(size_t)row * N + col0 + col] = bf16rne(acc[mt][nt][e] + bv);
            }
        }
    }
}

// ---------------- split-bf16 MFMA GEMM (3-term), 64x128 tile (r13-verified)
template<bool RELU>
__global__ __launch_bounds__(256)
void gemm_split64(const short* __restrict__ Ahi, const short* __restrict__ Alo,
                  const short* __restrict__ Bhi, const short* __restrict__ Blo,
                  const float* __restrict__ bias, float* __restrict__ C,
                  int M, int N, int K, int ldc)
{
    __shared__ short sAh[64*32];
    __shared__ short sAl[64*32];
    __shared__ short sBh[128*32];
    __shared__ short sBl[128*32];

    const int t = threadIdx.x;
    const int lane = t & 63, wid = t >> 6;
    const int row0 = blockIdx.y * 64, col0 = blockIdx.x * 128;
    const int g = lane >> 4, r = lane & 15;
    const int srow = lane >> 2;
    const int sslot = lane & 3;

    f32x4 acc[4][2];
    #pragma unroll
    for (int mt = 0; mt < 4; ++mt)
        #pragma unroll
        for (int nt = 0; nt < 2; ++nt) acc[mt][nt] = (f32x4){0.f, 0.f, 0.f, 0.f};

    for (int k0 = 0; k0 < K; k0 += 32) {
        {
            const int rl = wid * 16 + srow;
            const int scol = k0 + ((sslot ^ ((rl >> 2) & 3)) << 3);
            const size_t ga = (size_t)(row0 + rl) * K + scol;
            const int ldso = (wid * 16) * 32;
            __builtin_amdgcn_global_load_lds(GLB_CAST(Ahi + ga), LDS_CAST(sAh + ldso), 16, 0, 0);
            __builtin_amdgcn_global_load_lds(GLB_CAST(Alo + ga), LDS_CAST(sAl + ldso), 16, 0, 0);
        }
        #pragma unroll
        for (int i = 0; i < 2; ++i) {
            const int rl = i * 64 + wid * 16 + srow;
            const int scol = k0 + ((sslot ^ ((rl >> 2) & 3)) << 3);
            const size_t gb = (size_t)(col0 + rl) * K + scol;
            const int ldso = (i * 64 + wid * 16) * 32;
            __builtin_amdgcn_global_load_lds(GLB_CAST(Bhi + gb), LDS_CAST(sBh + ldso), 16, 0, 0);
            __builtin_amdgcn_global_load_lds(GLB_CAST(Blo + gb), LDS_CAST(sBl + ldso), 16, 0, 0);
        }
        __syncthreads();

        bf16x8 ah[4], al[4], bh[2], bl[2];
        #pragma unroll
        for (int mt = 0; mt < 4; ++mt) {
            const int row = mt * 16 + r;
            const int sw = g ^ ((row >> 2) & 3);
            ah[mt] = *reinterpret_cast<const bf16x8*>(sAh + row * 32 + sw * 8);
            al[mt] = *reinterpret_cast<const bf16x8*>(sAl + row * 32 + sw * 8);
        }
        #pragma unroll
        for (int nt = 0; nt < 2; ++nt) {
            const int row = wid * 32 + nt * 16 + r;
            const int sw = g ^ ((row >> 2) & 3);
            bh[nt] = *reinterpret_cast<const bf16x8*>(sBh + row * 32 + sw * 8);
            bl[nt] = *reinterpret_cast<const bf16x8*>(sBl + row * 32 + sw * 8);
        }
        #pragma unroll
        for (int mt = 0; mt < 4; ++mt)
            #pragma unroll
            for (int nt = 0; nt < 2; ++nt) {
                acc[mt][nt] = __builtin_amdgcn_mfma_f32_16x16x32_bf16(ah[mt], bh[nt], acc[mt][nt], 0, 0, 0);
                acc[mt][nt] = __builtin_amdgcn_mfma_f32_16x16x32_bf16(ah[mt], bl[nt], acc[mt][nt], 0, 0, 0);
                acc[mt][nt] = __builtin_amdgcn_mfma_f32_16x16x32_bf16(al[mt], bh[nt], acc[mt][nt], 0, 0, 0);
            }
        __syncthreads();
    }

    #pragma unroll
    for (int nt = 0; nt < 2; ++nt) {
        const int col = wid * 32 + nt * 16 + r;
        const float bv = bias[col0 + col];
        #pragma unroll
        for (int mt = 0; mt < 4; ++mt) {
            #pragma unroll
            for (int e = 0; e < 4; ++e) {
                const int row = row0 + mt * 16 + 4 * g + e;
                float v = acc[mt][nt][e] + bv;
                if (RELU) v = fmaxf(v, 0.f);
                C[(size_t)row * ldc + col0 + col] = v;
            }
        }
    }
}

// ---------------- importance / top-k
__global__ __launch_bounds__(256)
void importance_kernel(const float* __restrict__ h, const float* __restrict__ wi2,
                       const float* __restrict__ bi2, float* __restrict__ imp)
{
    const int wid = threadIdx.x >> 6, lane = threadIdx.x & 63;
    const int row = blockIdx.x * 4 + wid;
    const float* hr = h + (size_t)row * DH;
    float s = 0.f;
    #pragma unroll
    for (int i = 0; i < DH/64; ++i)
        s = fmaf(hr[lane + i*64], wi2[lane + i*64], s);
    #pragma unroll
    for (int off = 32; off; off >>= 1) s += __shfl_down(s, off);
    if (lane == 0) imp[row] = s + bi2[0];
}

__global__ __launch_bounds__(256)
void rank_kernel(const float* __restrict__ imp, int* __restrict__ flags)
{
    __shared__ float simp[SS];
    const int b = blockIdx.y;
    const int t = threadIdx.x;
    const float* bimp = imp + b * SS;
    for (int i = t; i < SS/4; i += 256)
        reinterpret_cast<float4*>(simp)[i] = reinterpret_cast<const float4*>(bimp)[i];
    __syncthreads();

    const int i = blockIdx.x * 32 + (t >> 3);
    const int part = t & 7;
    const float v = simp[i];
    const float4* slice = reinterpret_cast<const float4*>(simp + part * (SS/8));
    const int jb = part * (SS/8);
    int rank = 0;
    #pragma unroll 8
    for (int jj = 0; jj < SS/32; ++jj) {
        const float4 u4 = slice[jj];
        const int j = jb + jj * 4;
        rank += (u4.x > v) || ((u4.x == v) && (j + 0 < i));
        rank += (u4.y > v) || ((u4.y == v) && (j + 1 < i));
        rank += (u4.z > v) || ((u4.z == v) && (j + 2 < i));
        rank += (u4.w > v) || ((u4.w == v) && (j + 3 < i));
    }
    rank += __shfl_xor(rank, 1);
    rank += __shfl_xor(rank, 2);
    rank += __shfl_xor(rank, 4);
    if (part == 0) flags[b * SS + i] = (rank < KSEL) ? 1 : 0;
}

__global__ __launch_bounds__(256)
void compact_kernel(const int* __restrict__ flags, int* __restrict__ idxg)
{
    __shared__ int sscan[SS];
    __shared__ int sidx[KSEL];
    const int b = blockIdx.x, t = threadIdx.x;
    for (int i = t; i < SS; i += 256) sscan[i] = flags[b * SS + i];
    __syncthreads();
    for (int off = 1; off < SS; off <<= 1) {
        int vals[SS/256];
        #pragma unroll
        for (int c = 0; c < SS/256; ++c) {
            const int i = t + c * 256;
            int v = sscan[i];
            if (i >= off) v += sscan[i - off];
            vals[c] = v;
        }
        __syncthreads();
        #pragma unroll
        for (int c = 0; c < SS/256; ++c) sscan[t + c * 256] = vals[c];
        __syncthreads();
    }
    for (int i = t; i < SS; i += 256) {
        const int f = flags[b * SS + i];
        if (f) sidx[sscan[i] - 1] = i;
    }
    __syncthreads();
    for (int p = t; p < KPAD; p += 256)
        idxg[b * KPAD + p] = sidx[min(p, KSEL - 1)];
}

// ---------------- K/V relayout from compact KVc
__global__ __launch_bounds__(256)
void gather_kv(const short* __restrict__ KVc, short* __restrict__ Kg,
               short* __restrict__ Vg)
{
    __shared__ short Vs[64*72];
    const int t = threadIdx.x;
    const int c = blockIdx.x, h = blockIdx.y, b = blockIdx.z;
    const int srow = t >> 2;
    const int sq4  = t & 3;

    const size_t cbase = ((size_t)(b * HHD + h) * NCH + c) * 4096;

    const short* kb = KVc + (size_t)(b * KPAD + c * 64 + srow) * 2048 + h * HD + sq4 * 16;
    bf16x8 k0 = *reinterpret_cast<const bf16x8*>(kb);
    bf16x8 k1 = *reinterpret_cast<const bf16x8*>(kb + 8);
    short* kout = Kg + cbase + srow * HD + sq4 * 16;
    *reinterpret_cast<bf16x8*>(kout)     = k0;
    *reinterpret_cast<bf16x8*>(kout + 8) = k1;

    const short* vbp = kb + 1024;
    bf16x8 v0 = *reinterpret_cast<const bf16x8*>(vbp);
    bf16x8 v1 = *reinterpret_cast<const bf16x8*>(vbp + 8);
    #pragma unroll
    for (int j = 0; j < 8; ++j) {
        Vs[(sq4 * 16 + j) * 72 + srow]     = v0[j];
        Vs[(sq4 * 16 + 8 + j) * 72 + srow] = v1[j];
    }
    __syncthreads();

    const int x = 8 * (srow >> 4);
    short* vout = Vg + cbase + srow * 64;
    *reinterpret_cast<bf16x8*>(vout + ((sq4 * 16)     ^ x)) = *reinterpret_cast<const bf16x8*>(&Vs[srow * 72 + sq4 * 16]);
    *reinterpret_cast<bf16x8*>(vout + ((sq4 * 16 + 8) ^ x)) = *reinterpret_cast<const bf16x8*>(&Vs[srow * 72 + sq4 * 16 + 8]);
}

// ---------------- MFMA sparse flash attention: 8 waves / 128 q-rows per block,
// exp2 softmax (Q pre-scaled by log2e/8), truncating P->bf16 (bias cancels in ratio),
// ones-column denominator, double-buffered LDS
__global__ __launch_bounds__(512)
void attn_mfma(const short* __restrict__ Qb, const short* __restrict__ Kg,
               const short* __restrict__ Vg, short* __restrict__ AOhi)
{
    __shared__ short Ks[2][64*72];
    __shared__ short Vs[2][64*72];
    __shared__ short Ps[8][16*72];

    const int t = threadIdx.x;
    const int lane = t & 63, w = t >> 6;      // 8 waves
    const int g = lane >> 4, r = lane & 15;
    const int qt = blockIdx.x, h = blockIdx.y, b = blockIdx.z;
    const int q0 = qt * 128;
    short* Psw = &Ps[w][0];

    // staging: 512 threads x 1 bf16x8 per array per chunk
    const int srow = t >> 3;           // 0..63
    const int scol = (t & 7) * 8;      // 0..56
    const short* kcbase = Kg + ((size_t)(b * HHD + h) * NCH) * 4096 + srow * 64 + scol;
    const short* vcbase = Vg + ((size_t)(b * HHD + h) * NCH) * 4096 + srow * 64 + scol;

    bf16x8 qh[2];
    {
        const short* qrow = Qb + (size_t)(b * SS + q0 + w * 16 + r) * DD + h * HD;
        qh[0] = *reinterpret_cast<const bf16x8*>(qrow + 8 * g);
        qh[1] = *reinterpret_cast<const bf16x8*>(qrow + 32 + 8 * g);
    }

    bf16x8 ones;
    #pragma unroll
    for (int j = 0; j < 8; ++j) ones[j] = (short)0x3F80;

    f32x4 oacc[4];
    #pragma unroll
    for (int dt = 0; dt < 4; ++dt) oacc[dt] = (f32x4){0.f, 0.f, 0.f, 0.f};
    f32x4 dacc = (f32x4){0.f, 0.f, 0.f, 0.f};

    bf16x8 kreg = *reinterpret_cast<const bf16x8*>(kcbase);
    bf16x8 vreg = *reinterpret_cast<const bf16x8*>(vcbase);

    for (int c = 0; c < NCH; ++c) {
        const int cur = c & 1;
        *reinterpret_cast<bf16x8*>(&Ks[cur][srow*72 + scol]) = kreg;
        *reinterpret_cast<bf16x8*>(&Vs[cur][srow*72 + scol]) = vreg;
        if (c + 1 < NCH) {
            kreg = *reinterpret_cast<const bf16x8*>(kcbase + (size_t)(c + 1) * 4096);
            vreg = *reinterpret_cast<const bf16x8*>(vcbase + (size_t)(c + 1) * 4096);
        }
        __syncthreads();

        // ---- QK^T from LDS (scores already scaled by log2e/8 via Q)
        f32x4 sa[4];
        #pragma unroll
        for (int kt = 0; kt < 4; ++kt) {
            bf16x8 kf0 = *reinterpret_cast<const bf16x8*>(&Ks[cur][(kt*16 + r)*72 + 8*g]);
            bf16x8 kf1 = *reinterpret_cast<const bf16x8*>(&Ks[cur][(kt*16 + r)*72 + 32 + 8*g]);
            f32x4 s = (f32x4){0.f, 0.f, 0.f, 0.f};
            s = __builtin_amdgcn_mfma_f32_16x16x32_bf16(qh[0], kf0, s, 0, 0, 0);
            s = __builtin_amdgcn_mfma_f32_16x16x32_bf16(qh[1], kf1, s, 0, 0, 0);
            sa[kt] = s;
        }
        if (c == NCH - 1) {
            #pragma unroll
            for (int kt = 0; kt < 4; ++kt)
                if (c*64 + kt*16 + r >= KSEL)
                    sa[kt] = (f32x4){-INFINITY, -INFINITY, -INFINITY, -INFINITY};
        }

        // ---- p = exp2(s); truncate to bf16 (downward bias cancels in num/denom ratio)
        #pragma unroll
        for (int kt = 0; kt < 4; ++kt)
            #pragma unroll
            for (int e = 0; e < 4; ++e)
                Psw[(4*g + e)*72 + ((kt*16 + r) ^ (8*g))] =
                    (short)(__builtin_bit_cast(unsigned, exp2f(sa[kt][e])) >> 16);

        // ---- PV + denominator (ones-column MFMA)
        #pragma unroll
        for (int kc = 0; kc < 2; ++kc) {
            bf16x8 pf = *reinterpret_cast<const bf16x8*>(&Psw[r*72 + kc*32 + 8*(g ^ (r >> 2))]);
            dacc = __builtin_amdgcn_mfma_f32_16x16x32_bf16(pf, ones, dacc, 0, 0, 0);
            #pragma unroll
            for (int dt = 0; dt < 4; ++dt) {
                bf16x8 vf = *reinterpret_cast<const bf16x8*>(&Vs[cur][(dt*16 + r)*72 + kc*32 + 8*(g ^ dt)]);
                oacc[dt] = __builtin_amdgcn_mfma_f32_16x16x32_bf16(pf, vf, oacc[dt], 0, 0, 0);
            }
        }
    }

    #pragma unroll
    for (int dt = 0; dt < 4; ++dt)
        #pragma unroll
        for (int e = 0; e < 4; ++e) {
            const size_t a = (size_t)(b * SS + q0 + w*16 + 4*g + e) * DD + h * HD + dt*16 + r;
            AOhi[a] = bf16rne(oacc[dt][e] / dacc[e]);
        }
}

extern "C" void kernel_launch(void* const* d_in, const int* in_sizes, int n_in,
                              void* d_out, int out_size, void* d_ws, size_t ws_size,
                              hipStream_t stream)
{
    const float* x   = (const float*)d_in[0];
    const float* wq  = (const float*)d_in[1];
    const float* bq  = (const float*)d_in[2];
    const float* wk  = (const float*)d_in[3];
    const float* bk  = (const float*)d_in[4];
    const float* wv  = (const float*)d_in[5];
    const float* bv  = (const float*)d_in[6];
    const float* wo  = (const float*)d_in[7];
    const float* bo  = (const float*)d_in[8];
    const float* wi1 = (const float*)d_in[9];
    const float* bi1 = (const float*)d_in[10];
    const float* wi2 = (const float*)d_in[11];
    const float* bi2 = (const float*)d_in[12];
    float* out = (float*)d_out;

    const size_t MB = 1ull << 20;
    char* W = (char*)d_ws;
    short* x_hi  = (short*)(W + 0);          // 16 MB
    short* x_lo  = (short*)(W + 16*MB);      // 16 MB
    short* Qb    = (short*)(W + 32*MB);      // 16 MB (8192 x 1024 bf16, pre-scaled by log2e/8)
    short* KVc   = (short*)(W + 48*MB);      // 10.5 MB (2560 x 2048 bf16)
    short* Wi_hi = (short*)(W + 96*MB);      // 1 MB
    short* Wi_lo = (short*)(W + 97*MB);      // 1 MB
    short* Bqkv_hi=(short*)(W + 128*MB);     // 6 MB (wq,wk,wv hi, stacked)
    short* wo_hi = (short*)(W + 134*MB);     // 2 MB
    float* Hw    = (float*)(W + 144*MB);     // 16 MB (dead after importance_kernel)
    short* Kg    = (short*)(W + 144*MB);     // 5.25 MB (over dead Hw)
    short* Vg    = (short*)(W + 150*MB);     // 5.25 MB
    float* bkv   = (float*)(W + 160*MB);
    float* imp   = (float*)(W + 160*MB + 64*1024);
    int*   flags = (int*)(W + 160*MB + 128*1024);
    int*   idxg  = (int*)(W + 160*MB + 192*1024);
    short* AO_hi = x_hi;                     // x_hi dead after projections

    const size_t NM = (size_t)MTOT * DD;

    // 0. splits + fused bias
    split_convert<<<(NM/4 + 255)/256, 256, 0, stream>>>(x, x_hi, x_lo, NM/4);
    split_weights<<<dim3(DD*DD/4/256, 5), 256, 0, stream>>>(
        wq, wk, wv, wo, wi1, Bqkv_hi, wo_hi, Wi_hi, Wi_lo);
    concat_bias2<<<2048/256, 256, 0, stream>>>(bk, bv, bkv);

    // 1. indexer h = relu(x @ wi1^T + bi1)  -- 3-term split, 64x128 tiles
    gemm_split64<true><<<dim3(DH/128, MTOT/64), 256, 0, stream>>>(
        x_hi, x_lo, Wi_hi, Wi_lo, bi1, Hw, MTOT, DH, DD, DH);
    // 2-3. importance + top-k
    importance_kernel<<<MTOT/4, 256, 0, stream>>>(Hw, wi2, bi2, imp);
    rank_kernel<<<dim3(SS/32, BB), 256, 0, stream>>>(imp, flags);
    compact_kernel<<<BB, 256, 0, stream>>>(flags, idxg);

    // 4a. Q projection: 1-term bf16, pre-scaled by log2e/8 (exp2 softmax)
    gemm_bf16<true, true><<<dim3(DD/128, MTOT/128), 256, 0, stream>>>(
        x_hi, Bqkv_hi, bq, Qb, MTOT, DD, DD, DD);
    // 4b. gathered K/V projection: only the 2560 selected rows
    gemm_kv_gather<<<dim3(2048/128, MKV/128), 256, 0, stream>>>(
        x_hi, Bqkv_hi + (size_t)DD*DD, idxg, bkv, KVc);

    // 4c. relayout K/V chunk-contiguous
    gather_kv<<<dim3(NCH, HHD, BB), 256, 0, stream>>>(KVc, Kg, Vg);

    // 5. exp2/trunc MFMA sparse flash attention, 8 waves/block -> bf16
    attn_mfma<<<dim3(SS/128, HHD, BB), 512, 0, stream>>>(Qb, Kg, Vg, AO_hi);

    // 6. output projection: 1-term bf16 BK=64
    gemm_bf16<false, false><<<dim3(DD/128, MTOT/128), 256, 0, stream>>>(
        AO_hi, wo_hi, bo, out, MTOT, DD, DD, DD);
}